// Round 1
// baseline (1603.700 us; speedup 1.0000x reference)
//
#include <hip/hip_runtime.h>
#include <hip/hip_bf16.h>
#include <math.h>

// ---------------------------------------------------------------------------
// NGLU: B=512 parcels x P=200 poi nodes. N=102400, E=1638400, HID=256.
// Pipeline: 2-layer GCN (parcel-local edges) -> pooling -> parcel-similarity
// GCN -> bipartite GAT (algebraically reduced; fs never materialized) -> fc.
// Round 0: all-f32, simple tiled GEMMs, per-parcel LDS aggregation.
// Workspace use ~216 MiB (two N x 256 f32 ping-pong buffers + CSR + smalls).
// ---------------------------------------------------------------------------

#define N_NODES 102400
#define B_PAR   512
#define P_NODES 200
#define E_EDGES 1638400
#define HIDF    256
#define CSR_CAP 64

// ---------------------------- generic f32 GEMM ----------------------------
// C[M,Nc] = A[M,K] @ B[K,Nc]   (TRANSB: B is [Nc,K] row-major, i.e. A@B^T)
// Epilogue: optional row-scale, bias, relu, medout ((x+1)/2).
// BM=BN=64, BK=16, 256 threads, 4x4 micro-tile per thread.
template<bool TRANSB, bool ROWSCALE, bool BIAS, bool RELU, bool MEDOUT>
__global__ __launch_bounds__(256) void gemm_f32(
    const float* __restrict__ A, const float* __restrict__ B,
    float* __restrict__ C, int M, int Nc, int K,
    const float* __restrict__ rowscale, const float* __restrict__ bias)
{
    __shared__ float As[16][64];
    __shared__ float Bs[16][64];
    const int tid = threadIdx.x;
    const int m0 = blockIdx.y * 64;
    const int n0 = blockIdx.x * 64;
    const int tm = tid >> 4, tn = tid & 15;
    const int lrow = tid >> 2, lkb = (tid & 3) << 2;   // A / transposed-B loads
    const int bk = tid >> 4, bc = (tid & 15) << 2;     // normal B loads
    float acc[4][4] = {};

    for (int k0 = 0; k0 < K; k0 += 16) {
        float4 av = *(const float4*)(A + (size_t)(m0 + lrow) * K + k0 + lkb);
        As[lkb + 0][lrow] = av.x;
        As[lkb + 1][lrow] = av.y;
        As[lkb + 2][lrow] = av.z;
        As[lkb + 3][lrow] = av.w;
        if (TRANSB) {
            float4 bv = *(const float4*)(B + (size_t)(n0 + lrow) * K + k0 + lkb);
            Bs[lkb + 0][lrow] = bv.x;
            Bs[lkb + 1][lrow] = bv.y;
            Bs[lkb + 2][lrow] = bv.z;
            Bs[lkb + 3][lrow] = bv.w;
        } else {
            float4 bv = *(const float4*)(B + (size_t)(k0 + bk) * Nc + n0 + bc);
            Bs[bk][bc + 0] = bv.x;
            Bs[bk][bc + 1] = bv.y;
            Bs[bk][bc + 2] = bv.z;
            Bs[bk][bc + 3] = bv.w;
        }
        __syncthreads();
#pragma unroll
        for (int k = 0; k < 16; ++k) {
            float a[4], b[4];
#pragma unroll
            for (int i = 0; i < 4; ++i) a[i] = As[k][tm * 4 + i];
#pragma unroll
            for (int j = 0; j < 4; ++j) b[j] = Bs[k][tn * 4 + j];
#pragma unroll
            for (int i = 0; i < 4; ++i)
#pragma unroll
                for (int j = 0; j < 4; ++j)
                    acc[i][j] += a[i] * b[j];
        }
        __syncthreads();
    }

#pragma unroll
    for (int i = 0; i < 4; ++i) {
        int row = m0 + tm * 4 + i;
        float rs = ROWSCALE ? rowscale[row] : 1.f;
        float v[4];
#pragma unroll
        for (int j = 0; j < 4; ++j) {
            float x = acc[i][j];
            if (ROWSCALE) x *= rs;
            if (BIAS)     x += bias[n0 + tn * 4 + j];
            if (RELU)     x = fmaxf(x, 0.f);
            if (MEDOUT)   x = (x + 1.f) * 0.5f;
            v[j] = x;
        }
        float4 o; o.x = v[0]; o.y = v[1]; o.z = v[2]; o.w = v[3];
        *(float4*)(C + (size_t)row * Nc + n0 + tn * 4) = o;
    }
}

// ------------------------- graph preprocessing -----------------------------
__global__ __launch_bounds__(256) void build_csr_k(
    const int* __restrict__ esrc, const int* __restrict__ edst,
    int* __restrict__ deg, unsigned char* __restrict__ csr)
{
    int e = blockIdx.x * 256 + threadIdx.x;
    if (e >= E_EDGES) return;
    int d = edst[e], s = esrc[e];
    int slot = atomicAdd(&deg[d], 1);
    if (slot < CSR_CAP) csr[(size_t)d * CSR_CAP + slot] = (unsigned char)(s % P_NODES);
}

__global__ __launch_bounds__(256) void norm_k(const int* __restrict__ deg,
                                              float* __restrict__ nrm)
{
    int i = blockIdx.x * 256 + threadIdx.x;
    if (i >= N_NODES) return;
    nrm[i] = rsqrtf((float)(deg[i] + 1));   // +1 self loop, always >=1
}

// -------------------- GCN neighbor aggregation (per parcel) ----------------
// Out[d] = (H[d] + sum_{in-edges} H[src]) * norm[d] + bias  (H has src-norm)
__global__ __launch_bounds__(256) void gcn_agg_k(
    const float* __restrict__ H, float* __restrict__ Out,
    const int* __restrict__ deg, const unsigned char* __restrict__ csr,
    const float* __restrict__ nrm, const float* __restrict__ bias, int relu)
{
    __shared__ float sh[P_NODES * 64];
    const int p = blockIdx.x;
    const int tid = threadIdx.x;
    const size_t base = (size_t)p * P_NODES;
    for (int quarter = 0; quarter < 4; ++quarter) {
        const int f0 = quarter * 64;
        for (int i = tid; i < P_NODES * 64; i += 256) {
            int n = i >> 6, f = i & 63;
            sh[i] = H[(base + n) * HIDF + f0 + f];
        }
        __syncthreads();
        for (int i = tid; i < P_NODES * 64; i += 256) {
            int d = i >> 6, f = i & 63;
            int g = (int)base + d;
            float acc = sh[i];                 // self loop
            int cnt = deg[g]; if (cnt > CSR_CAP) cnt = CSR_CAP;
            const unsigned char* lst = csr + (size_t)g * CSR_CAP;
            for (int j = 0; j < cnt; ++j)
                acc += sh[(int)lst[j] * 64 + f];
            float v = acc * nrm[g] + bias[f0 + f];
            if (relu) v = fmaxf(v, 0.f);
            Out[(size_t)g * HIDF + f0 + f] = v;
        }
        __syncthreads();
    }
}

// ------------------------------ pooling ------------------------------------
__global__ __launch_bounds__(256) void pool_k(const float* __restrict__ X,
                                              float* __restrict__ P)
{
    int b = blockIdx.x, f = threadIdx.x;
    size_t base = (size_t)b * P_NODES * HIDF;
    float s = 0.f;
    for (int n = 0; n < P_NODES; ++n) s += X[base + (size_t)n * HIDF + f];
    P[(size_t)b * HIDF + f] = s * (1.f / 200.f);
}

// ------------------- med = rownorm(concat(hrs, pool)) ----------------------
__global__ __launch_bounds__(256) void med_build_k(
    const float* __restrict__ hrs, const float* __restrict__ pool,
    float* __restrict__ med)
{
    __shared__ float red[256];
    int b = blockIdx.x, f = threadIdx.x;
    float v0 = hrs[(size_t)b * 256 + f];
    float v1 = pool[(size_t)b * 256 + f];
    red[f] = v0 * v0 + v1 * v1;
    __syncthreads();
    for (int s = 128; s > 0; s >>= 1) {
        if (f < s) red[f] += red[f + s];
        __syncthreads();
    }
    float inv = rsqrtf(red[0]);
    med[(size_t)b * 512 + f]       = v0 * inv;
    med[(size_t)b * 512 + 256 + f] = v1 * inv;
}

// ---------------------- thresholded-similarity GCN -------------------------
__global__ __launch_bounds__(256) void dinv_k(const float* __restrict__ mo,
                                              float* __restrict__ dinv)
{
    __shared__ int red[256];
    int i = blockIdx.x, t = threadIdx.x;
    int c = 0;
    for (int j = t; j < 512; j += 256) c += (mo[(size_t)i * 512 + j] >= 0.9f) ? 1 : 0;
    red[t] = c; __syncthreads();
    for (int s = 128; s > 0; s >>= 1) {
        if (t < s) red[t] += red[t + s];
        __syncthreads();
    }
    if (t == 0) dinv[i] = rsqrtf((float)red[0]);
}

__global__ __launch_bounds__(256) void nadj_k(const float* __restrict__ mo,
                                              const float* __restrict__ dinv,
                                              float* __restrict__ nadj)
{
    int i = blockIdx.x, t = threadIdx.x;
    float di = dinv[i];
    for (int j = t; j < 512; j += 256) {
        float a = (mo[(size_t)i * 512 + j] >= 0.9f || j == i) ? 1.f : 0.f;
        nadj[(size_t)i * 512 + j] = a * di * dinv[j];
    }
}

// ------------------------------ GAT pieces ---------------------------------
// u[k,h] = sum_t W_in[k, h*256+t]*al[h,t];  v[k,h] same with ar.
__global__ __launch_bounds__(256) void uv_k(const float* __restrict__ W,
                                            const float* __restrict__ al,
                                            const float* __restrict__ ar,
                                            float* __restrict__ u,
                                            float* __restrict__ v)
{
    int k = threadIdx.x;
    for (int h = 0; h < 3; ++h) {
        float su = 0.f, sv = 0.f;
        for (int t = 0; t < 256; ++t) {
            float w = W[(size_t)k * 768 + h * 256 + t];
            su += w * al[h * 256 + t];
            sv += w * ar[h * 256 + t];
        }
        u[k * 3 + h] = su;
        v[k * 3 + h] = sv;
    }
}

__global__ __launch_bounds__(256) void er_k(const float* __restrict__ ph,
                                            const float* __restrict__ v,
                                            float* __restrict__ er)
{
    int id = blockIdx.x * 256 + threadIdx.x;
    if (id >= B_PAR * 3) return;
    int b = id / 3, h = id % 3;
    float s = 0.f;
    for (int k = 0; k < 256; ++k) s += ph[(size_t)b * 256 + k] * v[k * 3 + h];
    er[id] = s;
}

// Per-parcel: el = pp@u, e = leaky(el+er), softmax over 200 nodes/head,
// q[b,h,:] = sum_n alpha[n,h] * pp[n,:]
__global__ __launch_bounds__(256) void gat_poi2img_k(
    const float* __restrict__ pp, const float* __restrict__ u,
    const float* __restrict__ er, float* __restrict__ q)
{
    __shared__ float esh[600];
    __shared__ float ash[600];
    __shared__ float ush[768];
    __shared__ float mz[8];
    const int p = blockIdx.x, tid = threadIdx.x;
    const size_t base = (size_t)p * P_NODES;

    for (int i = tid; i < 768; i += 256) ush[i] = u[i];
    __syncthreads();

    for (int it = tid; it < 600; it += 256) {
        int n = it / 3, h = it % 3;
        const float* row = pp + (base + n) * HIDF;
        float s = 0.f;
        for (int k = 0; k < 256; ++k) s += row[k] * ush[k * 3 + h];
        s += er[p * 3 + h];
        esh[it] = s > 0.f ? s : 0.2f * s;      // leaky_relu
    }
    __syncthreads();

    int wave = tid >> 6, lane = tid & 63;
    if (wave < 3) {
        float mx = -1e30f;
        for (int n = lane; n < P_NODES; n += 64) mx = fmaxf(mx, esh[n * 3 + wave]);
        for (int o = 32; o > 0; o >>= 1) mx = fmaxf(mx, __shfl_xor(mx, o));
        float sm = 0.f;
        for (int n = lane; n < P_NODES; n += 64) sm += expf(esh[n * 3 + wave] - mx);
        for (int o = 32; o > 0; o >>= 1) sm += __shfl_xor(sm, o);
        if (lane == 0) { mz[wave] = mx; mz[4 + wave] = sm; }
    }
    __syncthreads();

    for (int it = tid; it < 600; it += 256) {
        int h = it % 3;
        ash[it] = expf(esh[it] - mz[h]) / (mz[4 + h] + 1e-9f);
    }
    __syncthreads();

    // tid == feature index
    float a0 = 0.f, a1 = 0.f, a2 = 0.f;
    for (int n = 0; n < P_NODES; ++n) {
        float vv = pp[(base + n) * HIDF + tid];
        a0 += ash[n * 3 + 0] * vv;
        a1 += ash[n * 3 + 1] * vv;
        a2 += ash[n * 3 + 2] * vv;
    }
    q[((size_t)p * 3 + 0) * 256 + tid] = a0;
    q[((size_t)p * 3 + 1) * 256 + tid] = a1;
    q[((size_t)p * 3 + 2) * 256 + tid] = a2;
}

// poi2img[b,j] = (1/3) sum_h q[b,h,:] . W_in[:, h*256+j]
__global__ __launch_bounds__(256) void qgemm_k(const float* __restrict__ q,
                                               const float* __restrict__ W,
                                               float* __restrict__ out)
{
    __shared__ float qs[768];
    int b = blockIdx.x, j = threadIdx.x;
    for (int i = j; i < 768; i += 256) qs[i] = q[(size_t)b * 768 + i];
    __syncthreads();
    float acc = 0.f;
    for (int h = 0; h < 3; ++h)
        for (int k = 0; k < 256; ++k)
            acc += qs[h * 256 + k] * W[(size_t)k * 768 + h * 256 + j];
    out[(size_t)b * 256 + j] = acc * (1.f / 3.f);
}

// Wm[k,j] = mean_h W_with[k, h*256+j] * 1/(1+1e-9)
__global__ __launch_bounds__(256) void wm_k(const float* __restrict__ W,
                                            float* __restrict__ Wm)
{
    int id = blockIdx.x * 256 + threadIdx.x;
    int k = id >> 8, j = id & 255;
    const float c = (1.f / 3.f) * (1.f / (1.f + 1e-9f));
    Wm[id] = (W[(size_t)k * 768 + j] + W[(size_t)k * 768 + 256 + j] +
              W[(size_t)k * 768 + 512 + j]) * c;
}

// --------------------------- final projection ------------------------------
__global__ __launch_bounds__(256) void final_k(
    const float* __restrict__ i2p, const float* __restrict__ poi_agg,
    const float* __restrict__ poi2img, const float* __restrict__ hrs_agg,
    const float* __restrict__ Wfc, const float* __restrict__ bfc,
    float* __restrict__ out)
{
    int id = blockIdx.x * 256 + threadIdx.x;
    if (id >= B_PAR * 12) return;
    int b = id / 12, o = id % 12;
    float acc = bfc[o];
    const float* srcs[4] = { i2p, poi_agg, poi2img, hrs_agg };
    for (int s = 0; s < 4; ++s) {
        const float* r = srcs[s] + (size_t)b * 256;
        for (int k = 0; k < 256; ++k)
            acc += r[k] * Wfc[(size_t)(s * 256 + k) * 12 + o];
    }
    out[id] = acc;
}

// ---------------------------------------------------------------------------
extern "C" void kernel_launch(void* const* d_in, const int* in_sizes, int n_in,
                              void* d_out, int out_size, void* d_ws, size_t ws_size,
                              hipStream_t stream)
{
    const float* g_poi = (const float*)d_in[0];
    const float* img   = (const float*)d_in[1];
    const int*   esrc  = (const int*)d_in[2];
    const int*   edst  = (const int*)d_in[3];
    const float* W1    = (const float*)d_in[4];
    const float* b1    = (const float*)d_in[5];
    const float* W2    = (const float*)d_in[6];
    const float* b2    = (const float*)d_in[7];
    const float* Whrs  = (const float*)d_in[8];
    const float* bhrs  = (const float*)d_in[9];
    const float* Wph   = (const float*)d_in[10];
    const float* bph   = (const float*)d_in[11];
    const float* Wpp   = (const float*)d_in[12];
    const float* bpp   = (const float*)d_in[13];
    const float* Wgin  = (const float*)d_in[14];
    const float* alin  = (const float*)d_in[15];
    const float* arin  = (const float*)d_in[16];
    const float* Wgw   = (const float*)d_in[17];
    // d_in[18], d_in[19] (al_with, ar_with) are numerically dead: every poi
    // node has exactly one incoming parcel edge -> softmax weight is 1/(1+1e-9).
    const float* Whg   = (const float*)d_in[20];
    const float* Wpg   = (const float*)d_in[21];
    const float* Wfc   = (const float*)d_in[22];
    const float* bfc   = (const float*)d_in[23];

    float* out      = (float*)d_out;            // [512*12] then [512*512]
    float* med_out  = out + B_PAR * 12;

    char* ws = (char*)d_ws;
    size_t off = 0;
    auto take = [&](size_t bytes) { void* p = ws + off; off += (bytes + 255) & ~(size_t)255; return p; };
    const size_t SZ_NF = (size_t)N_NODES * HIDF * sizeof(float);   // 100 MiB

    float*         bufA  = (float*)take(SZ_NF);
    float*         bufB  = (float*)take(SZ_NF);
    int*           deg   = (int*)take((size_t)N_NODES * 4);
    float*         nrm   = (float*)take((size_t)N_NODES * 4);
    unsigned char* csr   = (unsigned char*)take((size_t)N_NODES * CSR_CAP);
    float*         hrs   = (float*)take((size_t)B_PAR * 256 * 4);
    float*         pool  = (float*)take((size_t)B_PAR * 256 * 4);
    float*         medn  = (float*)take((size_t)B_PAR * 512 * 4);
    float*         dinv  = (float*)take((size_t)B_PAR * 4);
    float*         nadj  = (float*)take((size_t)B_PAR * 512 * 4);
    float*         t_h   = (float*)take((size_t)B_PAR * 256 * 4);
    float*         t_p   = (float*)take((size_t)B_PAR * 256 * 4);
    float*         hagg  = (float*)take((size_t)B_PAR * 256 * 4);
    float*         pagg  = (float*)take((size_t)B_PAR * 256 * 4);
    float*         ph    = (float*)take((size_t)B_PAR * 256 * 4);
    float*         u_in  = (float*)take(768 * 4);
    float*         v_in  = (float*)take(768 * 4);
    float*         er    = (float*)take((size_t)B_PAR * 3 * 4);
    float*         q     = (float*)take((size_t)B_PAR * 768 * 4);
    float*         p2i   = (float*)take((size_t)B_PAR * 256 * 4);
    float*         Wm    = (float*)take((size_t)256 * 256 * 4);
    float*         i2p   = (float*)take((size_t)B_PAR * 256 * 4);
    (void)ws_size; (void)in_sizes; (void)n_in; (void)out_size;

    // ---- graph preprocessing ----
    hipMemsetAsync(deg, 0, (size_t)N_NODES * 4, stream);
    build_csr_k<<<E_EDGES / 256, 256, 0, stream>>>(esrc, edst, deg, csr);
    norm_k<<<N_NODES / 256, 256, 0, stream>>>(deg, nrm);

    // ---- GCN layer 1: X1 = relu(agg((X@W1)*nrm)*nrm + b1) ----
    gemm_f32<false, true, false, false, false>
        <<<dim3(4, N_NODES / 64), 256, 0, stream>>>(g_poi, W1, bufA,
            N_NODES, 256, 64, nrm, nullptr);
    gcn_agg_k<<<B_PAR, 256, 0, stream>>>(bufA, bufB, deg, csr, nrm, b1, 1);

    // ---- GCN layer 2: poi_nodes = agg((X1@W2)*nrm)*nrm + b2 ----
    gemm_f32<false, true, false, false, false>
        <<<dim3(4, N_NODES / 64), 256, 0, stream>>>(bufB, W2, bufA,
            N_NODES, 256, 256, nrm, nullptr);
    gcn_agg_k<<<B_PAR, 256, 0, stream>>>(bufA, bufB, deg, csr, nrm, b2, 0);
    // bufB = poi_nodes

    pool_k<<<B_PAR, 256, 0, stream>>>(bufB, pool);

    // ---- hrs encoder ----
    gemm_f32<false, false, true, false, false>
        <<<dim3(4, 8), 256, 0, stream>>>(img, Whrs, hrs, 512, 256, 2048,
            nullptr, bhrs);

    // ---- med similarity + output 1 ----
    med_build_k<<<B_PAR, 256, 0, stream>>>(hrs, pool, medn);
    gemm_f32<true, false, false, false, true>
        <<<dim3(8, 8), 256, 0, stream>>>(medn, medn, med_out, 512, 512, 512,
            nullptr, nullptr);

    // ---- UniSimGraph GCN on thresholded adjacency ----
    dinv_k<<<B_PAR, 256, 0, stream>>>(med_out, dinv);
    nadj_k<<<B_PAR, 256, 0, stream>>>(med_out, dinv, nadj);
    gemm_f32<false, false, false, false, false>
        <<<dim3(4, 8), 256, 0, stream>>>(hrs, Whg, t_h, 512, 256, 256,
            nullptr, nullptr);
    gemm_f32<false, false, false, false, false>
        <<<dim3(4, 8), 256, 0, stream>>>(pool, Wpg, t_p, 512, 256, 256,
            nullptr, nullptr);
    gemm_f32<false, false, false, true, false>
        <<<dim3(4, 8), 256, 0, stream>>>(nadj, t_h, hagg, 512, 256, 512,
            nullptr, nullptr);
    gemm_f32<false, false, false, true, false>
        <<<dim3(4, 8), 256, 0, stream>>>(nadj, t_p, pagg, 512, 256, 512,
            nullptr, nullptr);

    // ---- projections ----
    gemm_f32<false, false, true, false, false>
        <<<dim3(4, 8), 256, 0, stream>>>(hrs, Wph, ph, 512, 256, 256,
            nullptr, bph);
    gemm_f32<false, false, true, false, false>
        <<<dim3(4, N_NODES / 64), 256, 0, stream>>>(bufB, Wpp, bufA,
            N_NODES, 256, 256, nullptr, bpp);
    // bufA = pp

    // ---- GAT poi2img (attention-pooled, fs never materialized) ----
    uv_k<<<1, 256, 0, stream>>>(Wgin, alin, arin, u_in, v_in);
    er_k<<<6, 256, 0, stream>>>(ph, v_in, er);
    gat_poi2img_k<<<B_PAR, 256, 0, stream>>>(bufA, u_in, er, q);
    qgemm_k<<<B_PAR, 256, 0, stream>>>(q, Wgin, p2i);

    // ---- img2poi (degenerate attention) pooled ----
    wm_k<<<256, 256, 0, stream>>>(Wgw, Wm);
    gemm_f32<false, false, false, false, false>
        <<<dim3(4, 8), 256, 0, stream>>>(ph, Wm, i2p, 512, 256, 256,
            nullptr, nullptr);

    // ---- final fc: output 0 ----
    final_k<<<24, 256, 0, stream>>>(i2p, pagg, p2i, hagg, Wfc, bfc, out);
}

// Round 2
// 816.415 us; speedup vs baseline: 1.9643x; 1.9643x over previous
//
#include <hip/hip_runtime.h>
#include <hip/hip_bf16.h>
#include <math.h>

// ---------------------------------------------------------------------------
// NGLU: B=512 parcels x P=200 poi nodes. N=102400, E=1638400, HID=256.
// Round 1: all N-sized work on MFMA (bf16, f32 accum).
//  - transforms: 128x128 tile, BK=64, XOR-swizzled LDS, mfma_f32_16x16x32_bf16
//  - GCN aggregation: dense per-parcel adjacency (u8 multiplicity counts ->
//    bf16, zero-padded to [512][256][256]) GEMM'd against parcel-padded Y.
// Region aliasing (stream-ordered): regionA = u8 counts -> Ypad -> pp(bf16);
// regionB = X1 -> poi_nodes.
// ---------------------------------------------------------------------------

#define N_NODES 102400
#define B_PAR   512
#define P_NODES 200
#define E_EDGES 1638400
#define HIDF    256

typedef __attribute__((ext_vector_type(8))) short bf16x8;
typedef __attribute__((ext_vector_type(4))) float f32x4;

__device__ __forceinline__ unsigned short f2bf(float x) {
    unsigned u = __builtin_bit_cast(unsigned, x);
    u += 0x7fffu + ((u >> 16) & 1u);               // RNE (finite data only)
    return (unsigned short)(u >> 16);
}
__device__ __forceinline__ float bf2f(unsigned short h) {
    return __builtin_bit_cast(float, (unsigned)h << 16);
}
// LDS tile [128 rows][64 k] bf16 = 128B/row; 16B-chunk XOR swizzle so that
// 16 lanes reading the same chunk of 16 different rows hit 8 bank-quads
// (2-way aliasing = free per m136).
__device__ __forceinline__ int lds_off(int row, int kbyte) {
    return row * 128 + ((((kbyte >> 4) ^ (row & 7)) << 4) | (kbyte & 15));
}

// ------------------------- MFMA transform GEMM -----------------------------
// C[M,256] = A[M,K] @ Bt^T  (Bt is [256][K] bf16, pre-transposed weights)
// OMODE: 0 = f32 [M][256], 1 = bf16 [M][256], 2 = bf16 parcel-padded
//        (row g -> [g/200][g%200] of [512][256][256]).
template<bool ABF16, int OMODE, bool ROWSC, bool BIASF, bool RELUF>
__global__ __launch_bounds__(256) void mfma_gemm(
    const void* __restrict__ Ain, const unsigned short* __restrict__ Bt,
    void* __restrict__ Cout, int K,
    const float* __restrict__ rowscale, const float* __restrict__ bias)
{
    __shared__ bf16x8 smem_v[2048];                 // 32 KiB
    unsigned char* Asm = (unsigned char*)smem_v;
    unsigned char* Bsm = Asm + 16384;

    const int tid  = threadIdx.x;
    const int m0   = blockIdx.y * 128;
    const int n0   = blockIdx.x * 128;
    const int sr   = tid >> 3, sc = tid & 7;        // staging: row, 8-elem chunk
    const int lane = tid & 63;
    const int wm   = (tid >> 7) & 1, wn = (tid >> 6) & 1;
    const int frow = lane & 15;
    const int fko  = (lane >> 4) << 4;              // 0,16,32,48 bytes

    f32x4 acc[4][4];
    const f32x4 fz = {0.f, 0.f, 0.f, 0.f};
#pragma unroll
    for (int i = 0; i < 4; ++i)
#pragma unroll
        for (int j = 0; j < 4; ++j) acc[i][j] = fz;

    for (int k0 = 0; k0 < K; k0 += 64) {
        bf16x8 areg[4], breg[4];
#pragma unroll
        for (int i = 0; i < 4; ++i) {
            int row = sr + 32 * i;
            if (ABF16) {
                areg[i] = *(const bf16x8*)((const unsigned short*)Ain
                            + (size_t)(m0 + row) * K + k0 + sc * 8);
            } else {
                const float* ap = (const float*)Ain + (size_t)(m0 + row) * K + k0 + sc * 8;
                float4 lo = *(const float4*)ap;
                float4 hi = *(const float4*)(ap + 4);
                union { bf16x8 v; unsigned short u[8]; } pk;
                pk.u[0] = f2bf(lo.x); pk.u[1] = f2bf(lo.y);
                pk.u[2] = f2bf(lo.z); pk.u[3] = f2bf(lo.w);
                pk.u[4] = f2bf(hi.x); pk.u[5] = f2bf(hi.y);
                pk.u[6] = f2bf(hi.z); pk.u[7] = f2bf(hi.w);
                areg[i] = pk.v;
            }
            breg[i] = *(const bf16x8*)(Bt + (size_t)(n0 + row) * K + k0 + sc * 8);
        }
        __syncthreads();                            // prev iter's LDS readers done
#pragma unroll
        for (int i = 0; i < 4; ++i) {
            *(bf16x8*)(Asm + lds_off(sr + 32 * i, sc * 16)) = areg[i];
            *(bf16x8*)(Bsm + lds_off(sr + 32 * i, sc * 16)) = breg[i];
        }
        __syncthreads();
#pragma unroll
        for (int ks = 0; ks < 2; ++ks) {
            const int kb = ks * 64 + fko;
            bf16x8 af[4], bfr[4];
#pragma unroll
            for (int t = 0; t < 4; ++t)
                af[t] = *(const bf16x8*)(Asm + lds_off(wm * 64 + t * 16 + frow, kb));
#pragma unroll
            for (int t = 0; t < 4; ++t)
                bfr[t] = *(const bf16x8*)(Bsm + lds_off(wn * 64 + t * 16 + frow, kb));
#pragma unroll
            for (int mi = 0; mi < 4; ++mi)
#pragma unroll
                for (int ni = 0; ni < 4; ++ni)
                    acc[mi][ni] = __builtin_amdgcn_mfma_f32_16x16x32_bf16(
                        af[mi], bfr[ni], acc[mi][ni], 0, 0, 0);
        }
    }

    const int r4 = (lane >> 4) << 2;                // C/D: col=l&15, row=(l>>4)*4+j
#pragma unroll
    for (int mi = 0; mi < 4; ++mi) {
#pragma unroll
        for (int ni = 0; ni < 4; ++ni) {
            int col = n0 + wn * 64 + ni * 16 + frow;
#pragma unroll
            for (int j = 0; j < 4; ++j) {
                int g = m0 + wm * 64 + mi * 16 + r4 + j;
                float v = acc[mi][ni][j];
                if (ROWSC) v *= rowscale[g];
                if (BIASF) v += bias[col];
                if (RELUF) v = fmaxf(v, 0.f);
                if (OMODE == 0) {
                    ((float*)Cout)[(size_t)g * 256 + col] = v;
                } else if (OMODE == 1) {
                    ((unsigned short*)Cout)[(size_t)g * 256 + col] = f2bf(v);
                } else {
                    int p = g / 200, r = g - p * 200;
                    ((unsigned short*)Cout)[((size_t)p * 256 + r) * 256 + col] = f2bf(v);
                }
            }
        }
    }
}

// --------------------- MFMA aggregation (dense adjacency) ------------------
// Out[p*200+d, f] = (sum_s Adjb[p][d][s] * Ypad[p][s][f]) * nrm[g] + bias[f]
// Adjb bf16 [512][256][256] (zero-padded), Ypad bf16 [512][256][256].
// grid: (2 n-tiles, 512*2 m-tiles). Y is transposed into LDS ([f][k]) via
// scalar b16 writes; swizzle keeps read-side ds_read_b128 ~2-way.
__global__ __launch_bounds__(256) void agg_mfma(
    const unsigned short* __restrict__ Adjb, const unsigned short* __restrict__ Ypad,
    unsigned short* __restrict__ Outb,
    const float* __restrict__ nrm, const float* __restrict__ bias, int relu)
{
    __shared__ bf16x8 smem_v[2048];
    unsigned char* Asm = (unsigned char*)smem_v;
    unsigned char* Bsm = Asm + 16384;

    const int tid  = threadIdx.x;
    const int p    = blockIdx.y >> 1;
    const int mt   = blockIdx.y & 1;
    const int n0   = blockIdx.x * 128;
    const int sr   = tid >> 3, sc = tid & 7;        // A staging
    const int bk   = tid >> 2, bf4 = tid & 3;       // B staging: k-row, f-chunk base
    const int lane = tid & 63;
    const int wm   = (tid >> 7) & 1, wn = (tid >> 6) & 1;
    const int frow = lane & 15;
    const int fko  = (lane >> 4) << 4;
    const size_t abase = ((size_t)p * 256 + mt * 128) * 256;
    const size_t ybase = (size_t)p * 256 * 256;

    f32x4 acc[4][4];
    const f32x4 fz = {0.f, 0.f, 0.f, 0.f};
#pragma unroll
    for (int i = 0; i < 4; ++i)
#pragma unroll
        for (int j = 0; j < 4; ++j) acc[i][j] = fz;

    for (int k0 = 0; k0 < 256; k0 += 64) {
        bf16x8 areg[4];
        uint4  yreg[4];
#pragma unroll
        for (int i = 0; i < 4; ++i) {
            areg[i] = *(const bf16x8*)(Adjb + abase + (size_t)(sr + 32 * i) * 256 + k0 + sc * 8);
            yreg[i] = *(const uint4*)(Ypad + ybase + (size_t)(k0 + bk) * 256
                                      + n0 + (bf4 + 4 * i) * 8);
        }
        __syncthreads();
#pragma unroll
        for (int i = 0; i < 4; ++i)
            *(bf16x8*)(Asm + lds_off(sr + 32 * i, sc * 16)) = areg[i];
#pragma unroll
        for (int i = 0; i < 4; ++i) {
            union { uint4 q; unsigned short u[8]; } y; y.q = yreg[i];
            int fb = (bf4 + 4 * i) * 8;
#pragma unroll
            for (int j = 0; j < 8; ++j)
                *(unsigned short*)(Bsm + lds_off(fb + j, bk * 2)) = y.u[j];
        }
        __syncthreads();
#pragma unroll
        for (int ks = 0; ks < 2; ++ks) {
            const int kb = ks * 64 + fko;
            bf16x8 af[4], bfr[4];
#pragma unroll
            for (int t = 0; t < 4; ++t)
                af[t] = *(const bf16x8*)(Asm + lds_off(wm * 64 + t * 16 + frow, kb));
#pragma unroll
            for (int t = 0; t < 4; ++t)
                bfr[t] = *(const bf16x8*)(Bsm + lds_off(wn * 64 + t * 16 + frow, kb));
#pragma unroll
            for (int mi = 0; mi < 4; ++mi)
#pragma unroll
                for (int ni = 0; ni < 4; ++ni)
                    acc[mi][ni] = __builtin_amdgcn_mfma_f32_16x16x32_bf16(
                        af[mi], bfr[ni], acc[mi][ni], 0, 0, 0);
        }
    }

    const int r4 = (lane >> 4) << 2;
#pragma unroll
    for (int mi = 0; mi < 4; ++mi) {
#pragma unroll
        for (int ni = 0; ni < 4; ++ni) {
            int col = n0 + wn * 64 + ni * 16 + frow;
#pragma unroll
            for (int j = 0; j < 4; ++j) {
                int rl = mt * 128 + wm * 64 + mi * 16 + r4 + j;
                if (rl < 200) {
                    int g = p * 200 + rl;
                    float v = acc[mi][ni][j] * nrm[g] + bias[col];
                    if (relu) v = fmaxf(v, 0.f);
                    Outb[(size_t)g * 256 + col] = f2bf(v);
                }
            }
        }
    }
}

// ------------------------- graph preprocessing -----------------------------
__global__ __launch_bounds__(256) void diag_k(unsigned char* __restrict__ A)
{
    int id = blockIdx.x * 256 + threadIdx.x;        // 512*200
    int p = id / 200, d = id - p * 200;
    A[((size_t)(p * 256 + d) << 8) + d] = 1;        // distinct words per thread
}

__global__ __launch_bounds__(256) void edge_k(const int* __restrict__ esrc,
                                              const int* __restrict__ edst,
                                              unsigned char* __restrict__ A)
{
    int e = blockIdx.x * 256 + threadIdx.x;
    int s = esrc[e], d = edst[e];
    int p = d / 200;                                 // src,dst share parcel
    int dl = d - p * 200, sl = s - p * 200;
    size_t bo = ((size_t)(p * 256 + dl) << 8) + (unsigned)sl;
    atomicAdd((unsigned int*)(A + (bo & ~(size_t)3)), 1u << ((bo & 3) * 8));
}

__global__ __launch_bounds__(256) void norm2_k(const unsigned char* __restrict__ A,
                                               float* __restrict__ nrm)
{
    int g = blockIdx.x * 256 + threadIdx.x;          // N
    int p = g / 200, d = g - p * 200;
    const uint4* row = (const uint4*)(A + ((size_t)(p * 256 + d) << 8));
    unsigned s = 0;
#pragma unroll
    for (int i = 0; i < 16; ++i) {
        uint4 w = row[i];
        unsigned a = w.x, b = w.y, c = w.z, e = w.w;
        s += (a & 255) + ((a >> 8) & 255) + ((a >> 16) & 255) + (a >> 24);
        s += (b & 255) + ((b >> 8) & 255) + ((b >> 16) & 255) + (b >> 24);
        s += (c & 255) + ((c >> 8) & 255) + ((c >> 16) & 255) + (c >> 24);
        s += (e & 255) + ((e >> 8) & 255) + ((e >> 16) & 255) + (e >> 24);
    }
    nrm[g] = rsqrtf((float)s);                       // row-sum = in-deg + self
}

__global__ __launch_bounds__(256) void cvt_adj_k(const unsigned char* __restrict__ A8,
                                                 unsigned short* __restrict__ Ab)
{
    size_t id = (size_t)blockIdx.x * 256 + threadIdx.x;  // 4194304 total
    const unsigned int* wp = (const unsigned int*)(A8 + id * 8);
    unsigned w0 = wp[0], w1 = wp[1];
    union { uint4 q; unsigned short u[8]; } o;
    o.u[0] = f2bf((float)(w0 & 255));  o.u[1] = f2bf((float)((w0 >> 8) & 255));
    o.u[2] = f2bf((float)((w0 >> 16) & 255)); o.u[3] = f2bf((float)(w0 >> 24));
    o.u[4] = f2bf((float)(w1 & 255));  o.u[5] = f2bf((float)((w1 >> 8) & 255));
    o.u[6] = f2bf((float)((w1 >> 16) & 255)); o.u[7] = f2bf((float)(w1 >> 24));
    *(uint4*)(Ab + id * 8) = o.q;
}

// W [K][256] f32 -> Wt [256][K] bf16
__global__ __launch_bounds__(256) void wprep_k(const float* __restrict__ W,
                                               unsigned short* __restrict__ Wt, int K)
{
    int id = blockIdx.x * 256 + threadIdx.x;
    if (id >= 256 * K) return;
    int n = id / K, k = id - n * K;
    Wt[id] = f2bf(W[(size_t)k * 256 + n]);
}

// ---------------------------- generic f32 GEMM ----------------------------
// (unchanged round-0 kernel for the small B-sized GEMMs)
template<bool TRANSB, bool ROWSCALE, bool BIAS, bool RELU, bool MEDOUT>
__global__ __launch_bounds__(256) void gemm_f32(
    const float* __restrict__ A, const float* __restrict__ B,
    float* __restrict__ C, int M, int Nc, int K,
    const float* __restrict__ rowscale, const float* __restrict__ bias)
{
    __shared__ float As[16][64];
    __shared__ float Bs[16][64];
    const int tid = threadIdx.x;
    const int m0 = blockIdx.y * 64;
    const int n0 = blockIdx.x * 64;
    const int tm = tid >> 4, tn = tid & 15;
    const int lrow = tid >> 2, lkb = (tid & 3) << 2;
    const int bk = tid >> 4, bc = (tid & 15) << 2;
    float acc[4][4] = {};

    for (int k0 = 0; k0 < K; k0 += 16) {
        float4 av = *(const float4*)(A + (size_t)(m0 + lrow) * K + k0 + lkb);
        As[lkb + 0][lrow] = av.x;
        As[lkb + 1][lrow] = av.y;
        As[lkb + 2][lrow] = av.z;
        As[lkb + 3][lrow] = av.w;
        if (TRANSB) {
            float4 bv = *(const float4*)(B + (size_t)(n0 + lrow) * K + k0 + lkb);
            Bs[lkb + 0][lrow] = bv.x;
            Bs[lkb + 1][lrow] = bv.y;
            Bs[lkb + 2][lrow] = bv.z;
            Bs[lkb + 3][lrow] = bv.w;
        } else {
            float4 bv = *(const float4*)(B + (size_t)(k0 + bk) * Nc + n0 + bc);
            Bs[bk][bc + 0] = bv.x;
            Bs[bk][bc + 1] = bv.y;
            Bs[bk][bc + 2] = bv.z;
            Bs[bk][bc + 3] = bv.w;
        }
        __syncthreads();
#pragma unroll
        for (int k = 0; k < 16; ++k) {
            float a[4], b[4];
#pragma unroll
            for (int i = 0; i < 4; ++i) a[i] = As[k][tm * 4 + i];
#pragma unroll
            for (int j = 0; j < 4; ++j) b[j] = Bs[k][tn * 4 + j];
#pragma unroll
            for (int i = 0; i < 4; ++i)
#pragma unroll
                for (int j = 0; j < 4; ++j)
                    acc[i][j] += a[i] * b[j];
        }
        __syncthreads();
    }

#pragma unroll
    for (int i = 0; i < 4; ++i) {
        int row = m0 + tm * 4 + i;
        float rs = ROWSCALE ? rowscale[row] : 1.f;
        float v[4];
#pragma unroll
        for (int j = 0; j < 4; ++j) {
            float x = acc[i][j];
            if (ROWSCALE) x *= rs;
            if (BIAS)     x += bias[n0 + tn * 4 + j];
            if (RELU)     x = fmaxf(x, 0.f);
            if (MEDOUT)   x = (x + 1.f) * 0.5f;
            v[j] = x;
        }
        float4 o; o.x = v[0]; o.y = v[1]; o.z = v[2]; o.w = v[3];
        *(float4*)(C + (size_t)row * Nc + n0 + tn * 4) = o;
    }
}

// ------------------------------ pooling (bf16 in) ---------------------------
__global__ __launch_bounds__(256) void pool_k(const unsigned short* __restrict__ X,
                                              float* __restrict__ Pl)
{
    int b = blockIdx.x, f = threadIdx.x;
    size_t base = (size_t)b * P_NODES * HIDF;
    float s = 0.f;
    for (int n = 0; n < P_NODES; ++n) s += bf2f(X[base + (size_t)n * HIDF + f]);
    Pl[(size_t)b * HIDF + f] = s * (1.f / 200.f);
}

// ------------------- med = rownorm(concat(hrs, pool)) ----------------------
__global__ __launch_bounds__(256) void med_build_k(
    const float* __restrict__ hrs, const float* __restrict__ pool,
    float* __restrict__ med)
{
    __shared__ float red[256];
    int b = blockIdx.x, f = threadIdx.x;
    float v0 = hrs[(size_t)b * 256 + f];
    float v1 = pool[(size_t)b * 256 + f];
    red[f] = v0 * v0 + v1 * v1;
    __syncthreads();
    for (int s = 128; s > 0; s >>= 1) {
        if (f < s) red[f] += red[f + s];
        __syncthreads();
    }
    float inv = rsqrtf(red[0]);
    med[(size_t)b * 512 + f]       = v0 * inv;
    med[(size_t)b * 512 + 256 + f] = v1 * inv;
}

// ---------------------- thresholded-similarity GCN -------------------------
__global__ __launch_bounds__(256) void dinv_k(const float* __restrict__ mo,
                                              float* __restrict__ dinv)
{
    __shared__ int red[256];
    int i = blockIdx.x, t = threadIdx.x;
    int c = 0;
    for (int j = t; j < 512; j += 256) c += (mo[(size_t)i * 512 + j] >= 0.9f) ? 1 : 0;
    red[t] = c; __syncthreads();
    for (int s = 128; s > 0; s >>= 1) {
        if (t < s) red[t] += red[t + s];
        __syncthreads();
    }
    if (t == 0) dinv[i] = rsqrtf((float)red[0]);
}

__global__ __launch_bounds__(256) void nadj_k(const float* __restrict__ mo,
                                              const float* __restrict__ dinv,
                                              float* __restrict__ nadj)
{
    int i = blockIdx.x, t = threadIdx.x;
    float di = dinv[i];
    for (int j = t; j < 512; j += 256) {
        float a = (mo[(size_t)i * 512 + j] >= 0.9f || j == i) ? 1.f : 0.f;
        nadj[(size_t)i * 512 + j] = a * di * dinv[j];
    }
}

// ------------------------------ GAT pieces ---------------------------------
__global__ __launch_bounds__(256) void uv_k(const float* __restrict__ W,
                                            const float* __restrict__ al,
                                            const float* __restrict__ ar,
                                            float* __restrict__ u,
                                            float* __restrict__ v)
{
    int k = threadIdx.x;
    for (int h = 0; h < 3; ++h) {
        float su = 0.f, sv = 0.f;
        for (int t = 0; t < 256; ++t) {
            float w = W[(size_t)k * 768 + h * 256 + t];
            su += w * al[h * 256 + t];
            sv += w * ar[h * 256 + t];
        }
        u[k * 3 + h] = su;
        v[k * 3 + h] = sv;
    }
}

__global__ __launch_bounds__(256) void er_k(const float* __restrict__ ph,
                                            const float* __restrict__ v,
                                            float* __restrict__ er)
{
    int id = blockIdx.x * 256 + threadIdx.x;
    if (id >= B_PAR * 3) return;
    int b = id / 3, h = id % 3;
    float s = 0.f;
    for (int k = 0; k < 256; ++k) s += ph[(size_t)b * 256 + k] * v[k * 3 + h];
    er[id] = s;
}

// pp now bf16
__global__ __launch_bounds__(256) void gat_poi2img_k(
    const unsigned short* __restrict__ pp, const float* __restrict__ u,
    const float* __restrict__ er, float* __restrict__ q)
{
    __shared__ float esh[600];
    __shared__ float ash[600];
    __shared__ float ush[768];
    __shared__ float mz[8];
    const int p = blockIdx.x, tid = threadIdx.x;
    const size_t base = (size_t)p * P_NODES;

    for (int i = tid; i < 768; i += 256) ush[i] = u[i];
    __syncthreads();

    for (int it = tid; it < 600; it += 256) {
        int n = it / 3, h = it % 3;
        const unsigned short* row = pp + (base + n) * HIDF;
        float s = 0.f;
        for (int k = 0; k < 256; k += 8) {
            union { uint4 qv; unsigned short us[8]; } w;
            w.qv = *(const uint4*)(row + k);
#pragma unroll
            for (int j = 0; j < 8; ++j) s += bf2f(w.us[j]) * ush[(k + j) * 3 + h];
        }
        s += er[p * 3 + h];
        esh[it] = s > 0.f ? s : 0.2f * s;
    }
    __syncthreads();

    int wave = tid >> 6, lane = tid & 63;
    if (wave < 3) {
        float mx = -1e30f;
        for (int n = lane; n < P_NODES; n += 64) mx = fmaxf(mx, esh[n * 3 + wave]);
        for (int o = 32; o > 0; o >>= 1) mx = fmaxf(mx, __shfl_xor(mx, o));
        float sm = 0.f;
        for (int n = lane; n < P_NODES; n += 64) sm += expf(esh[n * 3 + wave] - mx);
        for (int o = 32; o > 0; o >>= 1) sm += __shfl_xor(sm, o);
        if (lane == 0) { mz[wave] = mx; mz[4 + wave] = sm; }
    }
    __syncthreads();

    for (int it = tid; it < 600; it += 256) {
        int h = it % 3;
        ash[it] = expf(esh[it] - mz[h]) / (mz[4 + h] + 1e-9f);
    }
    __syncthreads();

    float a0 = 0.f, a1 = 0.f, a2 = 0.f;
    for (int n = 0; n < P_NODES; ++n) {
        float vv = bf2f(pp[(base + n) * HIDF + tid]);
        a0 += ash[n * 3 + 0] * vv;
        a1 += ash[n * 3 + 1] * vv;
        a2 += ash[n * 3 + 2] * vv;
    }
    q[((size_t)p * 3 + 0) * 256 + tid] = a0;
    q[((size_t)p * 3 + 1) * 256 + tid] = a1;
    q[((size_t)p * 3 + 2) * 256 + tid] = a2;
}

__global__ __launch_bounds__(256) void qgemm_k(const float* __restrict__ q,
                                               const float* __restrict__ W,
                                               float* __restrict__ out)
{
    __shared__ float qs[768];
    int b = blockIdx.x, j = threadIdx.x;
    for (int i = j; i < 768; i += 256) qs[i] = q[(size_t)b * 768 + i];
    __syncthreads();
    float acc = 0.f;
    for (int h = 0; h < 3; ++h)
        for (int k = 0; k < 256; ++k)
            acc += qs[h * 256 + k] * W[(size_t)k * 768 + h * 256 + j];
    out[(size_t)b * 256 + j] = acc * (1.f / 3.f);
}

__global__ __launch_bounds__(256) void wm_k(const float* __restrict__ W,
                                            float* __restrict__ Wm)
{
    int id = blockIdx.x * 256 + threadIdx.x;
    int k = id >> 8, j = id & 255;
    const float c = (1.f / 3.f) * (1.f / (1.f + 1e-9f));
    Wm[id] = (W[(size_t)k * 768 + j] + W[(size_t)k * 768 + 256 + j] +
              W[(size_t)k * 768 + 512 + j]) * c;
}

// --------------------------- final projection ------------------------------
__global__ __launch_bounds__(256) void final_k(
    const float* __restrict__ i2p, const float* __restrict__ poi_agg,
    const float* __restrict__ poi2img, const float* __restrict__ hrs_agg,
    const float* __restrict__ Wfc, const float* __restrict__ bfc,
    float* __restrict__ out)
{
    int id = blockIdx.x * 256 + threadIdx.x;
    if (id >= B_PAR * 12) return;
    int b = id / 12, o = id % 12;
    float acc = bfc[o];
    const float* srcs[4] = { i2p, poi_agg, poi2img, hrs_agg };
    for (int s = 0; s < 4; ++s) {
        const float* r = srcs[s] + (size_t)b * 256;
        for (int k = 0; k < 256; ++k)
            acc += r[k] * Wfc[(size_t)(s * 256 + k) * 12 + o];
    }
    out[id] = acc;
}

// ---------------------------------------------------------------------------
extern "C" void kernel_launch(void* const* d_in, const int* in_sizes, int n_in,
                              void* d_out, int out_size, void* d_ws, size_t ws_size,
                              hipStream_t stream)
{
    const float* g_poi = (const float*)d_in[0];
    const float* img   = (const float*)d_in[1];
    const int*   esrc  = (const int*)d_in[2];
    const int*   edst  = (const int*)d_in[3];
    const float* W1    = (const float*)d_in[4];
    const float* b1    = (const float*)d_in[5];
    const float* W2    = (const float*)d_in[6];
    const float* b2    = (const float*)d_in[7];
    const float* Whrs  = (const float*)d_in[8];
    const float* bhrs  = (const float*)d_in[9];
    const float* Wph   = (const float*)d_in[10];
    const float* bph   = (const float*)d_in[11];
    const float* Wpp   = (const float*)d_in[12];
    const float* bpp   = (const float*)d_in[13];
    const float* Wgin  = (const float*)d_in[14];
    const float* alin  = (const float*)d_in[15];
    const float* arin  = (const float*)d_in[16];
    const float* Wgw   = (const float*)d_in[17];
    // d_in[18]/d_in[19] (al_with/ar_with) numerically dead: each poi node has
    // exactly one incoming parcel edge -> edge-softmax weight = 1/(1+1e-9).
    const float* Whg   = (const float*)d_in[20];
    const float* Wpg   = (const float*)d_in[21];
    const float* Wfc   = (const float*)d_in[22];
    const float* bfc   = (const float*)d_in[23];

    float* out     = (float*)d_out;
    float* med_out = out + B_PAR * 12;

    char* ws = (char*)d_ws;
    size_t off = 0;
    auto take = [&](size_t bytes) { void* pv = ws + off; off += (bytes + 255) & ~(size_t)255; return pv; };

    const size_t SZ_PAD2 = (size_t)B_PAR * 256 * 256 * 2;   // 67.1 MB
    // regionA: u8 adjacency counts -> Ypad (bf16 padded) -> pp (bf16 flat)
    unsigned char*  regionA = (unsigned char*)take(SZ_PAD2);
    unsigned char*  adj8 = regionA;                          // [512][256][256] u8
    unsigned short* Ypad = (unsigned short*)regionA;         // [512][256][256] bf16
    unsigned short* ppb  = (unsigned short*)regionA;         // [N][256] bf16
    unsigned short* Adjb = (unsigned short*)take(SZ_PAD2);   // bf16 adjacency
    // regionB: X1 (relu'd gcn1) -> poi_nodes, both bf16 [N][256]
    unsigned short* PNX  = (unsigned short*)take((size_t)N_NODES * 256 * 2);
    unsigned short* X1   = PNX;
    unsigned short* PN   = PNX;

    unsigned short* W1t  = (unsigned short*)take(256 * 64 * 2);
    unsigned short* W2t  = (unsigned short*)take(256 * 256 * 2);
    unsigned short* Wppt = (unsigned short*)take(256 * 256 * 2);
    float* nrm  = (float*)take((size_t)N_NODES * 4);
    float* hrs  = (float*)take((size_t)B_PAR * 256 * 4);
    float* pool = (float*)take((size_t)B_PAR * 256 * 4);
    float* medn = (float*)take((size_t)B_PAR * 512 * 4);
    float* dinv = (float*)take((size_t)B_PAR * 4);
    float* nadj = (float*)take((size_t)B_PAR * 512 * 4);
    float* t_h  = (float*)take((size_t)B_PAR * 256 * 4);
    float* t_p  = (float*)take((size_t)B_PAR * 256 * 4);
    float* hagg = (float*)take((size_t)B_PAR * 256 * 4);
    float* pagg = (float*)take((size_t)B_PAR * 256 * 4);
    float* ph   = (float*)take((size_t)B_PAR * 256 * 4);
    float* u_in = (float*)take(768 * 4);
    float* v_in = (float*)take(768 * 4);
    float* er   = (float*)take((size_t)B_PAR * 3 * 4);
    float* q    = (float*)take((size_t)B_PAR * 768 * 4);
    float* p2i  = (float*)take((size_t)B_PAR * 256 * 4);
    float* Wm   = (float*)take((size_t)256 * 256 * 4);
    float* i2p  = (float*)take((size_t)B_PAR * 256 * 4);
    (void)ws_size; (void)in_sizes; (void)n_in; (void)out_size;

    // ---- adjacency build (u8 multiplicity counts, deterministic int atomics)
    hipMemsetAsync(adj8, 0, (size_t)B_PAR * 256 * 256, stream);
    diag_k<<<400, 256, 0, stream>>>(adj8);
    edge_k<<<E_EDGES / 256, 256, 0, stream>>>(esrc, edst, adj8);
    norm2_k<<<N_NODES / 256, 256, 0, stream>>>(adj8, nrm);
    cvt_adj_k<<<16384, 256, 0, stream>>>(adj8, Adjb);   // last read of adj8

    // ---- weight prep (transpose + bf16) ----
    wprep_k<<<64, 256, 0, stream>>>(W1, W1t, 64);
    wprep_k<<<256, 256, 0, stream>>>(W2, W2t, 256);
    wprep_k<<<256, 256, 0, stream>>>(Wpp, Wppt, 256);

    // ---- GCN layer 1 ----
    mfma_gemm<false, 2, true, false, false>
        <<<dim3(2, 800), 256, 0, stream>>>(g_poi, W1t, Ypad, 64, nrm, nullptr);
    agg_mfma<<<dim3(2, 1024), 256, 0, stream>>>(Adjb, Ypad, X1, nrm, b1, 1);

    // ---- GCN layer 2 ----
    mfma_gemm<true, 2, true, false, false>
        <<<dim3(2, 800), 256, 0, stream>>>(X1, W2t, Ypad, 256, nrm, nullptr);
    agg_mfma<<<dim3(2, 1024), 256, 0, stream>>>(Adjb, Ypad, PN, nrm, b2, 0);

    pool_k<<<B_PAR, 256, 0, stream>>>(PN, pool);

    // ---- hrs encoder ----
    gemm_f32<false, false, true, false, false>
        <<<dim3(4, 8), 256, 0, stream>>>(img, Whrs, hrs, 512, 256, 2048,
            nullptr, bhrs);

    // ---- med similarity + output 1 ----
    med_build_k<<<B_PAR, 256, 0, stream>>>(hrs, pool, medn);
    gemm_f32<true, false, false, false, true>
        <<<dim3(8, 8), 256, 0, stream>>>(medn, medn, med_out, 512, 512, 512,
            nullptr, nullptr);

    // ---- UniSimGraph GCN ----
    dinv_k<<<B_PAR, 256, 0, stream>>>(med_out, dinv);
    nadj_k<<<B_PAR, 256, 0, stream>>>(med_out, dinv, nadj);
    gemm_f32<false, false, false, false, false>
        <<<dim3(4, 8), 256, 0, stream>>>(hrs, Whg, t_h, 512, 256, 256,
            nullptr, nullptr);
    gemm_f32<false, false, false, false, false>
        <<<dim3(4, 8), 256, 0, stream>>>(pool, Wpg, t_p, 512, 256, 256,
            nullptr, nullptr);
    gemm_f32<false, false, false, true, false>
        <<<dim3(4, 8), 256, 0, stream>>>(nadj, t_h, hagg, 512, 256, 512,
            nullptr, nullptr);
    gemm_f32<false, false, false, true, false>
        <<<dim3(4, 8), 256, 0, stream>>>(nadj, t_p, pagg, 512, 256, 512,
            nullptr, nullptr);

    // ---- projections ----
    gemm_f32<false, false, true, false, false>
        <<<dim3(4, 8), 256, 0, stream>>>(hrs, Wph, ph, 512, 256, 256,
            nullptr, bph);
    // pp = poi_nodes @ Wpp + bpp (bf16 out, overwrites dead Ypad region)
    mfma_gemm<true, 1, false, true, false>
        <<<dim3(2, 800), 256, 0, stream>>>(PN, Wppt, ppb, 256, nullptr, bpp);

    // ---- GAT poi2img ----
    uv_k<<<1, 256, 0, stream>>>(Wgin, alin, arin, u_in, v_in);
    er_k<<<6, 256, 0, stream>>>(ph, v_in, er);
    gat_poi2img_k<<<B_PAR, 256, 0, stream>>>(ppb, u_in, er, q);
    qgemm_k<<<B_PAR, 256, 0, stream>>>(q, Wgin, p2i);

    // ---- img2poi (degenerate attention) pooled ----
    wm_k<<<256, 256, 0, stream>>>(Wgw, Wm);
    gemm_f32<false, false, false, false, false>
        <<<dim3(4, 8), 256, 0, stream>>>(ph, Wm, i2p, 512, 256, 256,
            nullptr, nullptr);

    // ---- final fc ----
    final_k<<<24, 256, 0, stream>>>(i2p, pagg, p2i, hagg, Wfc, bfc, out);
}

// Round 3
// 577.334 us; speedup vs baseline: 2.7778x; 1.4141x over previous
//
#include <hip/hip_runtime.h>
#include <hip/hip_bf16.h>
#include <math.h>

// ---------------------------------------------------------------------------
// NGLU: B=512 parcels x P=200 poi nodes. N=102400, E=1638400, HID=256.
// Round 2: everything matmul-shaped on one generic 128x128 bf16-MFMA kernel
// (split-K for K=2048), u8 adjacency consumed directly by agg MFMA,
// transposed-Y layout so no LDS transpose anywhere, small-GEMM fusions
// (Tcat, hp_agg, ph eliminated via weight folding).
// ---------------------------------------------------------------------------

#define N_NODES 102400
#define B_PAR   512
#define P_NODES 200
#define E_EDGES 1638400
#define HIDF    256

typedef __attribute__((ext_vector_type(8))) short bf16x8;
typedef __attribute__((ext_vector_type(4))) float f32x4;

__device__ __forceinline__ unsigned short f2bf(float x) {
    unsigned u = __builtin_bit_cast(unsigned, x);
    u += 0x7fffu + ((u >> 16) & 1u);               // RNE (finite data only)
    return (unsigned short)(u >> 16);
}
__device__ __forceinline__ float bf2f(unsigned short h) {
    return __builtin_bit_cast(float, (unsigned)h << 16);
}
// LDS tile [128 rows][64 k] bf16 = 128B/row; 16B-chunk XOR swizzle.
__device__ __forceinline__ int lds_off(int row, int kbyte) {
    return row * 128 + ((((kbyte >> 4) ^ (row & 7)) << 4) | (kbyte & 15));
}
template<bool BF16SRC>
__device__ __forceinline__ bf16x8 load_row8(const void* p, size_t elemoff) {
    if constexpr (BF16SRC) {
        return *(const bf16x8*)((const unsigned short*)p + elemoff);
    } else {
        const float* ap = (const float*)p + elemoff;
        float4 lo = *(const float4*)ap;
        float4 hi = *(const float4*)(ap + 4);
        union { bf16x8 v; unsigned short u[8]; } pk;
        pk.u[0] = f2bf(lo.x); pk.u[1] = f2bf(lo.y);
        pk.u[2] = f2bf(lo.z); pk.u[3] = f2bf(lo.w);
        pk.u[4] = f2bf(hi.x); pk.u[5] = f2bf(hi.y);
        pk.u[6] = f2bf(hi.z); pk.u[7] = f2bf(hi.w);
        return pk.v;
    }
}
__device__ __forceinline__ bf16x8 u8x8_to_bf16(uint2 w) {
    union { bf16x8 v; unsigned short u[8]; } r;
#pragma unroll
    for (int b = 0; b < 4; ++b) {
        r.u[b]     = (unsigned short)(__builtin_bit_cast(unsigned,
                        (float)((w.x >> (8 * b)) & 255u)) >> 16);   // exact: ints<256
        r.u[4 + b] = (unsigned short)(__builtin_bit_cast(unsigned,
                        (float)((w.y >> (8 * b)) & 255u)) >> 16);
    }
    return r.v;
}

// --------------------------- generic MFMA GEMM ------------------------------
// D[M,Nc] = alpha * A[M,K] @ Bt[Nc,K]^T (+scale/bias/relu/med epilogue)
// OMODE: 0=f32 [M][Nc], 1=bf16 [M][Nc], 2=bf16 parcel-transposed
//        (row=f, col=g -> Yt[g/200][f][g%200] of [512][256][256]).
// SCMODE: 0 none, 1 scale[row], 2 scale[col].  KCHUNK>0: split-K partials.
template<bool ABF16, bool BBF16, int OMODE, int SCMODE, bool BIASF, bool RELUF,
         bool MEDOUT, int KCHUNK>
__global__ __launch_bounds__(256) void mm_k(
    const void* __restrict__ Ain, const void* __restrict__ Bin,
    void* __restrict__ Cout, int M, int Nc, int K,
    const float* __restrict__ scale, const float* __restrict__ bias, float alpha)
{
    __shared__ bf16x8 smem_v[2048];                 // 32 KiB
    unsigned char* Asm = (unsigned char*)smem_v;
    unsigned char* Bsm = Asm + 16384;

    const int tid  = threadIdx.x;
    const int m0   = blockIdx.y * 128;
    const int n0   = blockIdx.x * 128;
    const int sr   = tid >> 3, sc = tid & 7;
    const int lane = tid & 63;
    const int wm   = (tid >> 7) & 1, wn = (tid >> 6) & 1;
    const int frow = lane & 15;
    const int fko  = (lane >> 4) << 4;

    int kbeg = 0, kend = K;
    float* Cf = (float*)Cout;
    if (KCHUNK > 0) {
        kbeg = blockIdx.z * KCHUNK; kend = kbeg + KCHUNK;
        Cf += (size_t)blockIdx.z * M * Nc;
    }

    f32x4 acc[4][4];
    const f32x4 fz = {0.f, 0.f, 0.f, 0.f};
#pragma unroll
    for (int i = 0; i < 4; ++i)
#pragma unroll
        for (int j = 0; j < 4; ++j) acc[i][j] = fz;

    for (int k0 = kbeg; k0 < kend; k0 += 64) {
        bf16x8 areg[4], breg[4];
#pragma unroll
        for (int i = 0; i < 4; ++i) {
            int row = sr + 32 * i;
            areg[i] = load_row8<ABF16>(Ain, (size_t)(m0 + row) * K + k0 + sc * 8);
            breg[i] = load_row8<BBF16>(Bin, (size_t)(n0 + row) * K + k0 + sc * 8);
        }
        __syncthreads();
#pragma unroll
        for (int i = 0; i < 4; ++i) {
            *(bf16x8*)(Asm + lds_off(sr + 32 * i, sc * 16)) = areg[i];
            *(bf16x8*)(Bsm + lds_off(sr + 32 * i, sc * 16)) = breg[i];
        }
        __syncthreads();
#pragma unroll
        for (int ks = 0; ks < 2; ++ks) {
            const int kb = ks * 64 + fko;
            bf16x8 af[4], bfr[4];
#pragma unroll
            for (int t = 0; t < 4; ++t)
                af[t] = *(const bf16x8*)(Asm + lds_off(wm * 64 + t * 16 + frow, kb));
#pragma unroll
            for (int t = 0; t < 4; ++t)
                bfr[t] = *(const bf16x8*)(Bsm + lds_off(wn * 64 + t * 16 + frow, kb));
#pragma unroll
            for (int mi = 0; mi < 4; ++mi)
#pragma unroll
                for (int ni = 0; ni < 4; ++ni)
                    acc[mi][ni] = __builtin_amdgcn_mfma_f32_16x16x32_bf16(
                        af[mi], bfr[ni], acc[mi][ni], 0, 0, 0);
        }
    }

    const int r4 = (lane >> 4) << 2;                // C/D: col=l&15, row=(l>>4)*4+j
#pragma unroll
    for (int mi = 0; mi < 4; ++mi) {
#pragma unroll
        for (int ni = 0; ni < 4; ++ni) {
            int col = n0 + wn * 64 + ni * 16 + frow;
#pragma unroll
            for (int j = 0; j < 4; ++j) {
                int row = m0 + wm * 64 + mi * 16 + r4 + j;
                float v = acc[mi][ni][j] * alpha;
                if (SCMODE == 1) v *= scale[row];
                if (SCMODE == 2) v *= scale[col];
                if (BIASF)       v += bias[col];
                if (RELUF)       v = fmaxf(v, 0.f);
                if (MEDOUT)      v += 0.5f;
                if (OMODE == 0) {
                    Cf[(size_t)row * Nc + col] = v;
                } else if (OMODE == 1) {
                    ((unsigned short*)Cout)[(size_t)row * Nc + col] = f2bf(v);
                } else {
                    int p = col / 200, r = col - p * 200;
                    ((unsigned short*)Cout)[((size_t)p * 256 + row) * 256 + r] = f2bf(v);
                }
            }
        }
    }
}

// ---------------- GCN aggregation: u8 adjacency x transposed Y --------------
// Out[p*200+d][f] = (sum_s Adj[p][d][s] * Yt[p][f][s]) * nrm[g] + bias[f]
__global__ __launch_bounds__(256) void agg_k(
    const unsigned char* __restrict__ Adj, const unsigned short* __restrict__ Yt,
    unsigned short* __restrict__ Outb, const float* __restrict__ nrm,
    const float* __restrict__ bias, int relu)
{
    __shared__ bf16x8 smem_v[2048];
    unsigned char* Asm = (unsigned char*)smem_v;
    unsigned char* Bsm = Asm + 16384;

    const int tid  = threadIdx.x;
    const int p    = blockIdx.y >> 1;
    const int mt   = blockIdx.y & 1;
    const int n0   = blockIdx.x * 128;
    const int sr   = tid >> 3, sc = tid & 7;
    const int lane = tid & 63;
    const int wm   = (tid >> 7) & 1, wn = (tid >> 6) & 1;
    const int frow = lane & 15;
    const int fko  = (lane >> 4) << 4;

    f32x4 acc[4][4];
    const f32x4 fz = {0.f, 0.f, 0.f, 0.f};
#pragma unroll
    for (int i = 0; i < 4; ++i)
#pragma unroll
        for (int j = 0; j < 4; ++j) acc[i][j] = fz;

    for (int k0 = 0; k0 < 256; k0 += 64) {
        bf16x8 areg[4], breg[4];
#pragma unroll
        for (int i = 0; i < 4; ++i) {
            int row = sr + 32 * i;
            uint2 w = *(const uint2*)(Adj +
                (((size_t)(p * 256 + mt * 128 + row)) << 8) + k0 + sc * 8);
            areg[i] = u8x8_to_bf16(w);
            breg[i] = *(const bf16x8*)(Yt +
                (((size_t)(p * 256 + n0 + row)) << 8) + k0 + sc * 8);
        }
        __syncthreads();
#pragma unroll
        for (int i = 0; i < 4; ++i) {
            *(bf16x8*)(Asm + lds_off(sr + 32 * i, sc * 16)) = areg[i];
            *(bf16x8*)(Bsm + lds_off(sr + 32 * i, sc * 16)) = breg[i];
        }
        __syncthreads();
#pragma unroll
        for (int ks = 0; ks < 2; ++ks) {
            const int kb = ks * 64 + fko;
            bf16x8 af[4], bfr[4];
#pragma unroll
            for (int t = 0; t < 4; ++t)
                af[t] = *(const bf16x8*)(Asm + lds_off(wm * 64 + t * 16 + frow, kb));
#pragma unroll
            for (int t = 0; t < 4; ++t)
                bfr[t] = *(const bf16x8*)(Bsm + lds_off(wn * 64 + t * 16 + frow, kb));
#pragma unroll
            for (int mi = 0; mi < 4; ++mi)
#pragma unroll
                for (int ni = 0; ni < 4; ++ni)
                    acc[mi][ni] = __builtin_amdgcn_mfma_f32_16x16x32_bf16(
                        af[mi], bfr[ni], acc[mi][ni], 0, 0, 0);
        }
    }

    const int r4 = (lane >> 4) << 2;
#pragma unroll
    for (int mi = 0; mi < 4; ++mi) {
#pragma unroll
        for (int ni = 0; ni < 4; ++ni) {
            int col = n0 + wn * 64 + ni * 16 + frow;
#pragma unroll
            for (int j = 0; j < 4; ++j) {
                int rl = mt * 128 + wm * 64 + mi * 16 + r4 + j;
                if (rl < 200) {
                    int g = p * 200 + rl;
                    float v = acc[mi][ni][j] * nrm[g] + bias[col];
                    if (relu) v = fmaxf(v, 0.f);
                    Outb[(size_t)g * 256 + col] = f2bf(v);
                }
            }
        }
    }
}

// ------------------------- graph preprocessing -----------------------------
// edges + self-loop diag, u8 multiplicity counts via packed u32 atomics
__global__ __launch_bounds__(256) void edge_diag_k(
    const int* __restrict__ esrc, const int* __restrict__ edst,
    unsigned char* __restrict__ A)
{
    int id = blockIdx.x * 256 + threadIdx.x;        // E + N = 1740800
    size_t bo;
    if (id < E_EDGES) {
        int s = esrc[id], d = edst[id];
        int p = d / 200;
        int dl = d - p * 200, sl = s - p * 200;
        bo = (((size_t)(p * 256 + dl)) << 8) + (unsigned)sl;
    } else {
        int i2 = id - E_EDGES;                      // < N
        int p = i2 / 200, d = i2 - p * 200;
        bo = (((size_t)(p * 256 + d)) << 8) + (unsigned)d;
    }
    atomicAdd((unsigned int*)(A + (bo & ~(size_t)3)), 1u << ((bo & 3) * 8));
}

__global__ __launch_bounds__(256) void norm2_k(const unsigned char* __restrict__ A,
                                               float* __restrict__ nrm)
{
    int g = blockIdx.x * 256 + threadIdx.x;
    int p = g / 200, d = g - p * 200;
    const uint4* row = (const uint4*)(A + (((size_t)(p * 256 + d)) << 8));
    unsigned s = 0;
#pragma unroll
    for (int i = 0; i < 16; ++i) {
        uint4 w = row[i];
        unsigned a = w.x, b = w.y, c = w.z, e = w.w;
        s += (a & 255) + ((a >> 8) & 255) + ((a >> 16) & 255) + (a >> 24);
        s += (b & 255) + ((b >> 8) & 255) + ((b >> 16) & 255) + (b >> 24);
        s += (c & 255) + ((c >> 8) & 255) + ((c >> 16) & 255) + (c >> 24);
        s += (e & 255) + ((e >> 8) & 255) + ((e >> 16) & 255) + (e >> 24);
    }
    nrm[g] = rsqrtf((float)s);                      // row-sum = in-deg + self
}

// ------------- all weight transposes/casts + img cast + Yt pad clear --------
__global__ __launch_bounds__(256) void prep_k(
    const float* __restrict__ W1, const float* __restrict__ W2,
    const float* __restrict__ Wpp, const float* __restrict__ Whg,
    const float* __restrict__ Wpg, const float* __restrict__ Whrs,
    const float* __restrict__ Wgin, const float* __restrict__ Wgw,
    const float* __restrict__ Wph, const float* __restrict__ img,
    unsigned short* __restrict__ W1t, unsigned short* __restrict__ W2t,
    unsigned short* __restrict__ Wppt, unsigned short* __restrict__ Whgt,
    unsigned short* __restrict__ Wpgt, unsigned short* __restrict__ Whrst,
    unsigned short* __restrict__ Wgint, unsigned short* __restrict__ Wmt,
    unsigned short* __restrict__ Wphb, unsigned short* __restrict__ imgb,
    unsigned short* __restrict__ Yt)
{
    int b = blockIdx.x, tid = threadIdx.x;
    if (b < 64) {                 // W1t [256][64]
        int id = b * 256 + tid; int n = id >> 6, k = id & 63;
        W1t[id] = f2bf(W1[(size_t)k * 256 + n]);
    } else if (b < 320) {         // W2t [256][256]
        int id = (b - 64) * 256 + tid; int n = id >> 8, k = id & 255;
        W2t[id] = f2bf(W2[(size_t)k * 256 + n]);
    } else if (b < 576) {         // Wppt
        int id = (b - 320) * 256 + tid; int n = id >> 8, k = id & 255;
        Wppt[id] = f2bf(Wpp[(size_t)k * 256 + n]);
    } else if (b < 832) {         // Whgt
        int id = (b - 576) * 256 + tid; int n = id >> 8, k = id & 255;
        Whgt[id] = f2bf(Whg[(size_t)k * 256 + n]);
    } else if (b < 1088) {        // Wpgt
        int id = (b - 832) * 256 + tid; int n = id >> 8, k = id & 255;
        Wpgt[id] = f2bf(Wpg[(size_t)k * 256 + n]);
    } else if (b < 3136) {        // Whrst [256][2048]
        int id = (b - 1088) * 256 + tid; int n = id >> 11, k = id & 2047;
        Whrst[id] = f2bf(Whrs[(size_t)k * 256 + n]);
    } else if (b < 3904) {        // Wgint [256][768], k-order = h*256+t
        int id = (b - 3136) * 256 + tid; int j = id / 768, k2 = id - j * 768;
        int t = k2 & 255, h = k2 >> 8;
        Wgint[id] = f2bf(Wgin[(size_t)t * 768 + h * 256 + j]);
    } else if (b < 4160) {        // Wmt [256 j][256 t] = mean_h Wgw / (1+1e-9)
        int id = (b - 3904) * 256 + tid; int j = id >> 8, t = id & 255;
        const float c3 = (1.f / 3.f) * (1.f / (1.f + 1e-9f));
        float s = Wgw[(size_t)t * 768 + j] + Wgw[(size_t)t * 768 + 256 + j] +
                  Wgw[(size_t)t * 768 + 512 + j];
        Wmt[id] = f2bf(s * c3);
    } else if (b < 4416) {        // Wphb cast
        int id = (b - 4160) * 256 + tid;
        Wphb[id] = f2bf(Wph[id]);
    } else if (b < 8512) {        // imgb cast [512][2048]
        int id = (b - 4416) * 256 + tid;
        imgb[id] = f2bf(img[id]);
    } else {                      // Yt pad clear: cols [200,256) of each row
        int row = (b - 8512) * 256 + tid;           // 131072 rows
        uint4 z = {0u, 0u, 0u, 0u};
        uint4* d = (uint4*)(Yt + (size_t)row * 256 + 200);
#pragma unroll
        for (int i = 0; i < 7; ++i) d[i] = z;
    }
}

// --------------------------- hrs split-K reduce -----------------------------
__global__ __launch_bounds__(256) void hrs_reduce_k(
    const float* __restrict__ part, const float* __restrict__ bhrs,
    float* __restrict__ hrs, unsigned short* __restrict__ hrsb)
{
    int id = blockIdx.x * 256 + threadIdx.x;        // 131072
    float s = bhrs[id & 255];
#pragma unroll
    for (int z = 0; z < 16; ++z) s += part[(size_t)z * 131072 + id];
    hrs[id] = s;
    hrsb[id] = f2bf(s);
}

// ------------------------------ pooling ------------------------------------
__global__ __launch_bounds__(256) void pool_k(const unsigned short* __restrict__ X,
                                              float* __restrict__ Pl,
                                              unsigned short* __restrict__ Plb)
{
    int b = blockIdx.x, f = threadIdx.x;
    size_t base = (size_t)b * P_NODES * HIDF;
    float s = 0.f;
    for (int n = 0; n < P_NODES; ++n) s += bf2f(X[base + (size_t)n * HIDF + f]);
    s *= (1.f / 200.f);
    Pl[(size_t)b * HIDF + f] = s;
    Plb[(size_t)b * HIDF + f] = f2bf(s);
}

// ------------------- med = rownorm(concat(hrs, pool)) -----------------------
__global__ __launch_bounds__(256) void med_build_k(
    const float* __restrict__ hrs, const float* __restrict__ pool,
    unsigned short* __restrict__ medb)
{
    __shared__ float red[256];
    int b = blockIdx.x, f = threadIdx.x;
    float v0 = hrs[(size_t)b * 256 + f];
    float v1 = pool[(size_t)b * 256 + f];
    red[f] = v0 * v0 + v1 * v1;
    __syncthreads();
    for (int s = 128; s > 0; s >>= 1) {
        if (f < s) red[f] += red[f + s];
        __syncthreads();
    }
    float inv = rsqrtf(red[0]);
    medb[(size_t)b * 512 + f]       = f2bf(v0 * inv);
    medb[(size_t)b * 512 + 256 + f] = f2bf(v1 * inv);
}

// ---------------------- thresholded-similarity GCN --------------------------
__global__ __launch_bounds__(256) void dinv_k(const float* __restrict__ mo,
                                              float* __restrict__ dinv)
{
    __shared__ int red[256];
    int i = blockIdx.x, t = threadIdx.x;
    int c = 0;
    for (int j = t; j < 512; j += 256) c += (mo[(size_t)i * 512 + j] >= 0.9f) ? 1 : 0;
    red[t] = c; __syncthreads();
    for (int s = 128; s > 0; s >>= 1) {
        if (t < s) red[t] += red[t + s];
        __syncthreads();
    }
    if (t == 0) dinv[i] = rsqrtf((float)red[0]);
}

__global__ __launch_bounds__(256) void nadj_k(const float* __restrict__ mo,
                                              const float* __restrict__ dinv,
                                              unsigned short* __restrict__ nadjb)
{
    int i = blockIdx.x, t = threadIdx.x;
    float di = dinv[i];
    for (int j = t; j < 512; j += 256) {
        float a = (mo[(size_t)i * 512 + j] >= 0.9f || j == i) ? 1.f : 0.f;
        nadjb[(size_t)i * 512 + j] = f2bf(a * di * dinv[j]);
    }
}

// ------------------------------ GAT pieces ----------------------------------
// u[k,h] from (Wgin,al); v -> vv2[c,h]=Wph@v, erb[h]=bph.v, bc[j]=bph.Wm[:,j]
__global__ __launch_bounds__(256) void uv_k(
    const float* __restrict__ Wgin, const float* __restrict__ al,
    const float* __restrict__ ar, const float* __restrict__ Wph,
    const float* __restrict__ bph, const unsigned short* __restrict__ Wmt,
    float* __restrict__ u, float* __restrict__ vv2,
    float* __restrict__ erb, float* __restrict__ bc)
{
    __shared__ float vsh[768];
    int k = threadIdx.x;
#pragma unroll
    for (int h = 0; h < 3; ++h) {
        float su = 0.f, sv = 0.f;
        for (int t = 0; t < 256; ++t) {
            float w = Wgin[(size_t)k * 768 + h * 256 + t];
            su += w * al[h * 256 + t];
            sv += w * ar[h * 256 + t];
        }
        u[k * 3 + h] = su;
        vsh[k * 3 + h] = sv;
    }
    __syncthreads();
    float a0 = 0.f, a1 = 0.f, a2 = 0.f, s = 0.f;
    for (int t = 0; t < 256; ++t) {
        float w = Wph[(size_t)k * 256 + t];
        a0 += w * vsh[t * 3 + 0];
        a1 += w * vsh[t * 3 + 1];
        a2 += w * vsh[t * 3 + 2];
        s  += bph[t] * bf2f(Wmt[(size_t)k * 256 + t]);   // bc[k]=sum_t bph[t]Wm[t][k]
    }
    vv2[k * 3 + 0] = a0; vv2[k * 3 + 1] = a1; vv2[k * 3 + 2] = a2;
    bc[k] = s;
    if (k < 3) {
        float e = 0.f;
        for (int t = 0; t < 256; ++t) e += bph[t] * vsh[t * 3 + k];
        erb[k] = e;
    }
}

__global__ __launch_bounds__(256) void er_k(const float* __restrict__ hrs,
                                            const float* __restrict__ vv2,
                                            const float* __restrict__ erb,
                                            float* __restrict__ er)
{
    int id = blockIdx.x * 256 + threadIdx.x;
    if (id >= B_PAR * 3) return;
    int b = id / 3, h = id % 3;
    float s = erb[h];
    for (int k = 0; k < 256; ++k) s += hrs[(size_t)b * 256 + k] * vv2[k * 3 + h];
    er[id] = s;
}

// Per-parcel: el = pp@u, e = leaky(el+er), softmax over 200 nodes/head,
// q[b,h,:] = sum_n alpha[n,h] * pp[n,:]
__global__ __launch_bounds__(256) void gat_poi2img_k(
    const unsigned short* __restrict__ pp, const float* __restrict__ u,
    const float* __restrict__ er, float* __restrict__ q)
{
    __shared__ float esh[600];
    __shared__ float ash[600];
    __shared__ float ush[768];
    __shared__ float mz[8];
    const int p = blockIdx.x, tid = threadIdx.x;
    const size_t base = (size_t)p * P_NODES;

    for (int i = tid; i < 768; i += 256) ush[i] = u[i];
    __syncthreads();

    for (int it = tid; it < 600; it += 256) {
        int n = it / 3, h = it % 3;
        const unsigned short* row = pp + (base + n) * HIDF;
        float s = 0.f;
        for (int k = 0; k < 256; k += 8) {
            union { uint4 qv; unsigned short us[8]; } w;
            w.qv = *(const uint4*)(row + k);
#pragma unroll
            for (int j = 0; j < 8; ++j) s += bf2f(w.us[j]) * ush[(k + j) * 3 + h];
        }
        s += er[p * 3 + h];
        esh[it] = s > 0.f ? s : 0.2f * s;
    }
    __syncthreads();

    int wave = tid >> 6, lane = tid & 63;
    if (wave < 3) {
        float mx = -1e30f;
        for (int n = lane; n < P_NODES; n += 64) mx = fmaxf(mx, esh[n * 3 + wave]);
        for (int o = 32; o > 0; o >>= 1) mx = fmaxf(mx, __shfl_xor(mx, o));
        float sm = 0.f;
        for (int n = lane; n < P_NODES; n += 64) sm += expf(esh[n * 3 + wave] - mx);
        for (int o = 32; o > 0; o >>= 1) sm += __shfl_xor(sm, o);
        if (lane == 0) { mz[wave] = mx; mz[4 + wave] = sm; }
    }
    __syncthreads();

    for (int it = tid; it < 600; it += 256) {
        int h = it % 3;
        ash[it] = expf(esh[it] - mz[h]) / (mz[4 + h] + 1e-9f);
    }
    __syncthreads();

    float a0 = 0.f, a1 = 0.f, a2 = 0.f;
    for (int n = 0; n < P_NODES; ++n) {
        float vv = bf2f(pp[(base + n) * HIDF + tid]);
        a0 += ash[n * 3 + 0] * vv;
        a1 += ash[n * 3 + 1] * vv;
        a2 += ash[n * 3 + 2] * vv;
    }
    q[((size_t)p * 3 + 0) * 256 + tid] = a0;
    q[((size_t)p * 3 + 1) * 256 + tid] = a1;
    q[((size_t)p * 3 + 2) * 256 + tid] = a2;
}

// --------------------------- final projection -------------------------------
__global__ __launch_bounds__(256) void final_k(
    const float* __restrict__ i2p, const float* __restrict__ hpagg,
    const float* __restrict__ p2i,
    const float* __restrict__ Wfc, const float* __restrict__ bfc,
    float* __restrict__ out)
{
    int id = blockIdx.x * 256 + threadIdx.x;
    if (id >= B_PAR * 12) return;
    int b = id / 12, o = id % 12;
    float acc = bfc[o];
    const float* s0 = i2p + (size_t)b * 256;          // img2poi_pooled
    const float* s1 = hpagg + (size_t)b * 512 + 256;  // poi_agg
    const float* s2 = p2i + (size_t)b * 256;          // poi2img
    const float* s3 = hpagg + (size_t)b * 512;        // hrs_agg
    for (int k = 0; k < 256; ++k) {
        acc += s0[k] * Wfc[(size_t)(0 * 256 + k) * 12 + o];
        acc += s1[k] * Wfc[(size_t)(1 * 256 + k) * 12 + o];
        acc += s2[k] * Wfc[(size_t)(2 * 256 + k) * 12 + o];
        acc += s3[k] * Wfc[(size_t)(3 * 256 + k) * 12 + o];
    }
    out[id] = acc;
}

// ---------------------------------------------------------------------------
extern "C" void kernel_launch(void* const* d_in, const int* in_sizes, int n_in,
                              void* d_out, int out_size, void* d_ws, size_t ws_size,
                              hipStream_t stream)
{
    const float* g_poi = (const float*)d_in[0];
    const float* img   = (const float*)d_in[1];
    const int*   esrc  = (const int*)d_in[2];
    const int*   edst  = (const int*)d_in[3];
    const float* W1    = (const float*)d_in[4];
    const float* b1    = (const float*)d_in[5];
    const float* W2    = (const float*)d_in[6];
    const float* b2    = (const float*)d_in[7];
    const float* Whrs  = (const float*)d_in[8];
    const float* bhrs  = (const float*)d_in[9];
    const float* Wph   = (const float*)d_in[10];
    const float* bph   = (const float*)d_in[11];
    const float* Wpp   = (const float*)d_in[12];
    const float* bpp   = (const float*)d_in[13];
    const float* Wgin  = (const float*)d_in[14];
    const float* alin  = (const float*)d_in[15];
    const float* arin  = (const float*)d_in[16];
    const float* Wgw   = (const float*)d_in[17];
    // d_in[18]/d_in[19] (al_with/ar_with) numerically dead: each poi node has
    // exactly one incoming parcel edge -> edge-softmax weight = 1/(1+1e-9).
    const float* Whg   = (const float*)d_in[20];
    const float* Wpg   = (const float*)d_in[21];
    const float* Wfc   = (const float*)d_in[22];
    const float* bfc   = (const float*)d_in[23];

    float* out     = (float*)d_out;
    float* med_out = out + B_PAR * 12;

    char* ws = (char*)d_ws;
    size_t off = 0;
    auto take = [&](size_t bytes) { void* pv = ws + off; off += (bytes + 255) & ~(size_t)255; return pv; };

    unsigned char*  adj8 = (unsigned char*)take((size_t)B_PAR * 256 * 256);     // 33.6MB
    unsigned short* Yt   = (unsigned short*)take((size_t)B_PAR * 256 * 256 * 2);// 67.1MB
    unsigned short* ppb  = Yt;                       // aliases Yt after agg L2
    unsigned short* XPN  = (unsigned short*)take((size_t)N_NODES * 256 * 2);    // 52.4MB
    float*          part = (float*)take((size_t)16 * 512 * 256 * 4);            // 8.4MB

    unsigned short* W1t   = (unsigned short*)take(256 * 64 * 2);
    unsigned short* W2t   = (unsigned short*)take(256 * 256 * 2);
    unsigned short* Wppt  = (unsigned short*)take(256 * 256 * 2);
    unsigned short* Whgt  = (unsigned short*)take(256 * 256 * 2);
    unsigned short* Wpgt  = (unsigned short*)take(256 * 256 * 2);
    unsigned short* Whrst = (unsigned short*)take((size_t)256 * 2048 * 2);
    unsigned short* Wgint = (unsigned short*)take((size_t)256 * 768 * 2);
    unsigned short* Wmt   = (unsigned short*)take(256 * 256 * 2);
    unsigned short* Wphb  = (unsigned short*)take(256 * 256 * 2);
    unsigned short* WcT   = (unsigned short*)take(256 * 256 * 2);
    unsigned short* imgb  = (unsigned short*)take((size_t)512 * 2048 * 2);
    unsigned short* hrsb  = (unsigned short*)take((size_t)B_PAR * 256 * 2);
    unsigned short* poolb = (unsigned short*)take((size_t)B_PAR * 256 * 2);
    unsigned short* medb  = (unsigned short*)take((size_t)B_PAR * 512 * 2);
    unsigned short* nadjb = (unsigned short*)take((size_t)B_PAR * 512 * 2);
    unsigned short* Tcatt = (unsigned short*)take((size_t)512 * 512 * 2);
    float* nrm   = (float*)take((size_t)N_NODES * 4);
    float* hrs   = (float*)take((size_t)B_PAR * 256 * 4);
    float* pool  = (float*)take((size_t)B_PAR * 256 * 4);
    float* dinv  = (float*)take((size_t)B_PAR * 4);
    float* hpagg = (float*)take((size_t)B_PAR * 512 * 4);
    float* u_in  = (float*)take(768 * 4);
    float* vv2   = (float*)take(768 * 4);
    float* erb   = (float*)take(16);
    float* bc    = (float*)take(256 * 4);
    float* er    = (float*)take((size_t)B_PAR * 3 * 4);
    float* q     = (float*)take((size_t)B_PAR * 768 * 4);
    float* p2i   = (float*)take((size_t)B_PAR * 256 * 4);
    float* i2p   = (float*)take((size_t)B_PAR * 256 * 4);
    (void)ws_size; (void)in_sizes; (void)n_in; (void)out_size;

    // ---- preprocessing ----
    hipMemsetAsync(adj8, 0, (size_t)B_PAR * 256 * 256, stream);
    prep_k<<<9024, 256, 0, stream>>>(W1, W2, Wpp, Whg, Wpg, Whrs, Wgin, Wgw,
        Wph, img, W1t, W2t, Wppt, Whgt, Wpgt, Whrst, Wgint, Wmt, Wphb, imgb, Yt);
    edge_diag_k<<<(E_EDGES + N_NODES) / 256, 256, 0, stream>>>(esrc, edst, adj8);
    norm2_k<<<N_NODES / 256, 256, 0, stream>>>(adj8, nrm);

    // ---- hrs encoder: split-K MFMA + reduce ----
    mm_k<true, true, 0, 0, false, false, false, 128>
        <<<dim3(2, 4, 16), 256, 0, stream>>>(imgb, Whrst, part, 512, 256, 2048,
            nullptr, nullptr, 1.f);
    hrs_reduce_k<<<512, 256, 0, stream>>>(part, bhrs, hrs, hrsb);

    // ---- GAT precomputes (independent small) ----
    uv_k<<<1, 256, 0, stream>>>(Wgin, alin, arin, Wph, bph, Wmt,
                                u_in, vv2, erb, bc);
    er_k<<<6, 256, 0, stream>>>(hrs, vv2, erb, er);
    // WcT[j][c] = (Wph @ Wm)[c][j]
    mm_k<true, true, 1, 0, false, false, false, 0>
        <<<dim3(2, 2), 256, 0, stream>>>(Wmt, Wphb, WcT, 256, 256, 256,
            nullptr, nullptr, 1.f);

    // ---- GCN layer 1: Yt = (X@W1)^T * nrm[col], agg ----
    mm_k<true, false, 2, 2, false, false, false, 0>
        <<<dim3(800, 2), 256, 0, stream>>>(W1t, g_poi, Yt, 256, N_NODES, 64,
            nrm, nullptr, 1.f);
    agg_k<<<dim3(2, 1024), 256, 0, stream>>>(adj8, Yt, XPN, nrm, b1, 1);

    // ---- GCN layer 2 ----
    mm_k<true, true, 2, 2, false, false, false, 0>
        <<<dim3(800, 2), 256, 0, stream>>>(W2t, XPN, Yt, 256, N_NODES, 256,
            nrm, nullptr, 1.f);
    agg_k<<<dim3(2, 1024), 256, 0, stream>>>(adj8, Yt, XPN, nrm, b2, 0);
    // XPN = poi_nodes (bf16)

    pool_k<<<B_PAR, 256, 0, stream>>>(XPN, pool, poolb);

    // ---- med similarity (output 1) ----
    med_build_k<<<B_PAR, 256, 0, stream>>>(hrs, pool, medb);
    mm_k<true, true, 0, 0, false, false, true, 0>
        <<<dim3(4, 4), 256, 0, stream>>>(medb, medb, med_out, 512, 512, 512,
            nullptr, nullptr, 0.5f);

    // ---- UniSimGraph GCN ----
    dinv_k<<<B_PAR, 256, 0, stream>>>(med_out, dinv);
    nadj_k<<<B_PAR, 256, 0, stream>>>(med_out, dinv, nadjb);
    // Tcatt rows 0-255: t_h^T ; rows 256-511: t_p^T
    mm_k<true, true, 1, 0, false, false, false, 0>
        <<<dim3(4, 2), 256, 0, stream>>>(Whgt, hrsb, Tcatt, 256, 512, 256,
            nullptr, nullptr, 1.f);
    mm_k<true, true, 1, 0, false, false, false, 0>
        <<<dim3(4, 2), 256, 0, stream>>>(Wpgt, poolb, Tcatt + (size_t)256 * 512,
            256, 512, 256, nullptr, nullptr, 1.f);
    // [hagg | pagg] = relu(nadj @ [t_h | t_p])
    mm_k<true, true, 0, 0, false, true, false, 0>
        <<<dim3(4, 4), 256, 0, stream>>>(nadjb, Tcatt, hpagg, 512, 512, 512,
            nullptr, nullptr, 1.f);

    // ---- pp projection (overwrites dead Yt region) ----
    mm_k<true, true, 1, 0, true, false, false, 0>
        <<<dim3(2, 800), 256, 0, stream>>>(XPN, Wppt, ppb, N_NODES, 256, 256,
            nullptr, bpp, 1.f);

    // ---- GAT poi2img ----
    gat_poi2img_k<<<B_PAR, 256, 0, stream>>>(ppb, u_in, er, q);
    mm_k<false, true, 0, 0, false, false, false, 0>
        <<<dim3(2, 4), 256, 0, stream>>>(q, Wgint, p2i, 512, 256, 768,
            nullptr, nullptr, 1.f / 3.f);

    // ---- img2poi pooled: i2p = hrs @ Wc + bc ----
    mm_k<true, true, 0, 0, true, false, false, 0>
        <<<dim3(2, 4), 256, 0, stream>>>(hrsb, WcT, i2p, 512, 256, 256,
            nullptr, bc, 1.f);

    // ---- final fc ----
    final_k<<<24, 256, 0, stream>>>(i2p, hpagg, p2i, Wfc, bfc, out);
}

// Round 4
// 532.634 us; speedup vs baseline: 3.0109x; 1.0839x over previous
//
#include <hip/hip_runtime.h>
#include <hip/hip_bf16.h>
#include <math.h>

// ---------------------------------------------------------------------------
// NGLU: B=512 parcels x P=200 poi nodes. N=102400, E=1638400, HID=256.
// Round 3: register-prefetch pipelining in the big MFMA kernels (agg_k, mm_k),
// 64x64-tile mm64_k for all B-sized GEMMs (incl. split-K hrs), vectorized
// pool, Yt pad-clear dropped (Anorm structural zeros annihilate pad garbage).
// ---------------------------------------------------------------------------

#define N_NODES 102400
#define B_PAR   512
#define P_NODES 200
#define E_EDGES 1638400
#define HIDF    256

typedef __attribute__((ext_vector_type(8))) short bf16x8;
typedef __attribute__((ext_vector_type(4))) float f32x4;

__device__ __forceinline__ unsigned short f2bf(float x) {
    unsigned u = __builtin_bit_cast(unsigned, x);
    u += 0x7fffu + ((u >> 16) & 1u);               // RNE (finite data only)
    return (unsigned short)(u >> 16);
}
__device__ __forceinline__ float bf2f(unsigned short h) {
    return __builtin_bit_cast(float, (unsigned)h << 16);
}
// LDS tile [rows][64 k] bf16 = 128B/row; 16B-chunk XOR swizzle.
__device__ __forceinline__ int lds_off(int row, int kbyte) {
    return row * 128 + ((((kbyte >> 4) ^ (row & 7)) << 4) | (kbyte & 15));
}
template<bool BF16SRC>
__device__ __forceinline__ bf16x8 load_row8(const void* p, size_t elemoff) {
    if constexpr (BF16SRC) {
        return *(const bf16x8*)((const unsigned short*)p + elemoff);
    } else {
        const float* ap = (const float*)p + elemoff;
        float4 lo = *(const float4*)ap;
        float4 hi = *(const float4*)(ap + 4);
        union { bf16x8 v; unsigned short u[8]; } pk;
        pk.u[0] = f2bf(lo.x); pk.u[1] = f2bf(lo.y);
        pk.u[2] = f2bf(lo.z); pk.u[3] = f2bf(lo.w);
        pk.u[4] = f2bf(hi.x); pk.u[5] = f2bf(hi.y);
        pk.u[6] = f2bf(hi.z); pk.u[7] = f2bf(hi.w);
        return pk.v;
    }
}
__device__ __forceinline__ bf16x8 u8x8_to_bf16(uint2 w) {
    union { bf16x8 v; unsigned short u[8]; } r;
#pragma unroll
    for (int b = 0; b < 4; ++b) {
        r.u[b]     = (unsigned short)(__builtin_bit_cast(unsigned,
                        (float)((w.x >> (8 * b)) & 255u)) >> 16);   // exact: ints<256
        r.u[4 + b] = (unsigned short)(__builtin_bit_cast(unsigned,
                        (float)((w.y >> (8 * b)) & 255u)) >> 16);
    }
    return r.v;
}

// --------------------------- 128x128 MFMA GEMM ------------------------------
// D[M,Nc] = alpha * A[M,K] @ Bt[Nc,K]^T (+scale/bias/relu epilogue)
// OMODE: 0=f32 [M][Nc], 1=bf16 [M][Nc], 2=bf16 parcel-transposed
//        (row=f, col=g -> Yt[g/200][f][g%200] of [512][256][256]).
// SCMODE: 0 none, 1 scale[row], 2 scale[col].
template<bool ABF16, bool BBF16, int OMODE, int SCMODE, bool BIASF, bool RELUF,
         bool MEDOUT>
__global__ __launch_bounds__(256) void mm_k(
    const void* __restrict__ Ain, const void* __restrict__ Bin,
    void* __restrict__ Cout, int M, int Nc, int K,
    const float* __restrict__ scale, const float* __restrict__ bias, float alpha)
{
    __shared__ bf16x8 smem_v[2048];                 // 32 KiB
    unsigned char* Asm = (unsigned char*)smem_v;
    unsigned char* Bsm = Asm + 16384;

    const int tid  = threadIdx.x;
    const int m0   = blockIdx.y * 128;
    const int n0   = blockIdx.x * 128;
    const int sr   = tid >> 3, sc = tid & 7;
    const int lane = tid & 63;
    const int wm   = (tid >> 7) & 1, wn = (tid >> 6) & 1;
    const int frow = lane & 15;
    const int fko  = (lane >> 4) << 4;

    f32x4 acc[4][4];
    const f32x4 fz = {0.f, 0.f, 0.f, 0.f};
#pragma unroll
    for (int i = 0; i < 4; ++i)
#pragma unroll
        for (int j = 0; j < 4; ++j) acc[i][j] = fz;

    bf16x8 areg[4], breg[4];
    auto load_tiles = [&](int k0) {
#pragma unroll
        for (int i = 0; i < 4; ++i) {
            int row = sr + 32 * i;
            areg[i] = load_row8<ABF16>(Ain, (size_t)(m0 + row) * K + k0 + sc * 8);
            breg[i] = load_row8<BBF16>(Bin, (size_t)(n0 + row) * K + k0 + sc * 8);
        }
    };

    load_tiles(0);
    for (int k0 = 0; k0 < K; k0 += 64) {
        __syncthreads();                            // prev iter's LDS readers done
#pragma unroll
        for (int i = 0; i < 4; ++i) {
            *(bf16x8*)(Asm + lds_off(sr + 32 * i, sc * 16)) = areg[i];
            *(bf16x8*)(Bsm + lds_off(sr + 32 * i, sc * 16)) = breg[i];
        }
        __syncthreads();
        if (k0 + 64 < K) load_tiles(k0 + 64);       // prefetch next (overlaps MFMA)
#pragma unroll
        for (int ks = 0; ks < 2; ++ks) {
            const int kb = ks * 64 + fko;
            bf16x8 af[4], bfr[4];
#pragma unroll
            for (int t = 0; t < 4; ++t)
                af[t] = *(const bf16x8*)(Asm + lds_off(wm * 64 + t * 16 + frow, kb));
#pragma unroll
            for (int t = 0; t < 4; ++t)
                bfr[t] = *(const bf16x8*)(Bsm + lds_off(wn * 64 + t * 16 + frow, kb));
#pragma unroll
            for (int mi = 0; mi < 4; ++mi)
#pragma unroll
                for (int ni = 0; ni < 4; ++ni)
                    acc[mi][ni] = __builtin_amdgcn_mfma_f32_16x16x32_bf16(
                        af[mi], bfr[ni], acc[mi][ni], 0, 0, 0);
        }
    }

    const int r4 = (lane >> 4) << 2;                // C/D: col=l&15, row=(l>>4)*4+j
#pragma unroll
    for (int mi = 0; mi < 4; ++mi) {
#pragma unroll
        for (int ni = 0; ni < 4; ++ni) {
            int col = n0 + wn * 64 + ni * 16 + frow;
#pragma unroll
            for (int j = 0; j < 4; ++j) {
                int row = m0 + wm * 64 + mi * 16 + r4 + j;
                float v = acc[mi][ni][j] * alpha;
                if (SCMODE == 1) v *= scale[row];
                if (SCMODE == 2) v *= scale[col];
                if (BIASF)       v += bias[col];
                if (RELUF)       v = fmaxf(v, 0.f);
                if (MEDOUT)      v += 0.5f;
                if (OMODE == 0) {
                    ((float*)Cout)[(size_t)row * Nc + col] = v;
                } else if (OMODE == 1) {
                    ((unsigned short*)Cout)[(size_t)row * Nc + col] = f2bf(v);
                } else {
                    int p = col / 200, r = col - p * 200;
                    ((unsigned short*)Cout)[((size_t)p * 256 + row) * 256 + r] = f2bf(v);
                }
            }
        }
    }
}

// ----------------------- 64x64 MFMA GEMM (small shapes) ---------------------
// Same math as mm_k; BM=BN=64, 4 waves, 16KB LDS -> many blocks for tiny GEMMs.
// KCHUNK>0: split-K, partials at Cout + z*M*Nc (f32, OMODE must be 0).
template<bool ABF16, bool BBF16, int OMODE, bool BIASF, bool RELUF,
         bool MEDOUT, int KCHUNK>
__global__ __launch_bounds__(256) void mm64_k(
    const void* __restrict__ Ain, const void* __restrict__ Bin,
    void* __restrict__ Cout, int M, int Nc, int K,
    const float* __restrict__ bias, float alpha)
{
    __shared__ bf16x8 smem_v[1024];                 // 16 KiB
    unsigned char* Asm = (unsigned char*)smem_v;
    unsigned char* Bsm = Asm + 8192;

    const int tid  = threadIdx.x;
    const int m0   = blockIdx.y * 64;
    const int n0   = blockIdx.x * 64;
    const int sr   = tid >> 3, sc = tid & 7;        // sr in [0,32)
    const int lane = tid & 63;
    const int wm   = (tid >> 7) & 1, wn = (tid >> 6) & 1;
    const int frow = lane & 15;
    const int fko  = (lane >> 4) << 4;

    int kbeg = 0, kend = K;
    float* Cf = (float*)Cout;
    if (KCHUNK > 0) {
        kbeg = blockIdx.z * KCHUNK; kend = kbeg + KCHUNK;
        Cf += (size_t)blockIdx.z * M * Nc;
    }

    f32x4 acc[2][2];
    const f32x4 fz = {0.f, 0.f, 0.f, 0.f};
#pragma unroll
    for (int i = 0; i < 2; ++i)
#pragma unroll
        for (int j = 0; j < 2; ++j) acc[i][j] = fz;

    bf16x8 areg[2], breg[2];
    auto load_tiles = [&](int k0) {
#pragma unroll
        for (int i = 0; i < 2; ++i) {
            int row = sr + 32 * i;
            areg[i] = load_row8<ABF16>(Ain, (size_t)(m0 + row) * K + k0 + sc * 8);
            breg[i] = load_row8<BBF16>(Bin, (size_t)(n0 + row) * K + k0 + sc * 8);
        }
    };

    load_tiles(kbeg);
    for (int k0 = kbeg; k0 < kend; k0 += 64) {
        __syncthreads();
#pragma unroll
        for (int i = 0; i < 2; ++i) {
            *(bf16x8*)(Asm + lds_off(sr + 32 * i, sc * 16)) = areg[i];
            *(bf16x8*)(Bsm + lds_off(sr + 32 * i, sc * 16)) = breg[i];
        }
        __syncthreads();
        if (k0 + 64 < kend) load_tiles(k0 + 64);
#pragma unroll
        for (int ks = 0; ks < 2; ++ks) {
            const int kb = ks * 64 + fko;
            bf16x8 af[2], bfr[2];
#pragma unroll
            for (int t = 0; t < 2; ++t)
                af[t] = *(const bf16x8*)(Asm + lds_off(wm * 32 + t * 16 + frow, kb));
#pragma unroll
            for (int t = 0; t < 2; ++t)
                bfr[t] = *(const bf16x8*)(Bsm + lds_off(wn * 32 + t * 16 + frow, kb));
#pragma unroll
            for (int mi = 0; mi < 2; ++mi)
#pragma unroll
                for (int ni = 0; ni < 2; ++ni)
                    acc[mi][ni] = __builtin_amdgcn_mfma_f32_16x16x32_bf16(
                        af[mi], bfr[ni], acc[mi][ni], 0, 0, 0);
        }
    }

    const int r4 = (lane >> 4) << 2;
#pragma unroll
    for (int mi = 0; mi < 2; ++mi) {
#pragma unroll
        for (int ni = 0; ni < 2; ++ni) {
            int col = n0 + wn * 32 + ni * 16 + frow;
#pragma unroll
            for (int j = 0; j < 4; ++j) {
                int row = m0 + wm * 32 + mi * 16 + r4 + j;
                float v = acc[mi][ni][j] * alpha;
                if (BIASF)  v += bias[col];
                if (RELUF)  v = fmaxf(v, 0.f);
                if (MEDOUT) v += 0.5f;
                if (OMODE == 0) {
                    Cf[(size_t)row * Nc + col] = v;
                } else {
                    ((unsigned short*)Cout)[(size_t)row * Nc + col] = f2bf(v);
                }
            }
        }
    }
}

// ---------------- GCN aggregation: u8 adjacency x transposed Y --------------
// Out[p*200+d][f] = (sum_s Adj[p][d][s] * Yt[p][f][s]) * nrm[g] + bias[f]
__global__ __launch_bounds__(256) void agg_k(
    const unsigned char* __restrict__ Adj, const unsigned short* __restrict__ Yt,
    unsigned short* __restrict__ Outb, const float* __restrict__ nrm,
    const float* __restrict__ bias, int relu)
{
    __shared__ bf16x8 smem_v[2048];
    unsigned char* Asm = (unsigned char*)smem_v;
    unsigned char* Bsm = Asm + 16384;

    const int tid  = threadIdx.x;
    const int p    = blockIdx.y >> 1;
    const int mt   = blockIdx.y & 1;
    const int n0   = blockIdx.x * 128;
    const int sr   = tid >> 3, sc = tid & 7;
    const int lane = tid & 63;
    const int wm   = (tid >> 7) & 1, wn = (tid >> 6) & 1;
    const int frow = lane & 15;
    const int fko  = (lane >> 4) << 4;

    f32x4 acc[4][4];
    const f32x4 fz = {0.f, 0.f, 0.f, 0.f};
#pragma unroll
    for (int i = 0; i < 4; ++i)
#pragma unroll
        for (int j = 0; j < 4; ++j) acc[i][j] = fz;

    uint2  awreg[4];
    bf16x8 breg[4];
    auto load_tiles = [&](int k0) {
#pragma unroll
        for (int i = 0; i < 4; ++i) {
            int row = sr + 32 * i;
            awreg[i] = *(const uint2*)(Adj +
                (((size_t)(p * 256 + mt * 128 + row)) << 8) + k0 + sc * 8);
            breg[i] = *(const bf16x8*)(Yt +
                (((size_t)(p * 256 + n0 + row)) << 8) + k0 + sc * 8);
        }
    };

    load_tiles(0);
#pragma unroll
    for (int t4 = 0; t4 < 4; ++t4) {
        __syncthreads();
#pragma unroll
        for (int i = 0; i < 4; ++i) {
            *(bf16x8*)(Asm + lds_off(sr + 32 * i, sc * 16)) = u8x8_to_bf16(awreg[i]);
            *(bf16x8*)(Bsm + lds_off(sr + 32 * i, sc * 16)) = breg[i];
        }
        __syncthreads();
        if (t4 < 3) load_tiles((t4 + 1) * 64);      // prefetch overlaps MFMA
#pragma unroll
        for (int ks = 0; ks < 2; ++ks) {
            const int kb = ks * 64 + fko;
            bf16x8 af[4], bfr[4];
#pragma unroll
            for (int t = 0; t < 4; ++t)
                af[t] = *(const bf16x8*)(Asm + lds_off(wm * 64 + t * 16 + frow, kb));
#pragma unroll
            for (int t = 0; t < 4; ++t)
                bfr[t] = *(const bf16x8*)(Bsm + lds_off(wn * 64 + t * 16 + frow, kb));
#pragma unroll
            for (int mi = 0; mi < 4; ++mi)
#pragma unroll
                for (int ni = 0; ni < 4; ++ni)
                    acc[mi][ni] = __builtin_amdgcn_mfma_f32_16x16x32_bf16(
                        af[mi], bfr[ni], acc[mi][ni], 0, 0, 0);
        }
    }

    const int r4 = (lane >> 4) << 2;
#pragma unroll
    for (int mi = 0; mi < 4; ++mi) {
#pragma unroll
        for (int ni = 0; ni < 4; ++ni) {
            int col = n0 + wn * 64 + ni * 16 + frow;
#pragma unroll
            for (int j = 0; j < 4; ++j) {
                int rl = mt * 128 + wm * 64 + mi * 16 + r4 + j;
                if (rl < 200) {
                    int g = p * 200 + rl;
                    float v = acc[mi][ni][j] * nrm[g] + bias[col];
                    if (relu) v = fmaxf(v, 0.f);
                    Outb[(size_t)g * 256 + col] = f2bf(v);
                }
            }
        }
    }
}

// ------------------------- graph preprocessing -----------------------------
__global__ __launch_bounds__(256) void edge_diag_k(
    const int* __restrict__ esrc, const int* __restrict__ edst,
    unsigned char* __restrict__ A)
{
    int id = blockIdx.x * 256 + threadIdx.x;        // E + N = 1740800
    size_t bo;
    if (id < E_EDGES) {
        int s = esrc[id], d = edst[id];
        int p = d / 200;
        int dl = d - p * 200, sl = s - p * 200;
        bo = (((size_t)(p * 256 + dl)) << 8) + (unsigned)sl;
    } else {
        int i2 = id - E_EDGES;                      // < N
        int p = i2 / 200, d = i2 - p * 200;
        bo = (((size_t)(p * 256 + d)) << 8) + (unsigned)d;
    }
    atomicAdd((unsigned int*)(A + (bo & ~(size_t)3)), 1u << ((bo & 3) * 8));
}

__global__ __launch_bounds__(256) void norm2_k(const unsigned char* __restrict__ A,
                                               float* __restrict__ nrm)
{
    int g = blockIdx.x * 256 + threadIdx.x;
    int p = g / 200, d = g - p * 200;
    const uint4* row = (const uint4*)(A + (((size_t)(p * 256 + d)) << 8));
    unsigned s = 0;
#pragma unroll
    for (int i = 0; i < 16; ++i) {
        uint4 w = row[i];
        unsigned a = w.x, b = w.y, c = w.z, e = w.w;
        s += (a & 255) + ((a >> 8) & 255) + ((a >> 16) & 255) + (a >> 24);
        s += (b & 255) + ((b >> 8) & 255) + ((b >> 16) & 255) + (b >> 24);
        s += (c & 255) + ((c >> 8) & 255) + ((c >> 16) & 255) + (c >> 24);
        s += (e & 255) + ((e >> 8) & 255) + ((e >> 16) & 255) + (e >> 24);
    }
    nrm[g] = rsqrtf((float)s);                      // row-sum = in-deg + self
}

// ------------- all weight transposes/casts + img cast -----------------------
__global__ __launch_bounds__(256) void prep_k(
    const float* __restrict__ W1, const float* __restrict__ W2,
    const float* __restrict__ Wpp, const float* __restrict__ Whg,
    const float* __restrict__ Wpg, const float* __restrict__ Whrs,
    const float* __restrict__ Wgin, const float* __restrict__ Wgw,
    const float* __restrict__ Wph, const float* __restrict__ img,
    unsigned short* __restrict__ W1t, unsigned short* __restrict__ W2t,
    unsigned short* __restrict__ Wppt, unsigned short* __restrict__ Whgt,
    unsigned short* __restrict__ Wpgt, unsigned short* __restrict__ Whrst,
    unsigned short* __restrict__ Wgint, unsigned short* __restrict__ Wmt,
    unsigned short* __restrict__ Wphb, unsigned short* __restrict__ imgb)
{
    int b = blockIdx.x, tid = threadIdx.x;
    if (b < 64) {                 // W1t [256][64]
        int id = b * 256 + tid; int n = id >> 6, k = id & 63;
        W1t[id] = f2bf(W1[(size_t)k * 256 + n]);
    } else if (b < 320) {         // W2t [256][256]
        int id = (b - 64) * 256 + tid; int n = id >> 8, k = id & 255;
        W2t[id] = f2bf(W2[(size_t)k * 256 + n]);
    } else if (b < 576) {         // Wppt
        int id = (b - 320) * 256 + tid; int n = id >> 8, k = id & 255;
        Wppt[id] = f2bf(Wpp[(size_t)k * 256 + n]);
    } else if (b < 832) {         // Whgt
        int id = (b - 576) * 256 + tid; int n = id >> 8, k = id & 255;
        Whgt[id] = f2bf(Whg[(size_t)k * 256 + n]);
    } else if (b < 1088) {        // Wpgt
        int id = (b - 832) * 256 + tid; int n = id >> 8, k = id & 255;
        Wpgt[id] = f2bf(Wpg[(size_t)k * 256 + n]);
    } else if (b < 3136) {        // Whrst [256][2048]
        int id = (b - 1088) * 256 + tid; int n = id >> 11, k = id & 2047;
        Whrst[id] = f2bf(Whrs[(size_t)k * 256 + n]);
    } else if (b < 3904) {        // Wgint [256][768], k-order = h*256+t
        int id = (b - 3136) * 256 + tid; int j = id / 768, k2 = id - j * 768;
        int t = k2 & 255, h = k2 >> 8;
        Wgint[id] = f2bf(Wgin[(size_t)t * 768 + h * 256 + j]);
    } else if (b < 4160) {        // Wmt [256 j][256 t] = mean_h Wgw / (1+1e-9)
        int id = (b - 3904) * 256 + tid; int j = id >> 8, t = id & 255;
        const float c3 = (1.f / 3.f) * (1.f / (1.f + 1e-9f));
        float s = Wgw[(size_t)t * 768 + j] + Wgw[(size_t)t * 768 + 256 + j] +
                  Wgw[(size_t)t * 768 + 512 + j];
        Wmt[id] = f2bf(s * c3);
    } else if (b < 4416) {        // Wphb cast
        int id = (b - 4160) * 256 + tid;
        Wphb[id] = f2bf(Wph[id]);
    } else {                      // imgb cast [512][2048]
        int id = (b - 4416) * 256 + tid;
        imgb[id] = f2bf(img[id]);
    }
}

// --------------------------- hrs split-K reduce -----------------------------
__global__ __launch_bounds__(256) void hrs_reduce_k(
    const float* __restrict__ part, const float* __restrict__ bhrs,
    float* __restrict__ hrs, unsigned short* __restrict__ hrsb)
{
    int id = blockIdx.x * 256 + threadIdx.x;        // 131072
    float s = bhrs[id & 255];
#pragma unroll
    for (int z = 0; z < 8; ++z) s += part[(size_t)z * 131072 + id];
    hrs[id] = s;
    hrsb[id] = f2bf(s);
}

// ------------------------------ pooling (vectorized) ------------------------
__global__ __launch_bounds__(256) void pool_k(const unsigned short* __restrict__ X,
                                              float* __restrict__ Pl,
                                              unsigned short* __restrict__ Plb)
{
    __shared__ float sh[2048];
    const int b = blockIdx.x, tid = threadIdx.x;
    const int cg = tid & 31, rg = tid >> 5;
    const size_t base = (size_t)b * P_NODES * HIDF + cg * 8;
    float acc[8] = {};
    for (int n = rg; n < P_NODES; n += 8) {
        union { uint4 q; unsigned short u[8]; } v;
        v.q = *(const uint4*)(X + base + (size_t)n * HIDF);
#pragma unroll
        for (int j = 0; j < 8; ++j) acc[j] += bf2f(v.u[j]);
    }
#pragma unroll
    for (int j = 0; j < 8; ++j) sh[rg * 256 + cg * 8 + j] = acc[j];
    __syncthreads();
    float s = 0.f;
#pragma unroll
    for (int r = 0; r < 8; ++r) s += sh[r * 256 + tid];
    s *= (1.f / 200.f);
    Pl[(size_t)b * 256 + tid] = s;
    Plb[(size_t)b * 256 + tid] = f2bf(s);
}

// ------------------- med = rownorm(concat(hrs, pool)) -----------------------
__global__ __launch_bounds__(256) void med_build_k(
    const float* __restrict__ hrs, const float* __restrict__ pool,
    unsigned short* __restrict__ medb)
{
    __shared__ float red[256];
    int b = blockIdx.x, f = threadIdx.x;
    float v0 = hrs[(size_t)b * 256 + f];
    float v1 = pool[(size_t)b * 256 + f];
    red[f] = v0 * v0 + v1 * v1;
    __syncthreads();
    for (int s = 128; s > 0; s >>= 1) {
        if (f < s) red[f] += red[f + s];
        __syncthreads();
    }
    float inv = rsqrtf(red[0]);
    medb[(size_t)b * 512 + f]       = f2bf(v0 * inv);
    medb[(size_t)b * 512 + 256 + f] = f2bf(v1 * inv);
}

// ---------------------- thresholded-similarity GCN --------------------------
__global__ __launch_bounds__(256) void dinv_k(const float* __restrict__ mo,
                                              float* __restrict__ dinv)
{
    __shared__ int red[256];
    int i = blockIdx.x, t = threadIdx.x;
    int c = 0;
    for (int j = t; j < 512; j += 256) c += (mo[(size_t)i * 512 + j] >= 0.9f) ? 1 : 0;
    red[t] = c; __syncthreads();
    for (int s = 128; s > 0; s >>= 1) {
        if (t < s) red[t] += red[t + s];
        __syncthreads();
    }
    if (t == 0) dinv[i] = rsqrtf((float)red[0]);
}

__global__ __launch_bounds__(256) void nadj_k(const float* __restrict__ mo,
                                              const float* __restrict__ dinv,
                                              unsigned short* __restrict__ nadjb)
{
    int i = blockIdx.x, t = threadIdx.x;
    float di = dinv[i];
    for (int j = t; j < 512; j += 256) {
        float a = (mo[(size_t)i * 512 + j] >= 0.9f || j == i) ? 1.f : 0.f;
        nadjb[(size_t)i * 512 + j] = f2bf(a * di * dinv[j]);
    }
}

// ------------------------------ GAT pieces ----------------------------------
__global__ __launch_bounds__(256) void uv_k(
    const float* __restrict__ Wgin, const float* __restrict__ al,
    const float* __restrict__ ar, const float* __restrict__ Wph,
    const float* __restrict__ bph, const unsigned short* __restrict__ Wmt,
    float* __restrict__ u, float* __restrict__ vv2,
    float* __restrict__ erb, float* __restrict__ bc)
{
    __shared__ float vsh[768];
    int k = threadIdx.x;
#pragma unroll
    for (int h = 0; h < 3; ++h) {
        float su = 0.f, sv = 0.f;
        for (int t = 0; t < 256; ++t) {
            float w = Wgin[(size_t)k * 768 + h * 256 + t];
            su += w * al[h * 256 + t];
            sv += w * ar[h * 256 + t];
        }
        u[k * 3 + h] = su;
        vsh[k * 3 + h] = sv;
    }
    __syncthreads();
    float a0 = 0.f, a1 = 0.f, a2 = 0.f, s = 0.f;
    for (int t = 0; t < 256; ++t) {
        float w = Wph[(size_t)k * 256 + t];
        a0 += w * vsh[t * 3 + 0];
        a1 += w * vsh[t * 3 + 1];
        a2 += w * vsh[t * 3 + 2];
        s  += bph[t] * bf2f(Wmt[(size_t)k * 256 + t]);   // bc[k]=sum_t bph[t]Wm[t][k]
    }
    vv2[k * 3 + 0] = a0; vv2[k * 3 + 1] = a1; vv2[k * 3 + 2] = a2;
    bc[k] = s;
    if (k < 3) {
        float e = 0.f;
        for (int t = 0; t < 256; ++t) e += bph[t] * vsh[t * 3 + k];
        erb[k] = e;
    }
}

__global__ __launch_bounds__(256) void er_k(const float* __restrict__ hrs,
                                            const float* __restrict__ vv2,
                                            const float* __restrict__ erb,
                                            float* __restrict__ er)
{
    int id = blockIdx.x * 256 + threadIdx.x;
    if (id >= B_PAR * 3) return;
    int b = id / 3, h = id % 3;
    float s = erb[h];
    for (int k = 0; k < 256; ++k) s += hrs[(size_t)b * 256 + k] * vv2[k * 3 + h];
    er[id] = s;
}

// Per-parcel: el = pp@u, e = leaky(el+er), softmax over 200 nodes/head,
// q[b,h,:] = sum_n alpha[n,h] * pp[n,:]
__global__ __launch_bounds__(256) void gat_poi2img_k(
    const unsigned short* __restrict__ pp, const float* __restrict__ u,
    const float* __restrict__ er, float* __restrict__ q)
{
    __shared__ float esh[600];
    __shared__ float ash[600];
    __shared__ float ush[768];
    __shared__ float mz[8];
    const int p = blockIdx.x, tid = threadIdx.x;
    const size_t base = (size_t)p * P_NODES;

    for (int i = tid; i < 768; i += 256) ush[i] = u[i];
    __syncthreads();

    for (int it = tid; it < 600; it += 256) {
        int n = it / 3, h = it % 3;
        const unsigned short* row = pp + (base + n) * HIDF;
        float s = 0.f;
        for (int k = 0; k < 256; k += 8) {
            union { uint4 qv; unsigned short us[8]; } w;
            w.qv = *(const uint4*)(row + k);
#pragma unroll
            for (int j = 0; j < 8; ++j) s += bf2f(w.us[j]) * ush[(k + j) * 3 + h];
        }
        s += er[p * 3 + h];
        esh[it] = s > 0.f ? s : 0.2f * s;
    }
    __syncthreads();

    int wave = tid >> 6, lane = tid & 63;
    if (wave < 3) {
        float mx = -1e30f;
        for (int n = lane; n < P_NODES; n += 64) mx = fmaxf(mx, esh[n * 3 + wave]);
        for (int o = 32; o > 0; o >>= 1) mx = fmaxf(mx, __shfl_xor(mx, o));
        float sm = 0.f;
        for (int n = lane; n < P_NODES; n += 64) sm += expf(esh[n * 3 + wave] - mx);
        for (int o = 32; o > 0; o >>= 1) sm += __shfl_xor(sm, o);
        if (lane == 0) { mz[wave] = mx; mz[4 + wave] = sm; }
    }
    __syncthreads();

    for (int it = tid; it < 600; it += 256) {
        int h = it % 3;
        ash[it] = expf(esh[it] - mz[h]) / (mz[4 + h] + 1e-9f);
    }
    __syncthreads();

    float a0 = 0.f, a1 = 0.f, a2 = 0.f;
    for (int n = 0; n < P_NODES; ++n) {
        float vv = bf2f(pp[(base + n) * HIDF + tid]);
        a0 += ash[n * 3 + 0] * vv;
        a1 += ash[n * 3 + 1] * vv;
        a2 += ash[n * 3 + 2] * vv;
    }
    q[((size_t)p * 3 + 0) * 256 + tid] = a0;
    q[((size_t)p * 3 + 1) * 256 + tid] = a1;
    q[((size_t)p * 3 + 2) * 256 + tid] = a2;
}

// --------------------------- final projection -------------------------------
__global__ __launch_bounds__(256) void final_k(
    const float* __restrict__ i2p, const float* __restrict__ hpagg,
    const float* __restrict__ p2i,
    const float* __restrict__ Wfc, const float* __restrict__ bfc,
    float* __restrict__ out)
{
    int id = blockIdx.x * 256 + threadIdx.x;
    if (id >= B_PAR * 12) return;
    int b = id / 12, o = id % 12;
    float acc = bfc[o];
    const float* s0 = i2p + (size_t)b * 256;          // img2poi_pooled
    const float* s1 = hpagg + (size_t)b * 512 + 256;  // poi_agg
    const float* s2 = p2i + (size_t)b * 256;          // poi2img
    const float* s3 = hpagg + (size_t)b * 512;        // hrs_agg
    for (int k = 0; k < 256; ++k) {
        acc += s0[k] * Wfc[(size_t)(0 * 256 + k) * 12 + o];
        acc += s1[k] * Wfc[(size_t)(1 * 256 + k) * 12 + o];
        acc += s2[k] * Wfc[(size_t)(2 * 256 + k) * 12 + o];
        acc += s3[k] * Wfc[(size_t)(3 * 256 + k) * 12 + o];
    }
    out[id] = acc;
}

// ---------------------------------------------------------------------------
extern "C" void kernel_launch(void* const* d_in, const int* in_sizes, int n_in,
                              void* d_out, int out_size, void* d_ws, size_t ws_size,
                              hipStream_t stream)
{
    const float* g_poi = (const float*)d_in[0];
    const float* img   = (const float*)d_in[1];
    const int*   esrc  = (const int*)d_in[2];
    const int*   edst  = (const int*)d_in[3];
    const float* W1    = (const float*)d_in[4];
    const float* b1    = (const float*)d_in[5];
    const float* W2    = (const float*)d_in[6];
    const float* b2    = (const float*)d_in[7];
    const float* Whrs  = (const float*)d_in[8];
    const float* bhrs  = (const float*)d_in[9];
    const float* Wph   = (const float*)d_in[10];
    const float* bph   = (const float*)d_in[11];
    const float* Wpp   = (const float*)d_in[12];
    const float* bpp   = (const float*)d_in[13];
    const float* Wgin  = (const float*)d_in[14];
    const float* alin  = (const float*)d_in[15];
    const float* arin  = (const float*)d_in[16];
    const float* Wgw   = (const float*)d_in[17];
    // d_in[18]/d_in[19] (al_with/ar_with) numerically dead: each poi node has
    // exactly one incoming parcel edge -> edge-softmax weight = 1/(1+1e-9).
    const float* Whg   = (const float*)d_in[20];
    const float* Wpg   = (const float*)d_in[21];
    const float* Wfc   = (const float*)d_in[22];
    const float* bfc   = (const float*)d_in[23];

    float* out     = (float*)d_out;
    float* med_out = out + B_PAR * 12;

    char* ws = (char*)d_ws;
    size_t off = 0;
    auto take = [&](size_t bytes) { void* pv = ws + off; off += (bytes + 255) & ~(size_t)255; return pv; };

    unsigned char*  adj8 = (unsigned char*)take((size_t)B_PAR * 256 * 256);     // 33.6MB
    unsigned short* Yt   = (unsigned short*)take((size_t)B_PAR * 256 * 256 * 2);// 67.1MB
    unsigned short* ppb  = Yt;                       // aliases Yt after agg L2
    unsigned short* XPN  = (unsigned short*)take((size_t)N_NODES * 256 * 2);    // 52.4MB
    float*          part = (float*)take((size_t)8 * 512 * 256 * 4);             // 4.2MB

    unsigned short* W1t   = (unsigned short*)take(256 * 64 * 2);
    unsigned short* W2t   = (unsigned short*)take(256 * 256 * 2);
    unsigned short* Wppt  = (unsigned short*)take(256 * 256 * 2);
    unsigned short* Whgt  = (unsigned short*)take(256 * 256 * 2);
    unsigned short* Wpgt  = (unsigned short*)take(256 * 256 * 2);
    unsigned short* Whrst = (unsigned short*)take((size_t)256 * 2048 * 2);
    unsigned short* Wgint = (unsigned short*)take((size_t)256 * 768 * 2);
    unsigned short* Wmt   = (unsigned short*)take(256 * 256 * 2);
    unsigned short* Wphb  = (unsigned short*)take(256 * 256 * 2);
    unsigned short* WcT   = (unsigned short*)take(256 * 256 * 2);
    unsigned short* imgb  = (unsigned short*)take((size_t)512 * 2048 * 2);
    unsigned short* hrsb  = (unsigned short*)take((size_t)B_PAR * 256 * 2);
    unsigned short* poolb = (unsigned short*)take((size_t)B_PAR * 256 * 2);
    unsigned short* medb  = (unsigned short*)take((size_t)B_PAR * 512 * 2);
    unsigned short* nadjb = (unsigned short*)take((size_t)B_PAR * 512 * 2);
    unsigned short* Tcatt = (unsigned short*)take((size_t)512 * 512 * 2);
    float* nrm   = (float*)take((size_t)N_NODES * 4);
    float* hrs   = (float*)take((size_t)B_PAR * 256 * 4);
    float* pool  = (float*)take((size_t)B_PAR * 256 * 4);
    float* dinv  = (float*)take((size_t)B_PAR * 4);
    float* hpagg = (float*)take((size_t)B_PAR * 512 * 4);
    float* u_in  = (float*)take(768 * 4);
    float* vv2   = (float*)take(768 * 4);
    float* erb   = (float*)take(16);
    float* bc    = (float*)take(256 * 4);
    float* er    = (float*)take((size_t)B_PAR * 3 * 4);
    float* q     = (float*)take((size_t)B_PAR * 768 * 4);
    float* p2i   = (float*)take((size_t)B_PAR * 256 * 4);
    float* i2p   = (float*)take((size_t)B_PAR * 256 * 4);
    (void)ws_size; (void)in_sizes; (void)n_in; (void)out_size;

    // ---- preprocessing ----
    hipMemsetAsync(adj8, 0, (size_t)B_PAR * 256 * 256, stream);
    prep_k<<<8512, 256, 0, stream>>>(W1, W2, Wpp, Whg, Wpg, Whrs, Wgin, Wgw,
        Wph, img, W1t, W2t, Wppt, Whgt, Wpgt, Whrst, Wgint, Wmt, Wphb, imgb);
    edge_diag_k<<<(E_EDGES + N_NODES) / 256, 256, 0, stream>>>(esrc, edst, adj8);
    norm2_k<<<N_NODES / 256, 256, 0, stream>>>(adj8, nrm);

    // ---- hrs encoder: split-K (8x256) 64-tile MFMA + reduce ----
    mm64_k<true, true, 0, false, false, false, 256>
        <<<dim3(4, 8, 8), 256, 0, stream>>>(imgb, Whrst, part, 512, 256, 2048,
            nullptr, 1.f);
    hrs_reduce_k<<<512, 256, 0, stream>>>(part, bhrs, hrs, hrsb);

    // ---- GAT precomputes ----
    uv_k<<<1, 256, 0, stream>>>(Wgin, alin, arin, Wph, bph, Wmt,
                                u_in, vv2, erb, bc);
    er_k<<<6, 256, 0, stream>>>(hrs, vv2, erb, er);
    // WcT[j][c] = (Wph @ Wm)[c][j]
    mm64_k<true, true, 1, false, false, false, 0>
        <<<dim3(4, 4), 256, 0, stream>>>(Wmt, Wphb, WcT, 256, 256, 256,
            nullptr, 1.f);

    // ---- GCN layer 1: Yt = (X@W1)^T * nrm[col], agg ----
    mm_k<true, false, 2, 2, false, false, false>
        <<<dim3(800, 2), 256, 0, stream>>>(W1t, g_poi, Yt, 256, N_NODES, 64,
            nrm, nullptr, 1.f);
    agg_k<<<dim3(2, 1024), 256, 0, stream>>>(adj8, Yt, XPN, nrm, b1, 1);

    // ---- GCN layer 2 ----
    mm_k<true, true, 2, 2, false, false, false>
        <<<dim3(800, 2), 256, 0, stream>>>(W2t, XPN, Yt, 256, N_NODES, 256,
            nrm, nullptr, 1.f);
    agg_k<<<dim3(2, 1024), 256, 0, stream>>>(adj8, Yt, XPN, nrm, b2, 0);
    // XPN = poi_nodes (bf16)

    pool_k<<<B_PAR, 256, 0, stream>>>(XPN, pool, poolb);

    // ---- med similarity (output 1) ----
    med_build_k<<<B_PAR, 256, 0, stream>>>(hrs, pool, medb);
    mm64_k<true, true, 0, false, false, true, 0>
        <<<dim3(8, 8), 256, 0, stream>>>(medb, medb, med_out, 512, 512, 512,
            nullptr, 0.5f);

    // ---- UniSimGraph GCN ----
    dinv_k<<<B_PAR, 256, 0, stream>>>(med_out, dinv);
    nadj_k<<<B_PAR, 256, 0, stream>>>(med_out, dinv, nadjb);
    // Tcatt rows 0-255: t_h^T ; rows 256-511: t_p^T
    mm64_k<true, true, 1, false, false, false, 0>
        <<<dim3(8, 4), 256, 0, stream>>>(Whgt, hrsb, Tcatt, 256, 512, 256,
            nullptr, 1.f);
    mm64_k<true, true, 1, false, false, false, 0>
        <<<dim3(8, 4), 256, 0, stream>>>(Wpgt, poolb, Tcatt + (size_t)256 * 512,
            256, 512, 256, nullptr, 1.f);
    // [hagg | pagg] = relu(nadj @ [t_h | t_p])
    mm64_k<true, true, 0, false, true, false, 0>
        <<<dim3(8, 8), 256, 0, stream>>>(nadjb, Tcatt, hpagg, 512, 512, 512,
            nullptr, 1.f);

    // ---- pp projection (overwrites dead Yt region) ----
    mm_k<true, true, 1, 0, true, false, false>
        <<<dim3(2, 800), 256, 0, stream>>>(XPN, Wppt, ppb, N_NODES, 256, 256,
            nullptr, bpp, 1.f);

    // ---- GAT poi2img ----
    gat_poi2img_k<<<B_PAR, 256, 0, stream>>>(ppb, u_in, er, q);
    mm64_k<false, true, 0, false, false, false, 0>
        <<<dim3(4, 8), 256, 0, stream>>>(q, Wgint, p2i, 512, 256, 768,
            nullptr, 1.f / 3.f);

    // ---- img2poi pooled: i2p = hrs @ Wc + bc ----
    mm64_k<true, true, 0, true, false, false, 0>
        <<<dim3(4, 8), 256, 0, stream>>>(hrsb, WcT, i2p, 512, 256, 256,
            bc, 1.f);

    // ---- final fc ----
    final_k<<<24, 256, 0, stream>>>(i2p, hpagg, p2i, Wfc, bfc, out);
}

// Round 5
// 526.960 us; speedup vs baseline: 3.0433x; 1.0108x over previous
//
#include <hip/hip_runtime.h>
#include <hip/hip_bf16.h>
#include <math.h>

// ---------------------------------------------------------------------------
// NGLU: B=512 parcels x P=200 poi nodes. N=102400, E=1638400, HID=256.
// Round 5: 256x256-tile 8-wave MFMA kernels for the GCN heavy path
// (agg256_k: one block per parcel; mm256_k: transforms/pp). 64 MFMA per wave
// per K-step between barriers (4x round-4) to cover L3/HBM latency; per-parcel
// operands read exactly once (L1-side traffic halved). Small GEMMs on mm64_k.
// ---------------------------------------------------------------------------

#define N_NODES 102400
#define B_PAR   512
#define P_NODES 200
#define E_EDGES 1638400
#define HIDF    256

typedef __attribute__((ext_vector_type(8))) short bf16x8;
typedef __attribute__((ext_vector_type(4))) float f32x4;

__device__ __forceinline__ unsigned short f2bf(float x) {
    unsigned u = __builtin_bit_cast(unsigned, x);
    u += 0x7fffu + ((u >> 16) & 1u);               // RNE (finite data only)
    return (unsigned short)(u >> 16);
}
__device__ __forceinline__ float bf2f(unsigned short h) {
    return __builtin_bit_cast(float, (unsigned)h << 16);
}
// LDS tile [rows][64 k] bf16 = 128B/row; 16B-chunk XOR swizzle -> 2-way max.
__device__ __forceinline__ int lds_off(int row, int kbyte) {
    return row * 128 + ((((kbyte >> 4) ^ (row & 7)) << 4) | (kbyte & 15));
}
template<bool BF16SRC>
__device__ __forceinline__ bf16x8 load_row8(const void* p, size_t elemoff) {
    if constexpr (BF16SRC) {
        return *(const bf16x8*)((const unsigned short*)p + elemoff);
    } else {
        const float* ap = (const float*)p + elemoff;
        float4 lo = *(const float4*)ap;
        float4 hi = *(const float4*)(ap + 4);
        union { bf16x8 v; unsigned short u[8]; } pk;
        pk.u[0] = f2bf(lo.x); pk.u[1] = f2bf(lo.y);
        pk.u[2] = f2bf(lo.z); pk.u[3] = f2bf(lo.w);
        pk.u[4] = f2bf(hi.x); pk.u[5] = f2bf(hi.y);
        pk.u[6] = f2bf(hi.z); pk.u[7] = f2bf(hi.w);
        return pk.v;
    }
}
__device__ __forceinline__ bf16x8 u8x8_to_bf16(uint2 w) {
    union { bf16x8 v; unsigned short u[8]; } r;
#pragma unroll
    for (int b = 0; b < 4; ++b) {
        r.u[b]     = (unsigned short)(__builtin_bit_cast(unsigned,
                        (float)((w.x >> (8 * b)) & 255u)) >> 16);   // exact: ints<256
        r.u[4 + b] = (unsigned short)(__builtin_bit_cast(unsigned,
                        (float)((w.y >> (8 * b)) & 255u)) >> 16);
    }
    return r.v;
}

// --------------------- 256x256-tile 8-wave MFMA GEMM ------------------------
// D[M,Nc] = A[M,K] @ B[Nc,K]^T  (row-major [m][k] / [n][k] operands)
// OMODE: 0=f32 [M][Nc], 1=bf16 [M][Nc], 2=bf16 parcel-transposed
//        (row=f, col=g -> Yt[g/200][f][g%200] of [512][256][256]).
// SCMODE: 0 none, 2 scale[col]. 512 threads, waves 2m x 4n, 64KB LDS.
template<bool ABF16, bool BBF16, int OMODE, int SCMODE, bool BIASF, bool RELUF>
__global__ __launch_bounds__(512, 2) void mm256_k(
    const void* __restrict__ Ain, const void* __restrict__ Bin,
    void* __restrict__ Cout, int M, int Nc, int K,
    const float* __restrict__ scale, const float* __restrict__ bias)
{
    __shared__ bf16x8 smem_v[4096];                 // 64 KiB
    unsigned char* Asm = (unsigned char*)smem_v;
    unsigned char* Bsm = Asm + 32768;

    const int tid  = threadIdx.x;
    const int m0   = blockIdx.y * 256;
    const int n0   = blockIdx.x * 256;
    const int sr   = tid >> 3, sc = tid & 7;        // staging: 64 rows x 8 chunks
    const int lane = tid & 63;
    const int wave = tid >> 6;
    const int wm   = wave >> 2, wn = wave & 3;      // wave tile: 128m x 64n
    const int frow = lane & 15;
    const int fko  = (lane >> 4) << 4;

    f32x4 acc[8][4];
    const f32x4 fz = {0.f, 0.f, 0.f, 0.f};
#pragma unroll
    for (int i = 0; i < 8; ++i)
#pragma unroll
        for (int j = 0; j < 4; ++j) acc[i][j] = fz;

    bf16x8 areg[4], breg[4];
    auto load_tiles = [&](int k0) {
#pragma unroll
        for (int i = 0; i < 4; ++i) {
            int row = sr + 64 * i;
            areg[i] = load_row8<ABF16>(Ain, (size_t)(m0 + row) * K + k0 + sc * 8);
            breg[i] = load_row8<BBF16>(Bin, (size_t)(n0 + row) * K + k0 + sc * 8);
        }
    };

    load_tiles(0);
    for (int k0 = 0; k0 < K; k0 += 64) {
        __syncthreads();                            // prev iter's LDS readers done
#pragma unroll
        for (int i = 0; i < 4; ++i) {
            *(bf16x8*)(Asm + lds_off(sr + 64 * i, sc * 16)) = areg[i];
            *(bf16x8*)(Bsm + lds_off(sr + 64 * i, sc * 16)) = breg[i];
        }
        __syncthreads();
        if (k0 + 64 < K) load_tiles(k0 + 64);       // prefetch overlaps MFMA
#pragma unroll
        for (int ks = 0; ks < 2; ++ks) {
            const int kb = ks * 64 + fko;
            bf16x8 bfr[4];
#pragma unroll
            for (int t = 0; t < 4; ++t)
                bfr[t] = *(const bf16x8*)(Bsm + lds_off(wn * 64 + t * 16 + frow, kb));
#pragma unroll
            for (int mi = 0; mi < 8; ++mi) {
                bf16x8 af = *(const bf16x8*)(Asm + lds_off(wm * 128 + mi * 16 + frow, kb));
#pragma unroll
                for (int ni = 0; ni < 4; ++ni)
                    acc[mi][ni] = __builtin_amdgcn_mfma_f32_16x16x32_bf16(
                        af, bfr[ni], acc[mi][ni], 0, 0, 0);
            }
        }
    }

    const int r4 = (lane >> 4) << 2;                // C/D: col=l&15, row=(l>>4)*4+j
#pragma unroll
    for (int mi = 0; mi < 8; ++mi) {
#pragma unroll
        for (int ni = 0; ni < 4; ++ni) {
            int col = n0 + wn * 64 + ni * 16 + frow;
#pragma unroll
            for (int j = 0; j < 4; ++j) {
                int row = m0 + wm * 128 + mi * 16 + r4 + j;
                float v = acc[mi][ni][j];
                if (SCMODE == 2) v *= scale[col];
                if (BIASF)       v += bias[col];
                if (RELUF)       v = fmaxf(v, 0.f);
                if (OMODE == 0) {
                    ((float*)Cout)[(size_t)row * Nc + col] = v;
                } else if (OMODE == 1) {
                    ((unsigned short*)Cout)[(size_t)row * Nc + col] = f2bf(v);
                } else {
                    int p = col / 200, r = col - p * 200;
                    ((unsigned short*)Cout)[((size_t)p * 256 + row) * 256 + r] = f2bf(v);
                }
            }
        }
    }
}

// ------------- GCN aggregation: one block per parcel, 256x256 ---------------
// Out[p*200+d][f] = (sum_s Adj[p][d][s] * Yt[p][f][s]) * nrm[g] + bias[f]
__global__ __launch_bounds__(512, 2) void agg256_k(
    const unsigned char* __restrict__ Adj, const unsigned short* __restrict__ Yt,
    unsigned short* __restrict__ Outb, const float* __restrict__ nrm,
    const float* __restrict__ bias, int relu)
{
    __shared__ bf16x8 smem_v[4096];                 // 64 KiB
    unsigned char* Asm = (unsigned char*)smem_v;
    unsigned char* Bsm = Asm + 32768;

    const int tid  = threadIdx.x;
    const int p    = blockIdx.x;
    const int sr   = tid >> 3, sc = tid & 7;
    const int lane = tid & 63;
    const int wave = tid >> 6;
    const int wm   = wave >> 2, wn = wave & 3;
    const int frow = lane & 15;
    const int fko  = (lane >> 4) << 4;
    const size_t abase = (size_t)p * 65536;         // u8 [256][256]
    const size_t ybase = (size_t)p * 65536;         // bf16 [256][256]

    f32x4 acc[8][4];
    const f32x4 fz = {0.f, 0.f, 0.f, 0.f};
#pragma unroll
    for (int i = 0; i < 8; ++i)
#pragma unroll
        for (int j = 0; j < 4; ++j) acc[i][j] = fz;

    uint2  awreg[4];
    bf16x8 breg[4];
    auto load_tiles = [&](int k0) {
#pragma unroll
        for (int i = 0; i < 4; ++i) {
            int row = sr + 64 * i;
            awreg[i] = *(const uint2*)(Adj + abase + (size_t)row * 256 + k0 + sc * 8);
            breg[i]  = *(const bf16x8*)(Yt + ybase + (size_t)row * 256 + k0 + sc * 8);
        }
    };

    load_tiles(0);
#pragma unroll
    for (int t4 = 0; t4 < 4; ++t4) {
        __syncthreads();
#pragma unroll
        for (int i = 0; i < 4; ++i) {
            *(bf16x8*)(Asm + lds_off(sr + 64 * i, sc * 16)) = u8x8_to_bf16(awreg[i]);
            *(bf16x8*)(Bsm + lds_off(sr + 64 * i, sc * 16)) = breg[i];
        }
        __syncthreads();
        if (t4 < 3) load_tiles((t4 + 1) * 64);      // prefetch overlaps MFMA
#pragma unroll
        for (int ks = 0; ks < 2; ++ks) {
            const int kb = ks * 64 + fko;
            bf16x8 bfr[4];
#pragma unroll
            for (int t = 0; t < 4; ++t)
                bfr[t] = *(const bf16x8*)(Bsm + lds_off(wn * 64 + t * 16 + frow, kb));
#pragma unroll
            for (int mi = 0; mi < 8; ++mi) {
                bf16x8 af = *(const bf16x8*)(Asm + lds_off(wm * 128 + mi * 16 + frow, kb));
#pragma unroll
                for (int ni = 0; ni < 4; ++ni)
                    acc[mi][ni] = __builtin_amdgcn_mfma_f32_16x16x32_bf16(
                        af, bfr[ni], acc[mi][ni], 0, 0, 0);
            }
        }
    }

    const int r4 = (lane >> 4) << 2;
#pragma unroll
    for (int mi = 0; mi < 8; ++mi) {
#pragma unroll
        for (int ni = 0; ni < 4; ++ni) {
            int col = wn * 64 + ni * 16 + frow;
#pragma unroll
            for (int j = 0; j < 4; ++j) {
                int d = wm * 128 + mi * 16 + r4 + j;
                if (d < 200) {
                    int g = p * 200 + d;
                    float v = acc[mi][ni][j] * nrm[g] + bias[col];
                    if (relu) v = fmaxf(v, 0.f);
                    Outb[(size_t)g * 256 + col] = f2bf(v);
                }
            }
        }
    }
}

// ----------------------- 64x64 MFMA GEMM (small shapes) ---------------------
template<bool ABF16, bool BBF16, int OMODE, bool BIASF, bool RELUF,
         bool MEDOUT, int KCHUNK>
__global__ __launch_bounds__(256) void mm64_k(
    const void* __restrict__ Ain, const void* __restrict__ Bin,
    void* __restrict__ Cout, int M, int Nc, int K,
    const float* __restrict__ bias, float alpha)
{
    __shared__ bf16x8 smem_v[1024];                 // 16 KiB
    unsigned char* Asm = (unsigned char*)smem_v;
    unsigned char* Bsm = Asm + 8192;

    const int tid  = threadIdx.x;
    const int m0   = blockIdx.y * 64;
    const int n0   = blockIdx.x * 64;
    const int sr   = tid >> 3, sc = tid & 7;
    const int lane = tid & 63;
    const int wm   = (tid >> 7) & 1, wn = (tid >> 6) & 1;
    const int frow = lane & 15;
    const int fko  = (lane >> 4) << 4;

    int kbeg = 0, kend = K;
    float* Cf = (float*)Cout;
    if (KCHUNK > 0) {
        kbeg = blockIdx.z * KCHUNK; kend = kbeg + KCHUNK;
        Cf += (size_t)blockIdx.z * M * Nc;
    }

    f32x4 acc[2][2];
    const f32x4 fz = {0.f, 0.f, 0.f, 0.f};
#pragma unroll
    for (int i = 0; i < 2; ++i)
#pragma unroll
        for (int j = 0; j < 2; ++j) acc[i][j] = fz;

    bf16x8 areg[2], breg[2];
    auto load_tiles = [&](int k0) {
#pragma unroll
        for (int i = 0; i < 2; ++i) {
            int row = sr + 32 * i;
            areg[i] = load_row8<ABF16>(Ain, (size_t)(m0 + row) * K + k0 + sc * 8);
            breg[i] = load_row8<BBF16>(Bin, (size_t)(n0 + row) * K + k0 + sc * 8);
        }
    };

    load_tiles(kbeg);
    for (int k0 = kbeg; k0 < kend; k0 += 64) {
        __syncthreads();
#pragma unroll
        for (int i = 0; i < 2; ++i) {
            *(bf16x8*)(Asm + lds_off(sr + 32 * i, sc * 16)) = areg[i];
            *(bf16x8*)(Bsm + lds_off(sr + 32 * i, sc * 16)) = breg[i];
        }
        __syncthreads();
        if (k0 + 64 < kend) load_tiles(k0 + 64);
#pragma unroll
        for (int ks = 0; ks < 2; ++ks) {
            const int kb = ks * 64 + fko;
            bf16x8 af[2], bfr[2];
#pragma unroll
            for (int t = 0; t < 2; ++t)
                af[t] = *(const bf16x8*)(Asm + lds_off(wm * 32 + t * 16 + frow, kb));
#pragma unroll
            for (int t = 0; t < 2; ++t)
                bfr[t] = *(const bf16x8*)(Bsm + lds_off(wn * 32 + t * 16 + frow, kb));
#pragma unroll
            for (int mi = 0; mi < 2; ++mi)
#pragma unroll
                for (int ni = 0; ni < 2; ++ni)
                    acc[mi][ni] = __builtin_amdgcn_mfma_f32_16x16x32_bf16(
                        af[mi], bfr[ni], acc[mi][ni], 0, 0, 0);
        }
    }

    const int r4 = (lane >> 4) << 2;
#pragma unroll
    for (int mi = 0; mi < 2; ++mi) {
#pragma unroll
        for (int ni = 0; ni < 2; ++ni) {
            int col = n0 + wn * 32 + ni * 16 + frow;
#pragma unroll
            for (int j = 0; j < 4; ++j) {
                int row = m0 + wm * 32 + mi * 16 + r4 + j;
                float v = acc[mi][ni][j] * alpha;
                if (BIASF)  v += bias[col];
                if (RELUF)  v = fmaxf(v, 0.f);
                if (MEDOUT) v += 0.5f;
                if (OMODE == 0) {
                    Cf[(size_t)row * Nc + col] = v;
                } else {
                    ((unsigned short*)Cout)[(size_t)row * Nc + col] = f2bf(v);
                }
            }
        }
    }
}

// ------------------------- graph preprocessing -----------------------------
__global__ __launch_bounds__(256) void edge_diag_k(
    const int* __restrict__ esrc, const int* __restrict__ edst,
    unsigned char* __restrict__ A)
{
    int id = blockIdx.x * 256 + threadIdx.x;        // E + N = 1740800
    size_t bo;
    if (id < E_EDGES) {
        int s = esrc[id], d = edst[id];
        int p = d / 200;
        int dl = d - p * 200, sl = s - p * 200;
        bo = (((size_t)(p * 256 + dl)) << 8) + (unsigned)sl;
    } else {
        int i2 = id - E_EDGES;                      // < N
        int p = i2 / 200, d = i2 - p * 200;
        bo = (((size_t)(p * 256 + d)) << 8) + (unsigned)d;
    }
    atomicAdd((unsigned int*)(A + (bo & ~(size_t)3)), 1u << ((bo & 3) * 8));
}

__global__ __launch_bounds__(256) void norm2_k(const unsigned char* __restrict__ A,
                                               float* __restrict__ nrm)
{
    int g = blockIdx.x * 256 + threadIdx.x;
    int p = g / 200, d = g - p * 200;
    const uint4* row = (const uint4*)(A + (((size_t)(p * 256 + d)) << 8));
    unsigned s = 0;
#pragma unroll
    for (int i = 0; i < 16; ++i) {
        uint4 w = row[i];
        unsigned a = w.x, b = w.y, c = w.z, e = w.w;
        s += (a & 255) + ((a >> 8) & 255) + ((a >> 16) & 255) + (a >> 24);
        s += (b & 255) + ((b >> 8) & 255) + ((b >> 16) & 255) + (b >> 24);
        s += (c & 255) + ((c >> 8) & 255) + ((c >> 16) & 255) + (c >> 24);
        s += (e & 255) + ((e >> 8) & 255) + ((e >> 16) & 255) + (e >> 24);
    }
    nrm[g] = rsqrtf((float)s);                      // row-sum = in-deg + self
}

// ------------- all weight transposes/casts + img cast -----------------------
__global__ __launch_bounds__(256) void prep_k(
    const float* __restrict__ W1, const float* __restrict__ W2,
    const float* __restrict__ Wpp, const float* __restrict__ Whg,
    const float* __restrict__ Wpg, const float* __restrict__ Whrs,
    const float* __restrict__ Wgin, const float* __restrict__ Wgw,
    const float* __restrict__ Wph, const float* __restrict__ img,
    unsigned short* __restrict__ W1t, unsigned short* __restrict__ W2t,
    unsigned short* __restrict__ Wppt, unsigned short* __restrict__ Whgt,
    unsigned short* __restrict__ Wpgt, unsigned short* __restrict__ Whrst,
    unsigned short* __restrict__ Wgint, unsigned short* __restrict__ Wmt,
    unsigned short* __restrict__ Wphb, unsigned short* __restrict__ imgb)
{
    int b = blockIdx.x, tid = threadIdx.x;
    if (b < 64) {                 // W1t [256][64]
        int id = b * 256 + tid; int n = id >> 6, k = id & 63;
        W1t[id] = f2bf(W1[(size_t)k * 256 + n]);
    } else if (b < 320) {         // W2t [256][256]
        int id = (b - 64) * 256 + tid; int n = id >> 8, k = id & 255;
        W2t[id] = f2bf(W2[(size_t)k * 256 + n]);
    } else if (b < 576) {         // Wppt
        int id = (b - 320) * 256 + tid; int n = id >> 8, k = id & 255;
        Wppt[id] = f2bf(Wpp[(size_t)k * 256 + n]);
    } else if (b < 832) {         // Whgt
        int id = (b - 576) * 256 + tid; int n = id >> 8, k = id & 255;
        Whgt[id] = f2bf(Whg[(size_t)k * 256 + n]);
    } else if (b < 1088) {        // Wpgt
        int id = (b - 832) * 256 + tid; int n = id >> 8, k = id & 255;
        Wpgt[id] = f2bf(Wpg[(size_t)k * 256 + n]);
    } else if (b < 3136) {        // Whrst [256][2048]
        int id = (b - 1088) * 256 + tid; int n = id >> 11, k = id & 2047;
        Whrst[id] = f2bf(Whrs[(size_t)k * 256 + n]);
    } else if (b < 3904) {        // Wgint [256][768], k-order = h*256+t
        int id = (b - 3136) * 256 + tid; int j = id / 768, k2 = id - j * 768;
        int t = k2 & 255, h = k2 >> 8;
        Wgint[id] = f2bf(Wgin[(size_t)t * 768 + h * 256 + j]);
    } else if (b < 4160) {        // Wmt [256 j][256 t] = mean_h Wgw / (1+1e-9)
        int id = (b - 3904) * 256 + tid; int j = id >> 8, t = id & 255;
        const float c3 = (1.f / 3.f) * (1.f / (1.f + 1e-9f));
        float s = Wgw[(size_t)t * 768 + j] + Wgw[(size_t)t * 768 + 256 + j] +
                  Wgw[(size_t)t * 768 + 512 + j];
        Wmt[id] = f2bf(s * c3);
    } else if (b < 4416) {        // Wphb cast
        int id = (b - 4160) * 256 + tid;
        Wphb[id] = f2bf(Wph[id]);
    } else {                      // imgb cast [512][2048]
        int id = (b - 4416) * 256 + tid;
        imgb[id] = f2bf(img[id]);
    }
}

// --------------------------- hrs split-K reduce -----------------------------
__global__ __launch_bounds__(256) void hrs_reduce_k(
    const float* __restrict__ part, const float* __restrict__ bhrs,
    float* __restrict__ hrs, unsigned short* __restrict__ hrsb)
{
    int id = blockIdx.x * 256 + threadIdx.x;        // 131072
    float s = bhrs[id & 255];
#pragma unroll
    for (int z = 0; z < 8; ++z) s += part[(size_t)z * 131072 + id];
    hrs[id] = s;
    hrsb[id] = f2bf(s);
}

// ------------------------------ pooling (vectorized) ------------------------
__global__ __launch_bounds__(256) void pool_k(const unsigned short* __restrict__ X,
                                              float* __restrict__ Pl,
                                              unsigned short* __restrict__ Plb)
{
    __shared__ float sh[2048];
    const int b = blockIdx.x, tid = threadIdx.x;
    const int cg = tid & 31, rg = tid >> 5;
    const size_t base = (size_t)b * P_NODES * HIDF + cg * 8;
    float acc[8] = {};
    for (int n = rg; n < P_NODES; n += 8) {
        union { uint4 q; unsigned short u[8]; } v;
        v.q = *(const uint4*)(X + base + (size_t)n * HIDF);
#pragma unroll
        for (int j = 0; j < 8; ++j) acc[j] += bf2f(v.u[j]);
    }
#pragma unroll
    for (int j = 0; j < 8; ++j) sh[rg * 256 + cg * 8 + j] = acc[j];
    __syncthreads();
    float s = 0.f;
#pragma unroll
    for (int r = 0; r < 8; ++r) s += sh[r * 256 + tid];
    s *= (1.f / 200.f);
    Pl[(size_t)b * 256 + tid] = s;
    Plb[(size_t)b * 256 + tid] = f2bf(s);
}

// ------------------- med = rownorm(concat(hrs, pool)) -----------------------
__global__ __launch_bounds__(256) void med_build_k(
    const float* __restrict__ hrs, const float* __restrict__ pool,
    unsigned short* __restrict__ medb)
{
    __shared__ float red[256];
    int b = blockIdx.x, f = threadIdx.x;
    float v0 = hrs[(size_t)b * 256 + f];
    float v1 = pool[(size_t)b * 256 + f];
    red[f] = v0 * v0 + v1 * v1;
    __syncthreads();
    for (int s = 128; s > 0; s >>= 1) {
        if (f < s) red[f] += red[f + s];
        __syncthreads();
    }
    float inv = rsqrtf(red[0]);
    medb[(size_t)b * 512 + f]       = f2bf(v0 * inv);
    medb[(size_t)b * 512 + 256 + f] = f2bf(v1 * inv);
}

// ---------------------- thresholded-similarity GCN --------------------------
__global__ __launch_bounds__(256) void dinv_k(const float* __restrict__ mo,
                                              float* __restrict__ dinv)
{
    __shared__ int red[256];
    int i = blockIdx.x, t = threadIdx.x;
    int c = 0;
    for (int j = t; j < 512; j += 256) c += (mo[(size_t)i * 512 + j] >= 0.9f) ? 1 : 0;
    red[t] = c; __syncthreads();
    for (int s = 128; s > 0; s >>= 1) {
        if (t < s) red[t] += red[t + s];
        __syncthreads();
    }
    if (t == 0) dinv[i] = rsqrtf((float)red[0]);
}

__global__ __launch_bounds__(256) void nadj_k(const float* __restrict__ mo,
                                              const float* __restrict__ dinv,
                                              unsigned short* __restrict__ nadjb)
{
    int i = blockIdx.x, t = threadIdx.x;
    float di = dinv[i];
    for (int j = t; j < 512; j += 256) {
        float a = (mo[(size_t)i * 512 + j] >= 0.9f || j == i) ? 1.f : 0.f;
        nadjb[(size_t)i * 512 + j] = f2bf(a * di * dinv[j]);
    }
}

// ------------------------------ GAT pieces ----------------------------------
__global__ __launch_bounds__(256) void uv_k(
    const float* __restrict__ Wgin, const float* __restrict__ al,
    const float* __restrict__ ar, const float* __restrict__ Wph,
    const float* __restrict__ bph, const unsigned short* __restrict__ Wmt,
    float* __restrict__ u, float* __restrict__ vv2,
    float* __restrict__ erb, float* __restrict__ bc)
{
    __shared__ float vsh[768];
    int k = threadIdx.x;
#pragma unroll
    for (int h = 0; h < 3; ++h) {
        float su = 0.f, sv = 0.f;
        for (int t = 0; t < 256; ++t) {
            float w = Wgin[(size_t)k * 768 + h * 256 + t];
            su += w * al[h * 256 + t];
            sv += w * ar[h * 256 + t];
        }
        u[k * 3 + h] = su;
        vsh[k * 3 + h] = sv;
    }
    __syncthreads();
    float a0 = 0.f, a1 = 0.f, a2 = 0.f, s = 0.f;
    for (int t = 0; t < 256; ++t) {
        float w = Wph[(size_t)k * 256 + t];
        a0 += w * vsh[t * 3 + 0];
        a1 += w * vsh[t * 3 + 1];
        a2 += w * vsh[t * 3 + 2];
        s  += bph[t] * bf2f(Wmt[(size_t)k * 256 + t]);   // bc[k]=sum_t bph[t]Wm[t][k]
    }
    vv2[k * 3 + 0] = a0; vv2[k * 3 + 1] = a1; vv2[k * 3 + 2] = a2;
    bc[k] = s;
    if (k < 3) {
        float e = 0.f;
        for (int t = 0; t < 256; ++t) e += bph[t] * vsh[t * 3 + k];
        erb[k] = e;
    }
}

__global__ __launch_bounds__(256) void er_k(const float* __restrict__ hrs,
                                            const float* __restrict__ vv2,
                                            const float* __restrict__ erb,
                                            float* __restrict__ er)
{
    int id = blockIdx.x * 256 + threadIdx.x;
    if (id >= B_PAR * 3) return;
    int b = id / 3, h = id % 3;
    float s = erb[h];
    for (int k = 0; k < 256; ++k) s += hrs[(size_t)b * 256 + k] * vv2[k * 3 + h];
    er[id] = s;
}

// Per-parcel: el = pp@u, e = leaky(el+er), softmax over 200 nodes/head,
// q[b,h,:] = sum_n alpha[n,h] * pp[n,:]
__global__ __launch_bounds__(256) void gat_poi2img_k(
    const unsigned short* __restrict__ pp, const float* __restrict__ u,
    const float* __restrict__ er, float* __restrict__ q)
{
    __shared__ float esh[600];
    __shared__ float ash[600];
    __shared__ float ush[768];
    __shared__ float mz[8];
    const int p = blockIdx.x, tid = threadIdx.x;
    const size_t base = (size_t)p * P_NODES;

    for (int i = tid; i < 768; i += 256) ush[i] = u[i];
    __syncthreads();

    for (int it = tid; it < 600; it += 256) {
        int n = it / 3, h = it % 3;
        const unsigned short* row = pp + (base + n) * HIDF;
        float s = 0.f;
        for (int k = 0; k < 256; k += 8) {
            union { uint4 qv; unsigned short us[8]; } w;
            w.qv = *(const uint4*)(row + k);
#pragma unroll
            for (int j = 0; j < 8; ++j) s += bf2f(w.us[j]) * ush[(k + j) * 3 + h];
        }
        s += er[p * 3 + h];
        esh[it] = s > 0.f ? s : 0.2f * s;
    }
    __syncthreads();

    int wave = tid >> 6, lane = tid & 63;
    if (wave < 3) {
        float mx = -1e30f;
        for (int n = lane; n < P_NODES; n += 64) mx = fmaxf(mx, esh[n * 3 + wave]);
        for (int o = 32; o > 0; o >>= 1) mx = fmaxf(mx, __shfl_xor(mx, o));
        float sm = 0.f;
        for (int n = lane; n < P_NODES; n += 64) sm += expf(esh[n * 3 + wave] - mx);
        for (int o = 32; o > 0; o >>= 1) sm += __shfl_xor(sm, o);
        if (lane == 0) { mz[wave] = mx; mz[4 + wave] = sm; }
    }
    __syncthreads();

    for (int it = tid; it < 600; it += 256) {
        int h = it % 3;
        ash[it] = expf(esh[it] - mz[h]) / (mz[4 + h] + 1e-9f);
    }
    __syncthreads();

    float a0 = 0.f, a1 = 0.f, a2 = 0.f;
    for (int n = 0; n < P_NODES; ++n) {
        float vv = bf2f(pp[(base + n) * HIDF + tid]);
        a0 += ash[n * 3 + 0] * vv;
        a1 += ash[n * 3 + 1] * vv;
        a2 += ash[n * 3 + 2] * vv;
    }
    q[((size_t)p * 3 + 0) * 256 + tid] = a0;
    q[((size_t)p * 3 + 1) * 256 + tid] = a1;
    q[((size_t)p * 3 + 2) * 256 + tid] = a2;
}

// --------------------------- final projection -------------------------------
__global__ __launch_bounds__(256) void final_k(
    const float* __restrict__ i2p, const float* __restrict__ hpagg,
    const float* __restrict__ p2i,
    const float* __restrict__ Wfc, const float* __restrict__ bfc,
    float* __restrict__ out)
{
    int id = blockIdx.x * 256 + threadIdx.x;
    if (id >= B_PAR * 12) return;
    int b = id / 12, o = id % 12;
    float acc = bfc[o];
    const float* s0 = i2p + (size_t)b * 256;          // img2poi_pooled
    const float* s1 = hpagg + (size_t)b * 512 + 256;  // poi_agg
    const float* s2 = p2i + (size_t)b * 256;          // poi2img
    const float* s3 = hpagg + (size_t)b * 512;        // hrs_agg
    for (int k = 0; k < 256; ++k) {
        acc += s0[k] * Wfc[(size_t)(0 * 256 + k) * 12 + o];
        acc += s1[k] * Wfc[(size_t)(1 * 256 + k) * 12 + o];
        acc += s2[k] * Wfc[(size_t)(2 * 256 + k) * 12 + o];
        acc += s3[k] * Wfc[(size_t)(3 * 256 + k) * 12 + o];
    }
    out[id] = acc;
}

// ---------------------------------------------------------------------------
extern "C" void kernel_launch(void* const* d_in, const int* in_sizes, int n_in,
                              void* d_out, int out_size, void* d_ws, size_t ws_size,
                              hipStream_t stream)
{
    const float* g_poi = (const float*)d_in[0];
    const float* img   = (const float*)d_in[1];
    const int*   esrc  = (const int*)d_in[2];
    const int*   edst  = (const int*)d_in[3];
    const float* W1    = (const float*)d_in[4];
    const float* b1    = (const float*)d_in[5];
    const float* W2    = (const float*)d_in[6];
    const float* b2    = (const float*)d_in[7];
    const float* Whrs  = (const float*)d_in[8];
    const float* bhrs  = (const float*)d_in[9];
    const float* Wph   = (const float*)d_in[10];
    const float* bph   = (const float*)d_in[11];
    const float* Wpp   = (const float*)d_in[12];
    const float* bpp   = (const float*)d_in[13];
    const float* Wgin  = (const float*)d_in[14];
    const float* alin  = (const float*)d_in[15];
    const float* arin  = (const float*)d_in[16];
    const float* Wgw   = (const float*)d_in[17];
    // d_in[18]/d_in[19] (al_with/ar_with) numerically dead: each poi node has
    // exactly one incoming parcel edge -> edge-softmax weight = 1/(1+1e-9).
    const float* Whg   = (const float*)d_in[20];
    const float* Wpg   = (const float*)d_in[21];
    const float* Wfc   = (const float*)d_in[22];
    const float* bfc   = (const float*)d_in[23];

    float* out     = (float*)d_out;
    float* med_out = out + B_PAR * 12;

    char* ws = (char*)d_ws;
    size_t off = 0;
    auto take = [&](size_t bytes) { void* pv = ws + off; off += (bytes + 255) & ~(size_t)255; return pv; };

    unsigned char*  adj8 = (unsigned char*)take((size_t)B_PAR * 256 * 256);     // 33.6MB
    unsigned short* Yt   = (unsigned short*)take((size_t)B_PAR * 256 * 256 * 2);// 67.1MB
    unsigned short* ppb  = Yt;                       // aliases Yt after agg L2
    unsigned short* XPN  = (unsigned short*)take((size_t)N_NODES * 256 * 2);    // 52.4MB
    float*          part = (float*)take((size_t)8 * 512 * 256 * 4);             // 4.2MB

    unsigned short* W1t   = (unsigned short*)take(256 * 64 * 2);
    unsigned short* W2t   = (unsigned short*)take(256 * 256 * 2);
    unsigned short* Wppt  = (unsigned short*)take(256 * 256 * 2);
    unsigned short* Whgt  = (unsigned short*)take(256 * 256 * 2);
    unsigned short* Wpgt  = (unsigned short*)take(256 * 256 * 2);
    unsigned short* Whrst = (unsigned short*)take((size_t)256 * 2048 * 2);
    unsigned short* Wgint = (unsigned short*)take((size_t)256 * 768 * 2);
    unsigned short* Wmt   = (unsigned short*)take(256 * 256 * 2);
    unsigned short* Wphb  = (unsigned short*)take(256 * 256 * 2);
    unsigned short* WcT   = (unsigned short*)take(256 * 256 * 2);
    unsigned short* imgb  = (unsigned short*)take((size_t)512 * 2048 * 2);
    unsigned short* hrsb  = (unsigned short*)take((size_t)B_PAR * 256 * 2);
    unsigned short* poolb = (unsigned short*)take((size_t)B_PAR * 256 * 2);
    unsigned short* medb  = (unsigned short*)take((size_t)B_PAR * 512 * 2);
    unsigned short* nadjb = (unsigned short*)take((size_t)B_PAR * 512 * 2);
    unsigned short* Tcatt = (unsigned short*)take((size_t)512 * 512 * 2);
    float* nrm   = (float*)take((size_t)N_NODES * 4);
    float* hrs   = (float*)take((size_t)B_PAR * 256 * 4);
    float* pool  = (float*)take((size_t)B_PAR * 256 * 4);
    float* dinv  = (float*)take((size_t)B_PAR * 4);
    float* hpagg = (float*)take((size_t)B_PAR * 512 * 4);
    float* u_in  = (float*)take(768 * 4);
    float* vv2   = (float*)take(768 * 4);
    float* erb   = (float*)take(16);
    float* bc    = (float*)take(256 * 4);
    float* er    = (float*)take((size_t)B_PAR * 3 * 4);
    float* q     = (float*)take((size_t)B_PAR * 768 * 4);
    float* p2i   = (float*)take((size_t)B_PAR * 256 * 4);
    float* i2p   = (float*)take((size_t)B_PAR * 256 * 4);
    (void)ws_size; (void)in_sizes; (void)n_in; (void)out_size;

    // ---- preprocessing ----
    hipMemsetAsync(adj8, 0, (size_t)B_PAR * 256 * 256, stream);
    prep_k<<<8512, 256, 0, stream>>>(W1, W2, Wpp, Whg, Wpg, Whrs, Wgin, Wgw,
        Wph, img, W1t, W2t, Wppt, Whgt, Wpgt, Whrst, Wgint, Wmt, Wphb, imgb);
    edge_diag_k<<<(E_EDGES + N_NODES) / 256, 256, 0, stream>>>(esrc, edst, adj8);
    norm2_k<<<N_NODES / 256, 256, 0, stream>>>(adj8, nrm);

    // ---- hrs encoder: split-K (8x256) 64-tile MFMA + reduce ----
    mm64_k<true, true, 0, false, false, false, 256>
        <<<dim3(4, 8, 8), 256, 0, stream>>>(imgb, Whrst, part, 512, 256, 2048,
            nullptr, 1.f);
    hrs_reduce_k<<<512, 256, 0, stream>>>(part, bhrs, hrs, hrsb);

    // ---- GAT precomputes ----
    uv_k<<<1, 256, 0, stream>>>(Wgin, alin, arin, Wph, bph, Wmt,
                                u_in, vv2, erb, bc);
    er_k<<<6, 256, 0, stream>>>(hrs, vv2, erb, er);
    // WcT[j][c] = (Wph @ Wm)[c][j]
    mm64_k<true, true, 1, false, false, false, 0>
        <<<dim3(4, 4), 256, 0, stream>>>(Wmt, Wphb, WcT, 256, 256, 256,
            nullptr, 1.f);

    // ---- GCN layer 1: Yt = (X@W1)^T * nrm[col], agg ----
    mm256_k<true, false, 2, 2, false, false>
        <<<dim3(400, 1), 512, 0, stream>>>(W1t, g_poi, Yt, 256, N_NODES, 64,
            nrm, nullptr);
    agg256_k<<<512, 512, 0, stream>>>(adj8, Yt, XPN, nrm, b1, 1);

    // ---- GCN layer 2 ----
    mm256_k<true, true, 2, 2, false, false>
        <<<dim3(400, 1), 512, 0, stream>>>(W2t, XPN, Yt, 256, N_NODES, 256,
            nrm, nullptr);
    agg256_k<<<512, 512, 0, stream>>>(adj8, Yt, XPN, nrm, b2, 0);
    // XPN = poi_nodes (bf16)

    pool_k<<<B_PAR, 256, 0, stream>>>(XPN, pool, poolb);

    // ---- med similarity (output 1) ----
    med_build_k<<<B_PAR, 256, 0, stream>>>(hrs, pool, medb);
    mm64_k<true, true, 0, false, false, true, 0>
        <<<dim3(8, 8), 256, 0, stream>>>(medb, medb, med_out, 512, 512, 512,
            nullptr, 0.5f);

    // ---- UniSimGraph GCN ----
    dinv_k<<<B_PAR, 256, 0, stream>>>(med_out, dinv);
    nadj_k<<<B_PAR, 256, 0, stream>>>(med_out, dinv, nadjb);
    // Tcatt rows 0-255: t_h^T ; rows 256-511: t_p^T
    mm64_k<true, true, 1, false, false, false, 0>
        <<<dim3(8, 4), 256, 0, stream>>>(Whgt, hrsb, Tcatt, 256, 512, 256,
            nullptr, 1.f);
    mm64_k<true, true, 1, false, false, false, 0>
        <<<dim3(8, 4), 256, 0, stream>>>(Wpgt, poolb, Tcatt + (size_t)256 * 512,
            256, 512, 256, nullptr, 1.f);
    // [hagg | pagg] = relu(nadj @ [t_h | t_p])
    mm64_k<true, true, 0, false, true, false, 0>
        <<<dim3(8, 8), 256, 0, stream>>>(nadjb, Tcatt, hpagg, 512, 512, 512,
            nullptr, 1.f);

    // ---- pp projection (overwrites dead Yt region) ----
    mm256_k<true, true, 1, 0, true, false>
        <<<dim3(1, 400), 512, 0, stream>>>(XPN, Wppt, ppb, N_NODES, 256, 256,
            nullptr, bpp);

    // ---- GAT poi2img ----
    gat_poi2img_k<<<B_PAR, 256, 0, stream>>>(ppb, u_in, er, q);
    mm64_k<false, true, 0, false, false, false, 0>
        <<<dim3(4, 8), 256, 0, stream>>>(q, Wgint, p2i, 512, 256, 768,
            nullptr, 1.f / 3.f);

    // ---- img2poi pooled: i2p = hrs @ Wc + bc ----
    mm64_k<true, true, 0, true, false, false, 0>
        <<<dim3(4, 8), 256, 0, stream>>>(hrsb, WcT, i2p, 512, 256, 256,
            bc, 1.f);

    // ---- final fc ----
    final_k<<<24, 256, 0, stream>>>(i2p, hpagg, p2i, Wfc, bfc, out);
}

// Round 6
// 498.424 us; speedup vs baseline: 3.2175x; 1.0573x over previous
//
#include <hip/hip_runtime.h>
#include <hip/hip_bf16.h>
#include <math.h>

// ---------------------------------------------------------------------------
// NGLU: B=512 parcels x P=200 poi nodes. N=102400, E=1638400, HID=256.
// Round 6: algebraic cuts.
//  - Layer 1 reassociated: (Adj@Xn)@W1 instead of Adj@(Xn@W1): agg K-input
//    width 64 (4.3 GF instead of 17.2), no transposed-Y round trip.
//  - pp eliminated: el = PN@(Wpp@u)+bpp.u ; p2i = qPN@(Wpp@Wgin)/3 + bias.
//  - Layer 2 unchanged (transform->Yt->agg256).
// ---------------------------------------------------------------------------

#define N_NODES 102400
#define B_PAR   512
#define P_NODES 200
#define E_EDGES 1638400
#define HIDF    256

typedef __attribute__((ext_vector_type(8))) short bf16x8;
typedef __attribute__((ext_vector_type(4))) float f32x4;

__device__ __forceinline__ unsigned short f2bf(float x) {
    unsigned u = __builtin_bit_cast(unsigned, x);
    u += 0x7fffu + ((u >> 16) & 1u);               // RNE (finite data only)
    return (unsigned short)(u >> 16);
}
__device__ __forceinline__ float bf2f(unsigned short h) {
    return __builtin_bit_cast(float, (unsigned)h << 16);
}
// LDS tile [rows][64 k] bf16 = 128B/row; 16B-chunk XOR swizzle.
__device__ __forceinline__ int lds_off(int row, int kbyte) {
    return row * 128 + ((((kbyte >> 4) ^ (row & 7)) << 4) | (kbyte & 15));
}
template<bool BF16SRC>
__device__ __forceinline__ bf16x8 load_row8(const void* p, size_t elemoff) {
    if constexpr (BF16SRC) {
        return *(const bf16x8*)((const unsigned short*)p + elemoff);
    } else {
        const float* ap = (const float*)p + elemoff;
        float4 lo = *(const float4*)ap;
        float4 hi = *(const float4*)(ap + 4);
        union { bf16x8 v; unsigned short u[8]; } pk;
        pk.u[0] = f2bf(lo.x); pk.u[1] = f2bf(lo.y);
        pk.u[2] = f2bf(lo.z); pk.u[3] = f2bf(lo.w);
        pk.u[4] = f2bf(hi.x); pk.u[5] = f2bf(hi.y);
        pk.u[6] = f2bf(hi.z); pk.u[7] = f2bf(hi.w);
        return pk.v;
    }
}
__device__ __forceinline__ bf16x8 u8x8_to_bf16(uint2 w) {
    union { bf16x8 v; unsigned short u[8]; } r;
#pragma unroll
    for (int b = 0; b < 4; ++b) {
        r.u[b]     = (unsigned short)(__builtin_bit_cast(unsigned,
                        (float)((w.x >> (8 * b)) & 255u)) >> 16);   // exact: ints<256
        r.u[4 + b] = (unsigned short)(__builtin_bit_cast(unsigned,
                        (float)((w.y >> (8 * b)) & 255u)) >> 16);
    }
    return r.v;
}

// --------------------- 256x256-tile 8-wave MFMA GEMM ------------------------
// D[M,Nc] = A[M,K] @ B[Nc,K]^T  (row-major [m][k] / [n][k] operands)
// OMODE: 0=f32 [M][Nc], 1=bf16 [M][Nc], 2=bf16 parcel-transposed
//        (row=f, col=g -> Yt[g/200][f][g%200] of [512][256][256]).
// SCMODE: 0 none, 1 scale[row], 2 scale[col].
template<bool ABF16, bool BBF16, int OMODE, int SCMODE, bool BIASF, bool RELUF>
__global__ __launch_bounds__(512, 2) void mm256_k(
    const void* __restrict__ Ain, const void* __restrict__ Bin,
    void* __restrict__ Cout, int M, int Nc, int K,
    const float* __restrict__ scale, const float* __restrict__ bias)
{
    __shared__ bf16x8 smem_v[4096];                 // 64 KiB
    unsigned char* Asm = (unsigned char*)smem_v;
    unsigned char* Bsm = Asm + 32768;

    const int tid  = threadIdx.x;
    const int m0   = blockIdx.y * 256;
    const int n0   = blockIdx.x * 256;
    const int sr   = tid >> 3, sc = tid & 7;
    const int lane = tid & 63;
    const int wave = tid >> 6;
    const int wm   = wave >> 2, wn = wave & 3;      // wave tile: 128m x 64n
    const int frow = lane & 15;
    const int fko  = (lane >> 4) << 4;

    f32x4 acc[8][4];
    const f32x4 fz = {0.f, 0.f, 0.f, 0.f};
#pragma unroll
    for (int i = 0; i < 8; ++i)
#pragma unroll
        for (int j = 0; j < 4; ++j) acc[i][j] = fz;

    bf16x8 areg[4], breg[4];
    auto load_tiles = [&](int k0) {
#pragma unroll
        for (int i = 0; i < 4; ++i) {
            int row = sr + 64 * i;
            areg[i] = load_row8<ABF16>(Ain, (size_t)(m0 + row) * K + k0 + sc * 8);
            breg[i] = load_row8<BBF16>(Bin, (size_t)(n0 + row) * K + k0 + sc * 8);
        }
    };

    load_tiles(0);
    for (int k0 = 0; k0 < K; k0 += 64) {
        __syncthreads();
#pragma unroll
        for (int i = 0; i < 4; ++i) {
            *(bf16x8*)(Asm + lds_off(sr + 64 * i, sc * 16)) = areg[i];
            *(bf16x8*)(Bsm + lds_off(sr + 64 * i, sc * 16)) = breg[i];
        }
        __syncthreads();
        if (k0 + 64 < K) load_tiles(k0 + 64);
#pragma unroll
        for (int ks = 0; ks < 2; ++ks) {
            const int kb = ks * 64 + fko;
            bf16x8 bfr[4];
#pragma unroll
            for (int t = 0; t < 4; ++t)
                bfr[t] = *(const bf16x8*)(Bsm + lds_off(wn * 64 + t * 16 + frow, kb));
#pragma unroll
            for (int mi = 0; mi < 8; ++mi) {
                bf16x8 af = *(const bf16x8*)(Asm + lds_off(wm * 128 + mi * 16 + frow, kb));
#pragma unroll
                for (int ni = 0; ni < 4; ++ni)
                    acc[mi][ni] = __builtin_amdgcn_mfma_f32_16x16x32_bf16(
                        af, bfr[ni], acc[mi][ni], 0, 0, 0);
            }
        }
    }

    const int r4 = (lane >> 4) << 2;                // C/D: col=l&15, row=(l>>4)*4+j
#pragma unroll
    for (int mi = 0; mi < 8; ++mi) {
#pragma unroll
        for (int ni = 0; ni < 4; ++ni) {
            int col = n0 + wn * 64 + ni * 16 + frow;
#pragma unroll
            for (int j = 0; j < 4; ++j) {
                int row = m0 + wm * 128 + mi * 16 + r4 + j;
                float v = acc[mi][ni][j];
                if (SCMODE == 1) v *= scale[row];
                if (SCMODE == 2) v *= scale[col];
                if (BIASF)       v += bias[col];
                if (RELUF)       v = fmaxf(v, 0.f);
                if (OMODE == 0) {
                    ((float*)Cout)[(size_t)row * Nc + col] = v;
                } else if (OMODE == 1) {
                    ((unsigned short*)Cout)[(size_t)row * Nc + col] = f2bf(v);
                } else {
                    int p = col / 200, r = col - p * 200;
                    ((unsigned short*)Cout)[((size_t)p * 256 + row) * 256 + r] = f2bf(v);
                }
            }
        }
    }
}

// ------------- GCN aggregation L2: one block per parcel, 256x256 ------------
// Out[p*200+d][f] = (sum_s Adj[p][d][s] * Yt[p][f][s]) * nrm[g] + bias[f]
__global__ __launch_bounds__(512, 2) void agg256_k(
    const unsigned char* __restrict__ Adj, const unsigned short* __restrict__ Yt,
    unsigned short* __restrict__ Outb, const float* __restrict__ nrm,
    const float* __restrict__ bias, int relu)
{
    __shared__ bf16x8 smem_v[4096];
    unsigned char* Asm = (unsigned char*)smem_v;
    unsigned char* Bsm = Asm + 32768;

    const int tid  = threadIdx.x;
    const int p    = blockIdx.x;
    const int sr   = tid >> 3, sc = tid & 7;
    const int lane = tid & 63;
    const int wave = tid >> 6;
    const int wm   = wave >> 2, wn = wave & 3;
    const int frow = lane & 15;
    const int fko  = (lane >> 4) << 4;
    const size_t abase = (size_t)p * 65536;
    const size_t ybase = (size_t)p * 65536;

    f32x4 acc[8][4];
    const f32x4 fz = {0.f, 0.f, 0.f, 0.f};
#pragma unroll
    for (int i = 0; i < 8; ++i)
#pragma unroll
        for (int j = 0; j < 4; ++j) acc[i][j] = fz;

    uint2  awreg[4];
    bf16x8 breg[4];
    auto load_tiles = [&](int k0) {
#pragma unroll
        for (int i = 0; i < 4; ++i) {
            int row = sr + 64 * i;
            awreg[i] = *(const uint2*)(Adj + abase + (size_t)row * 256 + k0 + sc * 8);
            breg[i]  = *(const bf16x8*)(Yt + ybase + (size_t)row * 256 + k0 + sc * 8);
        }
    };

    load_tiles(0);
#pragma unroll
    for (int t4 = 0; t4 < 4; ++t4) {
        __syncthreads();
#pragma unroll
        for (int i = 0; i < 4; ++i) {
            *(bf16x8*)(Asm + lds_off(sr + 64 * i, sc * 16)) = u8x8_to_bf16(awreg[i]);
            *(bf16x8*)(Bsm + lds_off(sr + 64 * i, sc * 16)) = breg[i];
        }
        __syncthreads();
        if (t4 < 3) load_tiles((t4 + 1) * 64);
#pragma unroll
        for (int ks = 0; ks < 2; ++ks) {
            const int kb = ks * 64 + fko;
            bf16x8 bfr[4];
#pragma unroll
            for (int t = 0; t < 4; ++t)
                bfr[t] = *(const bf16x8*)(Bsm + lds_off(wn * 64 + t * 16 + frow, kb));
#pragma unroll
            for (int mi = 0; mi < 8; ++mi) {
                bf16x8 af = *(const bf16x8*)(Asm + lds_off(wm * 128 + mi * 16 + frow, kb));
#pragma unroll
                for (int ni = 0; ni < 4; ++ni)
                    acc[mi][ni] = __builtin_amdgcn_mfma_f32_16x16x32_bf16(
                        af, bfr[ni], acc[mi][ni], 0, 0, 0);
            }
        }
    }

    const int r4 = (lane >> 4) << 2;
#pragma unroll
    for (int mi = 0; mi < 8; ++mi) {
#pragma unroll
        for (int ni = 0; ni < 4; ++ni) {
            int col = wn * 64 + ni * 16 + frow;
#pragma unroll
            for (int j = 0; j < 4; ++j) {
                int d = wm * 128 + mi * 16 + r4 + j;
                if (d < 200) {
                    int g = p * 200 + d;
                    float v = acc[mi][ni][j] * nrm[g] + bias[col];
                    if (relu) v = fmaxf(v, 0.f);
                    Outb[(size_t)g * 256 + col] = f2bf(v);
                }
            }
        }
    }
}

// --------- GCN aggregation L1 (reassociated): AX = Adj @ Xnt^T --------------
// AX[p*200+d][k] = sum_s Adj[p][d][s] * Xnt[p][k][s]   (k in [0,64))
__global__ __launch_bounds__(512) void agg1_k(
    const unsigned char* __restrict__ Adj, const unsigned short* __restrict__ Xnt,
    unsigned short* __restrict__ AX)
{
    __shared__ bf16x8 smem_v[2560];                 // 40 KiB: A 32K + B 8K
    unsigned char* Asm = (unsigned char*)smem_v;
    unsigned char* Bsm = Asm + 32768;

    const int tid  = threadIdx.x;
    const int p    = blockIdx.x;
    const int arow = tid >> 1, ah = tid & 1;        // A: 256 rows x 32B halves
    const int brow = tid >> 3, sc = tid & 7;        // B: 64 rows x 8 chunks
    const int lane = tid & 63;
    const int wave = tid >> 6;                      // 8 waves: rows wave*32
    const int frow = lane & 15;
    const int fko  = (lane >> 4) << 4;
    const size_t abase = (size_t)p * 65536;
    const size_t xbase = (size_t)p * 16384;

    f32x4 acc[2][4];
    const f32x4 fz = {0.f, 0.f, 0.f, 0.f};
#pragma unroll
    for (int i = 0; i < 2; ++i)
#pragma unroll
        for (int j = 0; j < 4; ++j) acc[i][j] = fz;

    uint4  aw[2];
    bf16x8 bg;
    auto load_tiles = [&](int k0) {
        const uint4* ap = (const uint4*)(Adj + abase + (size_t)arow * 256 + k0 + ah * 32);
        aw[0] = ap[0];
        aw[1] = ap[1];
        bg = *(const bf16x8*)(Xnt + xbase + (size_t)brow * 256 + k0 + sc * 8);
    };

    load_tiles(0);
#pragma unroll
    for (int t4 = 0; t4 < 4; ++t4) {
        __syncthreads();
        {
            uint2 l0 = {aw[0].x, aw[0].y}, h0 = {aw[0].z, aw[0].w};
            uint2 l1 = {aw[1].x, aw[1].y}, h1 = {aw[1].z, aw[1].w};
            int base = ah * 64;
            *(bf16x8*)(Asm + lds_off(arow, base +  0)) = u8x8_to_bf16(l0);
            *(bf16x8*)(Asm + lds_off(arow, base + 16)) = u8x8_to_bf16(h0);
            *(bf16x8*)(Asm + lds_off(arow, base + 32)) = u8x8_to_bf16(l1);
            *(bf16x8*)(Asm + lds_off(arow, base + 48)) = u8x8_to_bf16(h1);
            *(bf16x8*)(Bsm + lds_off(brow, sc * 16)) = bg;
        }
        __syncthreads();
        if (t4 < 3) load_tiles((t4 + 1) * 64);
#pragma unroll
        for (int ks = 0; ks < 2; ++ks) {
            const int kb = ks * 64 + fko;
            bf16x8 bfr[4];
#pragma unroll
            for (int t = 0; t < 4; ++t)
                bfr[t] = *(const bf16x8*)(Bsm + lds_off(t * 16 + frow, kb));
#pragma unroll
            for (int mi = 0; mi < 2; ++mi) {
                bf16x8 af = *(const bf16x8*)(Asm + lds_off(wave * 32 + mi * 16 + frow, kb));
#pragma unroll
                for (int ni = 0; ni < 4; ++ni)
                    acc[mi][ni] = __builtin_amdgcn_mfma_f32_16x16x32_bf16(
                        af, bfr[ni], acc[mi][ni], 0, 0, 0);
            }
        }
    }

    const int r4 = (lane >> 4) << 2;
#pragma unroll
    for (int mi = 0; mi < 2; ++mi) {
#pragma unroll
        for (int ni = 0; ni < 4; ++ni) {
            int col = ni * 16 + frow;
#pragma unroll
            for (int j = 0; j < 4; ++j) {
                int d = wave * 32 + mi * 16 + r4 + j;
                if (d < 200)
                    AX[((size_t)(p * 200 + d)) * 64 + col] = f2bf(acc[mi][ni][j]);
            }
        }
    }
}

// -------- Xnt[p][k][s] = g_poi[p*200+s][k] * nrm[p*200+s] (pad s>=200) -------
__global__ __launch_bounds__(256) void xt_k(const float* __restrict__ gp,
                                            const float* __restrict__ nrm,
                                            unsigned short* __restrict__ Xnt)
{
    __shared__ unsigned short lsh[64][264];
    const int p = blockIdx.x, tid = threadIdx.x;
    for (int idx = tid; idx < 256 * 16; idx += 256) {
        int s = idx >> 4, kc = idx & 15;
        float4 v = {0.f, 0.f, 0.f, 0.f};
        float nr = 0.f;
        if (s < 200) {
            v = *(const float4*)(gp + ((size_t)(p * 200 + s)) * 64 + kc * 4);
            nr = nrm[p * 200 + s];
        }
        lsh[kc * 4 + 0][s] = f2bf(v.x * nr);
        lsh[kc * 4 + 1][s] = f2bf(v.y * nr);
        lsh[kc * 4 + 2][s] = f2bf(v.z * nr);
        lsh[kc * 4 + 3][s] = f2bf(v.w * nr);
    }
    __syncthreads();
    for (int idx = tid; idx < 64 * 32; idx += 256) {
        int k = idx >> 5, ch = idx & 31;
        uint4 o = *(const uint4*)(&lsh[k][ch * 8]);
        *(uint4*)(Xnt + (size_t)p * 16384 + k * 256 + ch * 8) = o;
    }
}

// ----------------------- 64x64 MFMA GEMM (small shapes) ---------------------
template<bool ABF16, bool BBF16, int OMODE, bool BIASF, bool RELUF,
         bool MEDOUT, int KCHUNK>
__global__ __launch_bounds__(256) void mm64_k(
    const void* __restrict__ Ain, const void* __restrict__ Bin,
    void* __restrict__ Cout, int M, int Nc, int K,
    const float* __restrict__ bias, float alpha)
{
    __shared__ bf16x8 smem_v[1024];                 // 16 KiB
    unsigned char* Asm = (unsigned char*)smem_v;
    unsigned char* Bsm = Asm + 8192;

    const int tid  = threadIdx.x;
    const int m0   = blockIdx.y * 64;
    const int n0   = blockIdx.x * 64;
    const int sr   = tid >> 3, sc = tid & 7;
    const int lane = tid & 63;
    const int wm   = (tid >> 7) & 1, wn = (tid >> 6) & 1;
    const int frow = lane & 15;
    const int fko  = (lane >> 4) << 4;

    int kbeg = 0, kend = K;
    float* Cf = (float*)Cout;
    if (KCHUNK > 0) {
        kbeg = blockIdx.z * KCHUNK; kend = kbeg + KCHUNK;
        Cf += (size_t)blockIdx.z * M * Nc;
    }

    f32x4 acc[2][2];
    const f32x4 fz = {0.f, 0.f, 0.f, 0.f};
#pragma unroll
    for (int i = 0; i < 2; ++i)
#pragma unroll
        for (int j = 0; j < 2; ++j) acc[i][j] = fz;

    bf16x8 areg[2], breg[2];
    auto load_tiles = [&](int k0) {
#pragma unroll
        for (int i = 0; i < 2; ++i) {
            int row = sr + 32 * i;
            areg[i] = load_row8<ABF16>(Ain, (size_t)(m0 + row) * K + k0 + sc * 8);
            breg[i] = load_row8<BBF16>(Bin, (size_t)(n0 + row) * K + k0 + sc * 8);
        }
    };

    load_tiles(kbeg);
    for (int k0 = kbeg; k0 < kend; k0 += 64) {
        __syncthreads();
#pragma unroll
        for (int i = 0; i < 2; ++i) {
            *(bf16x8*)(Asm + lds_off(sr + 32 * i, sc * 16)) = areg[i];
            *(bf16x8*)(Bsm + lds_off(sr + 32 * i, sc * 16)) = breg[i];
        }
        __syncthreads();
        if (k0 + 64 < kend) load_tiles(k0 + 64);
#pragma unroll
        for (int ks = 0; ks < 2; ++ks) {
            const int kb = ks * 64 + fko;
            bf16x8 af[2], bfr[2];
#pragma unroll
            for (int t = 0; t < 2; ++t)
                af[t] = *(const bf16x8*)(Asm + lds_off(wm * 32 + t * 16 + frow, kb));
#pragma unroll
            for (int t = 0; t < 2; ++t)
                bfr[t] = *(const bf16x8*)(Bsm + lds_off(wn * 32 + t * 16 + frow, kb));
#pragma unroll
            for (int mi = 0; mi < 2; ++mi)
#pragma unroll
                for (int ni = 0; ni < 2; ++ni)
                    acc[mi][ni] = __builtin_amdgcn_mfma_f32_16x16x32_bf16(
                        af[mi], bfr[ni], acc[mi][ni], 0, 0, 0);
        }
    }

    const int r4 = (lane >> 4) << 2;
#pragma unroll
    for (int mi = 0; mi < 2; ++mi) {
#pragma unroll
        for (int ni = 0; ni < 2; ++ni) {
            int col = n0 + wn * 32 + ni * 16 + frow;
#pragma unroll
            for (int j = 0; j < 4; ++j) {
                int row = m0 + wm * 32 + mi * 16 + r4 + j;
                float v = acc[mi][ni][j] * alpha;
                if (BIASF)  v += bias[col];
                if (RELUF)  v = fmaxf(v, 0.f);
                if (MEDOUT) v += 0.5f;
                if (OMODE == 0) {
                    Cf[(size_t)row * Nc + col] = v;
                } else {
                    ((unsigned short*)Cout)[(size_t)row * Nc + col] = f2bf(v);
                }
            }
        }
    }
}

// ------------------------- graph preprocessing -----------------------------
__global__ __launch_bounds__(256) void edge_diag_k(
    const int* __restrict__ esrc, const int* __restrict__ edst,
    unsigned char* __restrict__ A)
{
    int id = blockIdx.x * 256 + threadIdx.x;        // E + N = 1740800
    size_t bo;
    if (id < E_EDGES) {
        int s = esrc[id], d = edst[id];
        int p = d / 200;
        int dl = d - p * 200, sl = s - p * 200;
        bo = (((size_t)(p * 256 + dl)) << 8) + (unsigned)sl;
    } else {
        int i2 = id - E_EDGES;                      // < N
        int p = i2 / 200, d = i2 - p * 200;
        bo = (((size_t)(p * 256 + d)) << 8) + (unsigned)d;
    }
    atomicAdd((unsigned int*)(A + (bo & ~(size_t)3)), 1u << ((bo & 3) * 8));
}

__global__ __launch_bounds__(256) void norm2_k(const unsigned char* __restrict__ A,
                                               float* __restrict__ nrm)
{
    int g = blockIdx.x * 256 + threadIdx.x;
    int p = g / 200, d = g - p * 200;
    const uint4* row = (const uint4*)(A + (((size_t)(p * 256 + d)) << 8));
    unsigned s = 0;
#pragma unroll
    for (int i = 0; i < 16; ++i) {
        uint4 w = row[i];
        unsigned a = w.x, b = w.y, c = w.z, e = w.w;
        s += (a & 255) + ((a >> 8) & 255) + ((a >> 16) & 255) + (a >> 24);
        s += (b & 255) + ((b >> 8) & 255) + ((b >> 16) & 255) + (b >> 24);
        s += (c & 255) + ((c >> 8) & 255) + ((c >> 16) & 255) + (c >> 24);
        s += (e & 255) + ((e >> 8) & 255) + ((e >> 16) & 255) + (e >> 24);
    }
    nrm[g] = rsqrtf((float)s);                      // row-sum = in-deg + self
}

// ------------- all weight transposes/casts + img cast -----------------------
__global__ __launch_bounds__(256) void prep_k(
    const float* __restrict__ W1, const float* __restrict__ W2,
    const float* __restrict__ Whg,
    const float* __restrict__ Wpg, const float* __restrict__ Whrs,
    const float* __restrict__ Wgin, const float* __restrict__ Wgw,
    const float* __restrict__ Wph, const float* __restrict__ img,
    unsigned short* __restrict__ W1t, unsigned short* __restrict__ W2t,
    unsigned short* __restrict__ Whgt,
    unsigned short* __restrict__ Wpgt, unsigned short* __restrict__ Whrst,
    unsigned short* __restrict__ Wgint, unsigned short* __restrict__ Wmt,
    unsigned short* __restrict__ Wphb, unsigned short* __restrict__ imgb)
{
    int b = blockIdx.x, tid = threadIdx.x;
    if (b < 64) {                 // W1t [256][64]
        int id = b * 256 + tid; int n = id >> 6, k = id & 63;
        W1t[id] = f2bf(W1[(size_t)k * 256 + n]);
    } else if (b < 320) {         // W2t [256][256]
        int id = (b - 64) * 256 + tid; int n = id >> 8, k = id & 255;
        W2t[id] = f2bf(W2[(size_t)k * 256 + n]);
    } else if (b < 576) {         // Whgt
        int id = (b - 320) * 256 + tid; int n = id >> 8, k = id & 255;
        Whgt[id] = f2bf(Whg[(size_t)k * 256 + n]);
    } else if (b < 832) {         // Wpgt
        int id = (b - 576) * 256 + tid; int n = id >> 8, k = id & 255;
        Wpgt[id] = f2bf(Wpg[(size_t)k * 256 + n]);
    } else if (b < 2880) {        // Whrst [256][2048]
        int id = (b - 832) * 256 + tid; int n = id >> 11, k = id & 2047;
        Whrst[id] = f2bf(Whrs[(size_t)k * 256 + n]);
    } else if (b < 3648) {        // Wgint [256][768], k-order = h*256+t
        int id = (b - 2880) * 256 + tid; int j = id / 768, k2 = id - j * 768;
        int t = k2 & 255, h = k2 >> 8;
        Wgint[id] = f2bf(Wgin[(size_t)t * 768 + h * 256 + j]);
    } else if (b < 3904) {        // Wmt [256 j][256 t] = mean_h Wgw / (1+1e-9)
        int id = (b - 3648) * 256 + tid; int j = id >> 8, t = id & 255;
        const float c3 = (1.f / 3.f) * (1.f / (1.f + 1e-9f));
        float s = Wgw[(size_t)t * 768 + j] + Wgw[(size_t)t * 768 + 256 + j] +
                  Wgw[(size_t)t * 768 + 512 + j];
        Wmt[id] = f2bf(s * c3);
    } else if (b < 4160) {        // Wphb cast
        int id = (b - 3904) * 256 + tid;
        Wphb[id] = f2bf(Wph[id]);
    } else {                      // imgb cast [512][2048]
        int id = (b - 4160) * 256 + tid;
        imgb[id] = f2bf(img[id]);
    }
}

// --- WpG[j][(h,c)] = sum_t Wpp[c][t]*Wgin[t][h*256+j]; bgg[j] (bias fold) ----
__global__ __launch_bounds__(256) void wpg_k(
    const float* __restrict__ Wpp, const float* __restrict__ Wgin,
    const float* __restrict__ bpp,
    unsigned short* __restrict__ WpG, float* __restrict__ bgg)
{
    __shared__ float wsh[256];
    const int b = blockIdx.x, j = threadIdx.x;
    if (b < 768) {
        int h = b >> 8, c = b & 255;
        wsh[j] = Wpp[(size_t)c * 256 + j];
        __syncthreads();
        float acc = 0.f;
        for (int t = 0; t < 256; ++t)
            acc += wsh[t] * Wgin[(size_t)t * 768 + h * 256 + j];
        WpG[(size_t)j * 768 + h * 256 + c] = f2bf(acc);
    } else {
        float s = 0.f;
        for (int h = 0; h < 3; ++h)
            for (int t = 0; t < 256; ++t)
                s += bpp[t] * Wgin[(size_t)t * 768 + h * 256 + j];
        bgg[j] = s * (1.f / 3.f);
    }
}

// --------------------------- hrs split-K reduce -----------------------------
__global__ __launch_bounds__(256) void hrs_reduce_k(
    const float* __restrict__ part, const float* __restrict__ bhrs,
    float* __restrict__ hrs, unsigned short* __restrict__ hrsb)
{
    int id = blockIdx.x * 256 + threadIdx.x;        // 131072
    float s = bhrs[id & 255];
#pragma unroll
    for (int z = 0; z < 8; ++z) s += part[(size_t)z * 131072 + id];
    hrs[id] = s;
    hrsb[id] = f2bf(s);
}

// ------------------------------ pooling (vectorized) ------------------------
__global__ __launch_bounds__(256) void pool_k(const unsigned short* __restrict__ X,
                                              float* __restrict__ Pl,
                                              unsigned short* __restrict__ Plb)
{
    __shared__ float sh[2048];
    const int b = blockIdx.x, tid = threadIdx.x;
    const int cg = tid & 31, rg = tid >> 5;
    const size_t base = (size_t)b * P_NODES * HIDF + cg * 8;
    float acc[8] = {};
    for (int n = rg; n < P_NODES; n += 8) {
        union { uint4 q; unsigned short u[8]; } v;
        v.q = *(const uint4*)(X + base + (size_t)n * HIDF);
#pragma unroll
        for (int j = 0; j < 8; ++j) acc[j] += bf2f(v.u[j]);
    }
#pragma unroll
    for (int j = 0; j < 8; ++j) sh[rg * 256 + cg * 8 + j] = acc[j];
    __syncthreads();
    float s = 0.f;
#pragma unroll
    for (int r = 0; r < 8; ++r) s += sh[r * 256 + tid];
    s *= (1.f / 200.f);
    Pl[(size_t)b * 256 + tid] = s;
    Plb[(size_t)b * 256 + tid] = f2bf(s);
}

// ------------------- med = rownorm(concat(hrs, pool)) -----------------------
__global__ __launch_bounds__(256) void med_build_k(
    const float* __restrict__ hrs, const float* __restrict__ pool,
    unsigned short* __restrict__ medb)
{
    __shared__ float red[256];
    int b = blockIdx.x, f = threadIdx.x;
    float v0 = hrs[(size_t)b * 256 + f];
    float v1 = pool[(size_t)b * 256 + f];
    red[f] = v0 * v0 + v1 * v1;
    __syncthreads();
    for (int s = 128; s > 0; s >>= 1) {
        if (f < s) red[f] += red[f + s];
        __syncthreads();
    }
    float inv = rsqrtf(red[0]);
    medb[(size_t)b * 512 + f]       = f2bf(v0 * inv);
    medb[(size_t)b * 512 + 256 + f] = f2bf(v1 * inv);
}

// ---------------------- thresholded-similarity GCN --------------------------
__global__ __launch_bounds__(256) void dinv_k(const float* __restrict__ mo,
                                              float* __restrict__ dinv)
{
    __shared__ int red[256];
    int i = blockIdx.x, t = threadIdx.x;
    int c = 0;
    for (int j = t; j < 512; j += 256) c += (mo[(size_t)i * 512 + j] >= 0.9f) ? 1 : 0;
    red[t] = c; __syncthreads();
    for (int s = 128; s > 0; s >>= 1) {
        if (t < s) red[t] += red[t + s];
        __syncthreads();
    }
    if (t == 0) dinv[i] = rsqrtf((float)red[0]);
}

__global__ __launch_bounds__(256) void nadj_k(const float* __restrict__ mo,
                                              const float* __restrict__ dinv,
                                              unsigned short* __restrict__ nadjb)
{
    int i = blockIdx.x, t = threadIdx.x;
    float di = dinv[i];
    for (int j = t; j < 512; j += 256) {
        float a = (mo[(size_t)i * 512 + j] >= 0.9f || j == i) ? 1.f : 0.f;
        nadjb[(size_t)i * 512 + j] = f2bf(a * di * dinv[j]);
    }
}

// ------------------------------ GAT pieces ----------------------------------
// u2[t,h] from (Wgin,al); v2[t,h] from (Wgin,ar);
// wu[c,h] = Wpp^T-fold of u2; vv2[c,h] = Wph-fold of v2;
// erb[h] = bph.v2 ; eb0[h] = bpp.u2 ; bc[k] = bph @ Wm[:,k]
__global__ __launch_bounds__(256) void uv_k(
    const float* __restrict__ Wgin, const float* __restrict__ al,
    const float* __restrict__ ar, const float* __restrict__ Wph,
    const float* __restrict__ bph, const unsigned short* __restrict__ Wmt,
    const float* __restrict__ Wpp, const float* __restrict__ bpp,
    float* __restrict__ wu, float* __restrict__ vv2,
    float* __restrict__ erb, float* __restrict__ eb0, float* __restrict__ bc)
{
    __shared__ float ush[768];
    __shared__ float vsh[768];
    int k = threadIdx.x;
#pragma unroll
    for (int h = 0; h < 3; ++h) {
        float su = 0.f, sv = 0.f;
        for (int t = 0; t < 256; ++t) {
            float w = Wgin[(size_t)k * 768 + h * 256 + t];
            su += w * al[h * 256 + t];
            sv += w * ar[h * 256 + t];
        }
        ush[k * 3 + h] = su;
        vsh[k * 3 + h] = sv;
    }
    __syncthreads();
    float a0 = 0.f, a1 = 0.f, a2 = 0.f;
    float w0 = 0.f, w1 = 0.f, w2 = 0.f, s = 0.f;
    for (int t = 0; t < 256; ++t) {
        float wp = Wph[(size_t)k * 256 + t];
        a0 += wp * vsh[t * 3 + 0];
        a1 += wp * vsh[t * 3 + 1];
        a2 += wp * vsh[t * 3 + 2];
        float wq = Wpp[(size_t)k * 256 + t];
        w0 += wq * ush[t * 3 + 0];
        w1 += wq * ush[t * 3 + 1];
        w2 += wq * ush[t * 3 + 2];
        s  += bph[t] * bf2f(Wmt[(size_t)k * 256 + t]);
    }
    vv2[k * 3 + 0] = a0; vv2[k * 3 + 1] = a1; vv2[k * 3 + 2] = a2;
    wu[k * 3 + 0]  = w0; wu[k * 3 + 1]  = w1; wu[k * 3 + 2]  = w2;
    bc[k] = s;
    if (k < 3) {
        float e = 0.f, e0 = 0.f;
        for (int t = 0; t < 256; ++t) {
            e  += bph[t] * vsh[t * 3 + k];
            e0 += bpp[t] * ush[t * 3 + k];
        }
        erb[k] = e;
        eb0[k] = e0;
    }
}

__global__ __launch_bounds__(256) void er_k(const float* __restrict__ hrs,
                                            const float* __restrict__ vv2,
                                            const float* __restrict__ erb,
                                            const float* __restrict__ eb0,
                                            float* __restrict__ er)
{
    int id = blockIdx.x * 256 + threadIdx.x;
    if (id >= B_PAR * 3) return;
    int b = id / 3, h = id % 3;
    float s = erb[h] + eb0[h];
    for (int k = 0; k < 256; ++k) s += hrs[(size_t)b * 256 + k] * vv2[k * 3 + h];
    er[id] = s;
}

// Per-parcel: el = PN@wu, e = leaky(el+er), softmax over 200 nodes/head,
// qPN[b,h,:] = sum_n alpha[n,h] * PN[n,:]
__global__ __launch_bounds__(256) void gat_poi2img_k(
    const unsigned short* __restrict__ PN, const float* __restrict__ wu,
    const float* __restrict__ er, float* __restrict__ q)
{
    __shared__ float esh[600];
    __shared__ float ash[600];
    __shared__ float ush[768];
    __shared__ float mz[8];
    const int p = blockIdx.x, tid = threadIdx.x;
    const size_t base = (size_t)p * P_NODES;

    for (int i = tid; i < 768; i += 256) ush[i] = wu[i];
    __syncthreads();

    for (int it = tid; it < 600; it += 256) {
        int n = it / 3, h = it % 3;
        const unsigned short* row = PN + (base + n) * HIDF;
        float s = 0.f;
        for (int k = 0; k < 256; k += 8) {
            union { uint4 qv; unsigned short us[8]; } w;
            w.qv = *(const uint4*)(row + k);
#pragma unroll
            for (int j = 0; j < 8; ++j) s += bf2f(w.us[j]) * ush[(k + j) * 3 + h];
        }
        s += er[p * 3 + h];
        esh[it] = s > 0.f ? s : 0.2f * s;
    }
    __syncthreads();

    int wave = tid >> 6, lane = tid & 63;
    if (wave < 3) {
        float mx = -1e30f;
        for (int n = lane; n < P_NODES; n += 64) mx = fmaxf(mx, esh[n * 3 + wave]);
        for (int o = 32; o > 0; o >>= 1) mx = fmaxf(mx, __shfl_xor(mx, o));
        float sm = 0.f;
        for (int n = lane; n < P_NODES; n += 64) sm += expf(esh[n * 3 + wave] - mx);
        for (int o = 32; o > 0; o >>= 1) sm += __shfl_xor(sm, o);
        if (lane == 0) { mz[wave] = mx; mz[4 + wave] = sm; }
    }
    __syncthreads();

    for (int it = tid; it < 600; it += 256) {
        int h = it % 3;
        ash[it] = expf(esh[it] - mz[h]) / (mz[4 + h] + 1e-9f);
    }
    __syncthreads();

    float a0 = 0.f, a1 = 0.f, a2 = 0.f;
    for (int n = 0; n < P_NODES; ++n) {
        float vv = bf2f(PN[(base + n) * HIDF + tid]);
        a0 += ash[n * 3 + 0] * vv;
        a1 += ash[n * 3 + 1] * vv;
        a2 += ash[n * 3 + 2] * vv;
    }
    q[((size_t)p * 3 + 0) * 256 + tid] = a0;
    q[((size_t)p * 3 + 1) * 256 + tid] = a1;
    q[((size_t)p * 3 + 2) * 256 + tid] = a2;
}

// --------------------------- final projection -------------------------------
__global__ __launch_bounds__(256) void final_k(
    const float* __restrict__ i2p, const float* __restrict__ hpagg,
    const float* __restrict__ p2i,
    const float* __restrict__ Wfc, const float* __restrict__ bfc,
    float* __restrict__ out)
{
    int id = blockIdx.x * 256 + threadIdx.x;
    if (id >= B_PAR * 12) return;
    int b = id / 12, o = id % 12;
    float acc = bfc[o];
    const float* s0 = i2p + (size_t)b * 256;          // img2poi_pooled
    const float* s1 = hpagg + (size_t)b * 512 + 256;  // poi_agg
    const float* s2 = p2i + (size_t)b * 256;          // poi2img
    const float* s3 = hpagg + (size_t)b * 512;        // hrs_agg
    for (int k = 0; k < 256; ++k) {
        acc += s0[k] * Wfc[(size_t)(0 * 256 + k) * 12 + o];
        acc += s1[k] * Wfc[(size_t)(1 * 256 + k) * 12 + o];
        acc += s2[k] * Wfc[(size_t)(2 * 256 + k) * 12 + o];
        acc += s3[k] * Wfc[(size_t)(3 * 256 + k) * 12 + o];
    }
    out[id] = acc;
}

// ---------------------------------------------------------------------------
extern "C" void kernel_launch(void* const* d_in, const int* in_sizes, int n_in,
                              void* d_out, int out_size, void* d_ws, size_t ws_size,
                              hipStream_t stream)
{
    const float* g_poi = (const float*)d_in[0];
    const float* img   = (const float*)d_in[1];
    const int*   esrc  = (const int*)d_in[2];
    const int*   edst  = (const int*)d_in[3];
    const float* W1    = (const float*)d_in[4];
    const float* b1    = (const float*)d_in[5];
    const float* W2    = (const float*)d_in[6];
    const float* b2    = (const float*)d_in[7];
    const float* Whrs  = (const float*)d_in[8];
    const float* bhrs  = (const float*)d_in[9];
    const float* Wph   = (const float*)d_in[10];
    const float* bph   = (const float*)d_in[11];
    const float* Wpp   = (const float*)d_in[12];
    const float* bpp   = (const float*)d_in[13];
    const float* Wgin  = (const float*)d_in[14];
    const float* alin  = (const float*)d_in[15];
    const float* arin  = (const float*)d_in[16];
    const float* Wgw   = (const float*)d_in[17];
    // d_in[18]/d_in[19] (al_with/ar_with) numerically dead: each poi node has
    // exactly one incoming parcel edge -> edge-softmax weight = 1/(1+1e-9).
    const float* Whg   = (const float*)d_in[20];
    const float* Wpg   = (const float*)d_in[21];
    const float* Wfc   = (const float*)d_in[22];
    const float* bfc   = (const float*)d_in[23];

    float* out     = (float*)d_out;
    float* med_out = out + B_PAR * 12;

    char* ws = (char*)d_ws;
    size_t off = 0;
    auto take = [&](size_t bytes) { void* pv = ws + off; off += (bytes + 255) & ~(size_t)255; return pv; };

    unsigned char*  adj8 = (unsigned char*)take((size_t)B_PAR * 256 * 256);     // 33.6MB
    unsigned short* Yt   = (unsigned short*)take((size_t)B_PAR * 256 * 256 * 2);// 67.1MB
    unsigned short* Xnt  = Yt;                      // [512][64][256], dead before Yt written
    unsigned short* XPN  = (unsigned short*)take((size_t)N_NODES * 256 * 2);    // 52.4MB
    unsigned short* AX   = (unsigned short*)take((size_t)N_NODES * 64 * 2);     // 13.1MB
    float*          part = (float*)take((size_t)8 * 512 * 256 * 4);             // 4.2MB

    unsigned short* W1t   = (unsigned short*)take(256 * 64 * 2);
    unsigned short* W2t   = (unsigned short*)take(256 * 256 * 2);
    unsigned short* Whgt  = (unsigned short*)take(256 * 256 * 2);
    unsigned short* Wpgt  = (unsigned short*)take(256 * 256 * 2);
    unsigned short* Whrst = (unsigned short*)take((size_t)256 * 2048 * 2);
    unsigned short* Wgint = (unsigned short*)take((size_t)256 * 768 * 2);
    unsigned short* Wmt   = (unsigned short*)take(256 * 256 * 2);
    unsigned short* Wphb  = (unsigned short*)take(256 * 256 * 2);
    unsigned short* WcT   = (unsigned short*)take(256 * 256 * 2);
    unsigned short* WpG   = (unsigned short*)take((size_t)256 * 768 * 2);
    unsigned short* imgb  = (unsigned short*)take((size_t)512 * 2048 * 2);
    unsigned short* hrsb  = (unsigned short*)take((size_t)B_PAR * 256 * 2);
    unsigned short* poolb = (unsigned short*)take((size_t)B_PAR * 256 * 2);
    unsigned short* medb  = (unsigned short*)take((size_t)B_PAR * 512 * 2);
    unsigned short* nadjb = (unsigned short*)take((size_t)B_PAR * 512 * 2);
    unsigned short* Tcatt = (unsigned short*)take((size_t)512 * 512 * 2);
    float* nrm   = (float*)take((size_t)N_NODES * 4);
    float* hrs   = (float*)take((size_t)B_PAR * 256 * 4);
    float* pool  = (float*)take((size_t)B_PAR * 256 * 4);
    float* dinv  = (float*)take((size_t)B_PAR * 4);
    float* hpagg = (float*)take((size_t)B_PAR * 512 * 4);
    float* wu    = (float*)take(768 * 4);
    float* vv2   = (float*)take(768 * 4);
    float* erb   = (float*)take(16);
    float* eb0   = (float*)take(16);
    float* bc    = (float*)take(256 * 4);
    float* bgg   = (float*)take(256 * 4);
    float* er    = (float*)take((size_t)B_PAR * 3 * 4);
    float* q     = (float*)take((size_t)B_PAR * 768 * 4);
    float* p2i   = (float*)take((size_t)B_PAR * 256 * 4);
    float* i2p   = (float*)take((size_t)B_PAR * 256 * 4);
    (void)ws_size; (void)in_sizes; (void)n_in; (void)out_size;

    // ---- preprocessing ----
    hipMemsetAsync(adj8, 0, (size_t)B_PAR * 256 * 256, stream);
    prep_k<<<8256, 256, 0, stream>>>(W1, W2, Whg, Wpg, Whrs, Wgin, Wgw,
        Wph, img, W1t, W2t, Whgt, Wpgt, Whrst, Wgint, Wmt, Wphb, imgb);
    edge_diag_k<<<(E_EDGES + N_NODES) / 256, 256, 0, stream>>>(esrc, edst, adj8);
    norm2_k<<<N_NODES / 256, 256, 0, stream>>>(adj8, nrm);
    wpg_k<<<769, 256, 0, stream>>>(Wpp, Wgin, bpp, WpG, bgg);

    // ---- hrs encoder: split-K (8x256) 64-tile MFMA + reduce ----
    mm64_k<true, true, 0, false, false, false, 256>
        <<<dim3(4, 8, 8), 256, 0, stream>>>(imgb, Whrst, part, 512, 256, 2048,
            nullptr, 1.f);
    hrs_reduce_k<<<512, 256, 0, stream>>>(part, bhrs, hrs, hrsb);

    // ---- GAT precomputes ----
    uv_k<<<1, 256, 0, stream>>>(Wgin, alin, arin, Wph, bph, Wmt, Wpp, bpp,
                                wu, vv2, erb, eb0, bc);
    er_k<<<6, 256, 0, stream>>>(hrs, vv2, erb, eb0, er);
    // WcT[j][c] = (Wph @ Wm)[c][j]
    mm64_k<true, true, 1, false, false, false, 0>
        <<<dim3(4, 4), 256, 0, stream>>>(Wmt, Wphb, WcT, 256, 256, 256,
            nullptr, 1.f);

    // ---- GCN layer 1 (reassociated): AX = Adj@Xn, X1 = relu(AX@W1*nrm+b1) ---
    xt_k<<<512, 256, 0, stream>>>(g_poi, nrm, Xnt);
    agg1_k<<<512, 512, 0, stream>>>(adj8, Xnt, AX);
    mm256_k<true, true, 1, 1, true, true>
        <<<dim3(1, 400), 512, 0, stream>>>(AX, W1t, XPN, N_NODES, 256, 64,
            nrm, b1);
    // XPN = X1 (bf16)

    // ---- GCN layer 2: Yt = (X1@W2)^T * nrm[col], agg ----
    mm256_k<true, true, 2, 2, false, false>
        <<<dim3(400, 1), 512, 0, stream>>>(W2t, XPN, Yt, 256, N_NODES, 256,
            nrm, nullptr);
    agg256_k<<<512, 512, 0, stream>>>(adj8, Yt, XPN, nrm, b2, 0);
    // XPN = poi_nodes (bf16)

    pool_k<<<B_PAR, 256, 0, stream>>>(XPN, pool, poolb);

    // ---- med similarity (output 1) ----
    med_build_k<<<B_PAR, 256, 0, stream>>>(hrs, pool, medb);
    mm64_k<true, true, 0, false, false, true, 0>
        <<<dim3(8, 8), 256, 0, stream>>>(medb, medb, med_out, 512, 512, 512,
            nullptr, 0.5f);

    // ---- UniSimGraph GCN ----
    dinv_k<<<B_PAR, 256, 0, stream>>>(med_out, dinv);
    nadj_k<<<B_PAR, 256, 0, stream>>>(med_out, dinv, nadjb);
    mm64_k<true, true, 1, false, false, false, 0>
        <<<dim3(8, 4), 256, 0, stream>>>(Whgt, hrsb, Tcatt, 256, 512, 256,
            nullptr, 1.f);
    mm64_k<true, true, 1, false, false, false, 0>
        <<<dim3(8, 4), 256, 0, stream>>>(Wpgt, poolb, Tcatt + (size_t)256 * 512,
            256, 512, 256, nullptr, 1.f);
    mm64_k<true, true, 0, false, true, false, 0>
        <<<dim3(8, 8), 256, 0, stream>>>(nadjb, Tcatt, hpagg, 512, 512, 512,
            nullptr, 1.f);

    // ---- GAT poi2img (pp never materialized) ----
    gat_poi2img_k<<<B_PAR, 256, 0, stream>>>(XPN, wu, er, q);
    // p2i = (1/3) qPN @ WpG + bgg
    mm64_k<false, true, 0, true, false, false, 0>
        <<<dim3(4, 8), 256, 0, stream>>>(q, WpG, p2i, 512, 256, 768,
            bgg, 1.f / 3.f);

    // ---- img2poi pooled: i2p = hrs @ Wc + bc ----
    mm64_k<true, true, 0, true, false, false, 0>
        <<<dim3(4, 8), 256, 0, stream>>>(hrsb, WcT, i2p, 512, 256, 256,
            bc, 1.f);

    // ---- final fc ----
    final_k<<<24, 256, 0, stream>>>(i2p, hpagg, p2i, Wfc, bfc, out);
}